// Round 1
// baseline (1274.327 us; speedup 1.0000x reference)
//
#include <hip/hip_runtime.h>
#include <cstdint>
#include <cstddef>

#define N_NODES 100000
#define N_EDGES 1600000
#define IN_DIM  64
#define HID     128
#define NCLS    18
#define BATCH   8
#define TOPK    5000
#define NPER    12500   // N_NODES / BATCH
#define SORTN   16384   // next pow2 >= NPER

// ---------------- degree / norm ----------------

__global__ __launch_bounds__(256) void k_degrees(const int* __restrict__ src,
                                                 const int* __restrict__ dst,
                                                 int* __restrict__ degS,
                                                 int* __restrict__ degD) {
    int e = blockIdx.x * 256 + threadIdx.x;
    if (e < N_EDGES) {
        atomicAdd(&degS[src[e]], 1);
        atomicAdd(&degD[dst[e]], 1);
    }
}

__global__ __launch_bounds__(256) void k_norms(const int* __restrict__ degS,
                                               const int* __restrict__ degD,
                                               float* __restrict__ normS,
                                               float* __restrict__ normD) {
    int i = blockIdx.x * 256 + threadIdx.x;
    if (i < N_NODES) {
        normS[i] = 1.0f / sqrtf((float)max(degS[i], 1));
        normD[i] = 1.0f / sqrtf((float)max(degD[i], 1));
    }
}

// ---------------- exclusive scan of in-degrees (3-kernel) ----------------

__global__ __launch_bounds__(1024) void k_scanA(const int* __restrict__ degD,
                                                int* __restrict__ blockSums) {
    __shared__ int lds[1024];
    int i = blockIdx.x * 1024 + threadIdx.x;
    lds[threadIdx.x] = (i < N_NODES) ? degD[i] : 0;
    __syncthreads();
    for (int s = 512; s > 0; s >>= 1) {
        if (threadIdx.x < s) lds[threadIdx.x] += lds[threadIdx.x + s];
        __syncthreads();
    }
    if (threadIdx.x == 0) blockSums[blockIdx.x] = lds[0];
}

__global__ void k_scanB(const int* __restrict__ blockSums, int* __restrict__ blockOff,
                        int nblocks) {
    if (threadIdx.x == 0 && blockIdx.x == 0) {
        int run = 0;
        for (int b = 0; b < nblocks; ++b) { blockOff[b] = run; run += blockSums[b]; }
        blockOff[nblocks] = run;
    }
}

__global__ __launch_bounds__(1024) void k_scanC(const int* __restrict__ degD,
                                                const int* __restrict__ blockOff,
                                                int* __restrict__ row_ptr,
                                                int* __restrict__ cursor) {
    __shared__ int lds[1024];
    int i = blockIdx.x * 1024 + threadIdx.x;
    int v = (i < N_NODES) ? degD[i] : 0;
    lds[threadIdx.x] = v;
    __syncthreads();
    for (int s = 1; s < 1024; s <<= 1) {      // inclusive Hillis-Steele
        int t = (threadIdx.x >= (unsigned)s) ? lds[threadIdx.x - s] : 0;
        __syncthreads();
        lds[threadIdx.x] += t;
        __syncthreads();
    }
    if (i < N_NODES) {
        int excl = lds[threadIdx.x] - v + blockOff[blockIdx.x];
        row_ptr[i] = excl;
        cursor[i]  = excl;
    }
    if (i == 0) row_ptr[N_NODES] = blockOff[gridDim.x];
}

__global__ __launch_bounds__(256) void k_place(const int* __restrict__ src,
                                               const int* __restrict__ dst,
                                               int* __restrict__ cursor,
                                               int* __restrict__ ssrc) {
    int e = blockIdx.x * 256 + threadIdx.x;
    if (e < N_EDGES) {
        int d = dst[e];
        int pos = atomicAdd(&cursor[d], 1);
        ssrc[pos] = src[e];
    }
}

// ---------------- GEMM1: h_scaled = (X @ W1) * normS ----------------

__global__ __launch_bounds__(128) void k_gemm1(const float* __restrict__ X,
                                               const float* __restrict__ W1,
                                               const float* __restrict__ normS,
                                               float* __restrict__ out) {
    __shared__ float w[IN_DIM * HID];   // 32 KB
    __shared__ float f[4 * IN_DIM];
    for (int i = threadIdx.x; i < IN_DIM * HID; i += 128) w[i] = W1[i];
    __syncthreads();
    const int j = threadIdx.x;
    for (int g = blockIdx.x; g < N_NODES / 4; g += gridDim.x) {
        int r0 = g * 4;
        for (int i = threadIdx.x; i < 4 * IN_DIM; i += 128)
            f[i] = X[(size_t)r0 * IN_DIM + i];
        __syncthreads();
        float a0 = 0.f, a1 = 0.f, a2 = 0.f, a3 = 0.f;
        for (int k = 0; k < IN_DIM; ++k) {
            float wv = w[k * HID + j];
            a0 += f[0 * IN_DIM + k] * wv;
            a1 += f[1 * IN_DIM + k] * wv;
            a2 += f[2 * IN_DIM + k] * wv;
            a3 += f[3 * IN_DIM + k] * wv;
        }
        out[(size_t)(r0 + 0) * HID + j] = a0 * normS[r0 + 0];
        out[(size_t)(r0 + 1) * HID + j] = a1 * normS[r0 + 1];
        out[(size_t)(r0 + 2) * HID + j] = a2 * normS[r0 + 2];
        out[(size_t)(r0 + 3) * HID + j] = a3 * normS[r0 + 3];
        __syncthreads();
    }
}

// ---------------- GEMM2: h_scaled2 = (h1 @ W2) * normS ----------------

__global__ __launch_bounds__(128) void k_gemm2(const float* __restrict__ X,
                                               const float* __restrict__ W2,
                                               const float* __restrict__ normS,
                                               float* __restrict__ out) {
    __shared__ float w[HID * HID];      // 64 KB
    __shared__ float f[4 * HID];
    for (int i = threadIdx.x; i < HID * HID; i += 128) w[i] = W2[i];
    __syncthreads();
    const int j = threadIdx.x;
    for (int g = blockIdx.x; g < N_NODES / 4; g += gridDim.x) {
        int r0 = g * 4;
        for (int i = threadIdx.x; i < 4 * HID; i += 128)
            f[i] = X[(size_t)r0 * HID + i];
        __syncthreads();
        float a0 = 0.f, a1 = 0.f, a2 = 0.f, a3 = 0.f;
        for (int k = 0; k < HID; ++k) {
            float wv = w[k * HID + j];
            a0 += f[0 * HID + k] * wv;
            a1 += f[1 * HID + k] * wv;
            a2 += f[2 * HID + k] * wv;
            a3 += f[3 * HID + k] * wv;
        }
        out[(size_t)(r0 + 0) * HID + j] = a0 * normS[r0 + 0];
        out[(size_t)(r0 + 1) * HID + j] = a1 * normS[r0 + 1];
        out[(size_t)(r0 + 2) * HID + j] = a2 * normS[r0 + 2];
        out[(size_t)(r0 + 3) * HID + j] = a3 * normS[r0 + 3];
        __syncthreads();
    }
}

// ---------------- CSR aggregation + norm + bias + relu ----------------

__global__ __launch_bounds__(256) void k_agg(const float* __restrict__ hs,
                                             const int* __restrict__ row_ptr,
                                             const int* __restrict__ ssrc,
                                             const float* __restrict__ normD,
                                             const float* __restrict__ bias,
                                             float* __restrict__ out,
                                             float* __restrict__ keys) {
    int node = blockIdx.x * 2 + (threadIdx.x >> 7);
    int ch = threadIdx.x & 127;
    if (node >= N_NODES) return;
    int beg = row_ptr[node], end = row_ptr[node + 1];
    float acc = 0.f;
    #pragma unroll 4
    for (int e = beg; e < end; ++e)
        acc += hs[(size_t)ssrc[e] * HID + ch];
    float v = fmaxf(acc * normD[node] + bias[ch], 0.f);
    out[(size_t)node * HID + ch] = v;
    if (keys != nullptr && ch == HID - 1) keys[node] = v;
}

// ---------------- top-K per graph: bitonic sort of (key desc, idx asc) ----------------

__global__ __launch_bounds__(1024) void k_topk(const float* __restrict__ keys,
                                               int* __restrict__ topk_idx) {
    __shared__ unsigned long long arr[SORTN];   // 128 KB
    const int b = blockIdx.x;
    const float* kb = keys + b * NPER;
    for (int i = threadIdx.x; i < SORTN; i += 1024) {
        unsigned long long c;
        if (i < NPER) {
            unsigned u = __float_as_uint(kb[i]);
            unsigned s = (u & 0x80000000u) ? ~u : (u | 0x80000000u); // ascending map
            unsigned d = ~s;                                        // descending
            c = ((unsigned long long)d << 32) | (unsigned)i;
        } else {
            c = 0xFFFFFFFFFFFFFFFFull;  // sorts last
        }
        arr[i] = c;
    }
    __syncthreads();
    for (int k = 2; k <= SORTN; k <<= 1) {
        for (int jj = k >> 1; jj > 0; jj >>= 1) {
            for (int i = threadIdx.x; i < SORTN; i += 1024) {
                int ixj = i ^ jj;
                if (ixj > i) {
                    unsigned long long a = arr[i], c2 = arr[ixj];
                    bool up = ((i & k) == 0);
                    if (up ? (a > c2) : (a < c2)) { arr[i] = c2; arr[ixj] = a; }
                }
            }
            __syncthreads();
        }
    }
    for (int i = threadIdx.x; i < TOPK; i += 1024)
        topk_idx[b * TOPK + i] = (int)(arr[i] & 0xFFFFFFFFu);
}

// ---------------- output init + final reduction GEMM ----------------

__global__ void k_outinit(const float* __restrict__ b3, float* __restrict__ out) {
    int i = threadIdx.x;
    if (i < BATCH * NCLS) out[i] = b3[i % NCLS];
}

#define KPB 100   // top-k rows per block

__global__ __launch_bounds__(128) void k_final(const float* __restrict__ h2,
                                               const int* __restrict__ topk_idx,
                                               const float* __restrict__ W3,
                                               float* __restrict__ out) {
    __shared__ float red[128 * NCLS];
    const int b = blockIdx.x / (TOPK / KPB);
    const int chunk = blockIdx.x % (TOPK / KPB);
    const int j = threadIdx.x;
    float acc[NCLS];
    #pragma unroll
    for (int c = 0; c < NCLS; ++c) acc[c] = 0.f;
    const int k0 = chunk * KPB;
    for (int k = k0; k < k0 + KPB; ++k) {
        int node = b * NPER + topk_idx[b * TOPK + k];
        float h = h2[(size_t)node * HID + j];
        const float* wrow = W3 + (size_t)(k * HID + j) * NCLS;
        #pragma unroll
        for (int c = 0; c < NCLS; ++c) acc[c] += h * wrow[c];
    }
    #pragma unroll
    for (int c = 0; c < NCLS; ++c) red[j * NCLS + c] = acc[c];
    __syncthreads();
    for (int s = 64; s > 0; s >>= 1) {
        if (j < s) {
            #pragma unroll
            for (int c = 0; c < NCLS; ++c) red[j * NCLS + c] += red[(j + s) * NCLS + c];
        }
        __syncthreads();
    }
    if (j < NCLS) atomicAdd(&out[b * NCLS + j], red[j]);
}

// ---------------- launch ----------------

extern "C" void kernel_launch(void* const* d_in, const int* in_sizes, int n_in,
                              void* d_out, int out_size, void* d_ws, size_t ws_size,
                              hipStream_t stream) {
    const float* features = (const float*)d_in[0];
    const int*   src      = (const int*)d_in[1];
    const int*   dst      = (const int*)d_in[2];
    const float* W1       = (const float*)d_in[3];
    const float* b1       = (const float*)d_in[4];
    const float* W2       = (const float*)d_in[5];
    const float* b2       = (const float*)d_in[6];
    const float* W3       = (const float*)d_in[7];
    const float* b3       = (const float*)d_in[8];
    float* out = (float*)d_out;

    char* p = (char*)d_ws;
    auto carve = [&](size_t bytes) -> void* {
        void* r = (void*)p;
        p += (bytes + 511) & ~(size_t)511;
        return r;
    };
    int*   degS      = (int*)carve((size_t)N_NODES * 4);
    int*   degD      = (int*)carve((size_t)N_NODES * 4);
    float* normS     = (float*)carve((size_t)N_NODES * 4);
    float* normD     = (float*)carve((size_t)N_NODES * 4);
    int*   row_ptr   = (int*)carve((size_t)(N_NODES + 1) * 4);
    int*   cursor    = (int*)carve((size_t)N_NODES * 4);
    int*   blockSums = (int*)carve(1024 * 4);
    int*   blockOff  = (int*)carve(1024 * 4);
    int*   ssrc      = (int*)carve((size_t)N_EDGES * 4);
    float* keys      = (float*)carve((size_t)N_NODES * 4);
    int*   topk_idx  = (int*)carve((size_t)BATCH * TOPK * 4);
    float* bufA      = (float*)carve((size_t)N_NODES * HID * 4);
    float* bufB      = (float*)carve((size_t)N_NODES * HID * 4);

    const int EB = (N_EDGES + 255) / 256;
    const int NB = (N_NODES + 255) / 256;
    const int SB = (N_NODES + 1023) / 1024;

    hipMemsetAsync(degS, 0, (size_t)N_NODES * 4, stream);
    hipMemsetAsync(degD, 0, (size_t)N_NODES * 4, stream);

    k_degrees<<<EB, 256, 0, stream>>>(src, dst, degS, degD);
    k_norms<<<NB, 256, 0, stream>>>(degS, degD, normS, normD);
    k_scanA<<<SB, 1024, 0, stream>>>(degD, blockSums);
    k_scanB<<<1, 64, 0, stream>>>(blockSums, blockOff, SB);
    k_scanC<<<SB, 1024, 0, stream>>>(degD, blockOff, row_ptr, cursor);
    k_place<<<EB, 256, 0, stream>>>(src, dst, cursor, ssrc);

    k_gemm1<<<2048, 128, 0, stream>>>(features, W1, normS, bufA);
    k_agg<<<(N_NODES + 1) / 2, 256, 0, stream>>>(bufA, row_ptr, ssrc, normD, b1, bufB, nullptr);
    k_gemm2<<<2048, 128, 0, stream>>>(bufB, W2, normS, bufA);
    k_agg<<<(N_NODES + 1) / 2, 256, 0, stream>>>(bufA, row_ptr, ssrc, normD, b2, bufB, keys);

    k_topk<<<BATCH, 1024, 0, stream>>>(keys, topk_idx);
    k_outinit<<<1, 256, 0, stream>>>(b3, out);
    k_final<<<BATCH * (TOPK / KPB), 128, 0, stream>>>(bufB, topk_idx, W3, out);
}

// Round 2
// 1048.746 us; speedup vs baseline: 1.2151x; 1.2151x over previous
//
#include <hip/hip_runtime.h>
#include <cstdint>
#include <cstddef>

#define N_NODES 100000
#define N_EDGES 1600000
#define IN_DIM  64
#define HID     128
#define NCLS    18
#define BATCH   8
#define TOPK    5000
#define NPER    12500   // N_NODES / BATCH
#define SORTN   16384   // next pow2 >= NPER
#define SORTC   2048    // LDS-local chunk for hybrid bitonic

// ---------------- degree / norm ----------------

__global__ __launch_bounds__(256) void k_degrees(const int* __restrict__ src,
                                                 const int* __restrict__ dst,
                                                 int* __restrict__ degS,
                                                 int* __restrict__ degD) {
    int e = blockIdx.x * 256 + threadIdx.x;
    if (e < N_EDGES) {
        atomicAdd(&degS[src[e]], 1);
        atomicAdd(&degD[dst[e]], 1);
    }
}

__global__ __launch_bounds__(256) void k_norms(const int* __restrict__ degS,
                                               const int* __restrict__ degD,
                                               float* __restrict__ normS,
                                               float* __restrict__ normD) {
    int i = blockIdx.x * 256 + threadIdx.x;
    if (i < N_NODES) {
        normS[i] = 1.0f / sqrtf((float)max(degS[i], 1));
        normD[i] = 1.0f / sqrtf((float)max(degD[i], 1));
    }
}

// ---------------- exclusive scan of in-degrees (3-kernel) ----------------

__global__ __launch_bounds__(1024) void k_scanA(const int* __restrict__ degD,
                                                int* __restrict__ blockSums) {
    __shared__ int lds[1024];
    int i = blockIdx.x * 1024 + threadIdx.x;
    lds[threadIdx.x] = (i < N_NODES) ? degD[i] : 0;
    __syncthreads();
    for (int s = 512; s > 0; s >>= 1) {
        if (threadIdx.x < s) lds[threadIdx.x] += lds[threadIdx.x + s];
        __syncthreads();
    }
    if (threadIdx.x == 0) blockSums[blockIdx.x] = lds[0];
}

__global__ void k_scanB(const int* __restrict__ blockSums, int* __restrict__ blockOff,
                        int nblocks) {
    if (threadIdx.x == 0 && blockIdx.x == 0) {
        int run = 0;
        for (int b = 0; b < nblocks; ++b) { blockOff[b] = run; run += blockSums[b]; }
        blockOff[nblocks] = run;
    }
}

__global__ __launch_bounds__(1024) void k_scanC(const int* __restrict__ degD,
                                                const int* __restrict__ blockOff,
                                                int* __restrict__ row_ptr,
                                                int* __restrict__ cursor) {
    __shared__ int lds[1024];
    int i = blockIdx.x * 1024 + threadIdx.x;
    int v = (i < N_NODES) ? degD[i] : 0;
    lds[threadIdx.x] = v;
    __syncthreads();
    for (int s = 1; s < 1024; s <<= 1) {      // inclusive Hillis-Steele
        int t = (threadIdx.x >= (unsigned)s) ? lds[threadIdx.x - s] : 0;
        __syncthreads();
        lds[threadIdx.x] += t;
        __syncthreads();
    }
    if (i < N_NODES) {
        int excl = lds[threadIdx.x] - v + blockOff[blockIdx.x];
        row_ptr[i] = excl;
        cursor[i]  = excl;
    }
    if (i == 0) row_ptr[N_NODES] = blockOff[gridDim.x];
}

__global__ __launch_bounds__(256) void k_place(const int* __restrict__ src,
                                               const int* __restrict__ dst,
                                               int* __restrict__ cursor,
                                               int* __restrict__ ssrc) {
    int e = blockIdx.x * 256 + threadIdx.x;
    if (e < N_EDGES) {
        int d = dst[e];
        int pos = atomicAdd(&cursor[d], 1);
        ssrc[pos] = src[e];
    }
}

// ---------------- GEMM1: h_scaled = (X @ W1) * normS ----------------

__global__ __launch_bounds__(128) void k_gemm1(const float* __restrict__ X,
                                               const float* __restrict__ W1,
                                               const float* __restrict__ normS,
                                               float* __restrict__ out) {
    __shared__ float w[IN_DIM * HID];   // 32 KB
    __shared__ float f[4 * IN_DIM];
    for (int i = threadIdx.x; i < IN_DIM * HID; i += 128) w[i] = W1[i];
    __syncthreads();
    const int j = threadIdx.x;
    for (int g = blockIdx.x; g < N_NODES / 4; g += gridDim.x) {
        int r0 = g * 4;
        for (int i = threadIdx.x; i < 4 * IN_DIM; i += 128)
            f[i] = X[(size_t)r0 * IN_DIM + i];
        __syncthreads();
        float a0 = 0.f, a1 = 0.f, a2 = 0.f, a3 = 0.f;
        for (int k = 0; k < IN_DIM; ++k) {
            float wv = w[k * HID + j];
            a0 += f[0 * IN_DIM + k] * wv;
            a1 += f[1 * IN_DIM + k] * wv;
            a2 += f[2 * IN_DIM + k] * wv;
            a3 += f[3 * IN_DIM + k] * wv;
        }
        out[(size_t)(r0 + 0) * HID + j] = a0 * normS[r0 + 0];
        out[(size_t)(r0 + 1) * HID + j] = a1 * normS[r0 + 1];
        out[(size_t)(r0 + 2) * HID + j] = a2 * normS[r0 + 2];
        out[(size_t)(r0 + 3) * HID + j] = a3 * normS[r0 + 3];
        __syncthreads();
    }
}

// ---------------- GEMM2: h_scaled2 = (h1 @ W2) * normS ----------------

__global__ __launch_bounds__(128) void k_gemm2(const float* __restrict__ X,
                                               const float* __restrict__ W2,
                                               const float* __restrict__ normS,
                                               float* __restrict__ out) {
    __shared__ float w[HID * HID];      // 64 KB
    __shared__ float f[4 * HID];
    for (int i = threadIdx.x; i < HID * HID; i += 128) w[i] = W2[i];
    __syncthreads();
    const int j = threadIdx.x;
    for (int g = blockIdx.x; g < N_NODES / 4; g += gridDim.x) {
        int r0 = g * 4;
        for (int i = threadIdx.x; i < 4 * HID; i += 128)
            f[i] = X[(size_t)r0 * HID + i];
        __syncthreads();
        float a0 = 0.f, a1 = 0.f, a2 = 0.f, a3 = 0.f;
        for (int k = 0; k < HID; ++k) {
            float wv = w[k * HID + j];
            a0 += f[0 * HID + k] * wv;
            a1 += f[1 * HID + k] * wv;
            a2 += f[2 * HID + k] * wv;
            a3 += f[3 * HID + k] * wv;
        }
        out[(size_t)(r0 + 0) * HID + j] = a0 * normS[r0 + 0];
        out[(size_t)(r0 + 1) * HID + j] = a1 * normS[r0 + 1];
        out[(size_t)(r0 + 2) * HID + j] = a2 * normS[r0 + 2];
        out[(size_t)(r0 + 3) * HID + j] = a3 * normS[r0 + 3];
        __syncthreads();
    }
}

// ---------------- CSR aggregation + norm + bias + relu ----------------

__global__ __launch_bounds__(256) void k_agg(const float* __restrict__ hs,
                                             const int* __restrict__ row_ptr,
                                             const int* __restrict__ ssrc,
                                             const float* __restrict__ normD,
                                             const float* __restrict__ bias,
                                             float* __restrict__ out,
                                             float* __restrict__ keys) {
    int node = blockIdx.x * 2 + (threadIdx.x >> 7);
    int ch = threadIdx.x & 127;
    if (node >= N_NODES) return;
    int beg = row_ptr[node], end = row_ptr[node + 1];
    float acc = 0.f;
    #pragma unroll 4
    for (int e = beg; e < end; ++e)
        acc += hs[(size_t)ssrc[e] * HID + ch];
    float v = fmaxf(acc * normD[node] + bias[ch], 0.f);
    out[(size_t)node * HID + ch] = v;
    if (keys != nullptr && ch == HID - 1) keys[node] = v;
}

// ---------------- hybrid bitonic top-K ----------------
// Same comparator network as a single-block bitonic sort of SORTN u64 keys
// (desc-mapped key<<32 | local idx), decomposed into LDS-local and global
// passes so the whole GPU participates instead of 8 workgroups.

__global__ __launch_bounds__(256) void k_sort_init(const float* __restrict__ keys,
                                                   unsigned long long* __restrict__ arr) {
    int i = blockIdx.x * 256 + threadIdx.x;          // 0 .. 8*16384-1
    if (i >= BATCH * SORTN) return;
    int g = i >> 14;            // /SORTN
    int l = i & (SORTN - 1);
    unsigned long long c;
    if (l < NPER) {
        unsigned u = __float_as_uint(keys[g * NPER + l]);
        unsigned s = (u & 0x80000000u) ? ~u : (u | 0x80000000u); // ascending map
        unsigned d = ~s;                                         // descending
        c = ((unsigned long long)d << 32) | (unsigned)l;
    } else {
        c = 0xFFFFFFFFFFFFFFFFull;  // sorts last
    }
    arr[i] = c;
}

// stages k = 2 .. SORTC entirely in LDS (one block per SORTC-chunk)
__global__ __launch_bounds__(1024) void k_sort_local_full(unsigned long long* __restrict__ arr) {
    __shared__ unsigned long long lds[SORTC];
    const int base  = blockIdx.x * SORTC;            // flat base into arr
    const int gbase = base & (SORTN - 1);            // base within the graph's array
    lds[threadIdx.x]        = arr[base + threadIdx.x];
    lds[threadIdx.x + 1024] = arr[base + threadIdx.x + 1024];
    __syncthreads();
    for (int k = 2; k <= SORTC; k <<= 1) {
        for (int j = k >> 1; j > 0; j >>= 1) {
            int t = threadIdx.x;                     // SORTC/2 = 1024 CEs
            int i = ((t & ~(j - 1)) << 1) | (t & (j - 1));
            bool up = (((gbase + i) & k) == 0);
            unsigned long long a = lds[i], b = lds[i + j];
            if ((a > b) == up) { lds[i] = b; lds[i + j] = a; }
            __syncthreads();
        }
    }
    arr[base + threadIdx.x]        = lds[threadIdx.x];
    arr[base + threadIdx.x + 1024] = lds[threadIdx.x + 1024];
}

// one global compare-exchange substage (stride j >= SORTC)
__global__ __launch_bounds__(256) void k_sort_global(unsigned long long* __restrict__ arr,
                                                     int k, int j) {
    int tg = blockIdx.x * 256 + threadIdx.x;         // 8 * 8192 CEs
    if (tg >= BATCH * (SORTN / 2)) return;
    int g = tg >> 13;                                // / (SORTN/2)
    int t = tg & (SORTN / 2 - 1);
    int i = ((t & ~(j - 1)) << 1) | (t & (j - 1));
    bool up = ((i & k) == 0);
    unsigned long long* p = arr + (size_t)g * SORTN;
    unsigned long long a = p[i], b = p[i + j];
    if ((a > b) == up) { p[i] = b; p[i + j] = a; }
}

// tail strides j = SORTC/2 .. 1 of stage k, LDS-local per SORTC-chunk
__global__ __launch_bounds__(1024) void k_sort_local_tail(unsigned long long* __restrict__ arr,
                                                          int k) {
    __shared__ unsigned long long lds[SORTC];
    const int base  = blockIdx.x * SORTC;
    const int gbase = base & (SORTN - 1);
    lds[threadIdx.x]        = arr[base + threadIdx.x];
    lds[threadIdx.x + 1024] = arr[base + threadIdx.x + 1024];
    __syncthreads();
    for (int j = SORTC >> 1; j > 0; j >>= 1) {
        int t = threadIdx.x;
        int i = ((t & ~(j - 1)) << 1) | (t & (j - 1));
        bool up = (((gbase + i) & k) == 0);
        unsigned long long a = lds[i], b = lds[i + j];
        if ((a > b) == up) { lds[i] = b; lds[i + j] = a; }
        __syncthreads();
    }
    arr[base + threadIdx.x]        = lds[threadIdx.x];
    arr[base + threadIdx.x + 1024] = lds[threadIdx.x + 1024];
}

__global__ __launch_bounds__(256) void k_sort_emit(const unsigned long long* __restrict__ arr,
                                                   int* __restrict__ topk_idx) {
    int i = blockIdx.x * 256 + threadIdx.x;
    if (i >= BATCH * TOPK) return;
    int b = i / TOPK;
    int k = i - b * TOPK;
    topk_idx[i] = (int)(arr[(size_t)b * SORTN + k] & 0xFFFFFFFFull);
}

// ---------------- output init + final reduction GEMM ----------------

__global__ void k_outinit(const float* __restrict__ b3, float* __restrict__ out) {
    int i = threadIdx.x;
    if (i < BATCH * NCLS) out[i] = b3[i % NCLS];
}

#define KPB 100   // top-k rows per block

__global__ __launch_bounds__(128) void k_final(const float* __restrict__ h2,
                                               const int* __restrict__ topk_idx,
                                               const float* __restrict__ W3,
                                               float* __restrict__ out) {
    __shared__ float red[128 * NCLS];
    const int b = blockIdx.x / (TOPK / KPB);
    const int chunk = blockIdx.x % (TOPK / KPB);
    const int j = threadIdx.x;
    float acc[NCLS];
    #pragma unroll
    for (int c = 0; c < NCLS; ++c) acc[c] = 0.f;
    const int k0 = chunk * KPB;
    for (int k = k0; k < k0 + KPB; ++k) {
        int node = b * NPER + topk_idx[b * TOPK + k];
        float h = h2[(size_t)node * HID + j];
        const float* wrow = W3 + (size_t)(k * HID + j) * NCLS;
        #pragma unroll
        for (int c = 0; c < NCLS; ++c) acc[c] += h * wrow[c];
    }
    #pragma unroll
    for (int c = 0; c < NCLS; ++c) red[j * NCLS + c] = acc[c];
    __syncthreads();
    for (int s = 64; s > 0; s >>= 1) {
        if (j < s) {
            #pragma unroll
            for (int c = 0; c < NCLS; ++c) red[j * NCLS + c] += red[(j + s) * NCLS + c];
        }
        __syncthreads();
    }
    if (j < NCLS) atomicAdd(&out[b * NCLS + j], red[j]);
}

// ---------------- launch ----------------

extern "C" void kernel_launch(void* const* d_in, const int* in_sizes, int n_in,
                              void* d_out, int out_size, void* d_ws, size_t ws_size,
                              hipStream_t stream) {
    const float* features = (const float*)d_in[0];
    const int*   src      = (const int*)d_in[1];
    const int*   dst      = (const int*)d_in[2];
    const float* W1       = (const float*)d_in[3];
    const float* b1       = (const float*)d_in[4];
    const float* W2       = (const float*)d_in[5];
    const float* b2       = (const float*)d_in[6];
    const float* W3       = (const float*)d_in[7];
    const float* b3       = (const float*)d_in[8];
    float* out = (float*)d_out;

    char* p = (char*)d_ws;
    auto carve = [&](size_t bytes) -> void* {
        void* r = (void*)p;
        p += (bytes + 511) & ~(size_t)511;
        return r;
    };
    int*   degS      = (int*)carve((size_t)N_NODES * 4);
    int*   degD      = (int*)carve((size_t)N_NODES * 4);
    float* normS     = (float*)carve((size_t)N_NODES * 4);
    float* normD     = (float*)carve((size_t)N_NODES * 4);
    int*   row_ptr   = (int*)carve((size_t)(N_NODES + 1) * 4);
    int*   cursor    = (int*)carve((size_t)N_NODES * 4);
    int*   blockSums = (int*)carve(1024 * 4);
    int*   blockOff  = (int*)carve(1024 * 4);
    int*   ssrc      = (int*)carve((size_t)N_EDGES * 4);
    float* keys      = (float*)carve((size_t)N_NODES * 4);
    int*   topk_idx  = (int*)carve((size_t)BATCH * TOPK * 4);
    unsigned long long* sortbuf = (unsigned long long*)carve((size_t)BATCH * SORTN * 8);
    float* bufA      = (float*)carve((size_t)N_NODES * HID * 4);
    float* bufB      = (float*)carve((size_t)N_NODES * HID * 4);

    const int EB = (N_EDGES + 255) / 256;
    const int NB = (N_NODES + 255) / 256;
    const int SB = (N_NODES + 1023) / 1024;

    hipMemsetAsync(degS, 0, (size_t)N_NODES * 4, stream);
    hipMemsetAsync(degD, 0, (size_t)N_NODES * 4, stream);

    k_degrees<<<EB, 256, 0, stream>>>(src, dst, degS, degD);
    k_norms<<<NB, 256, 0, stream>>>(degS, degD, normS, normD);
    k_scanA<<<SB, 1024, 0, stream>>>(degD, blockSums);
    k_scanB<<<1, 64, 0, stream>>>(blockSums, blockOff, SB);
    k_scanC<<<SB, 1024, 0, stream>>>(degD, blockOff, row_ptr, cursor);
    k_place<<<EB, 256, 0, stream>>>(src, dst, cursor, ssrc);

    k_gemm1<<<2048, 128, 0, stream>>>(features, W1, normS, bufA);
    k_agg<<<(N_NODES + 1) / 2, 256, 0, stream>>>(bufA, row_ptr, ssrc, normD, b1, bufB, nullptr);
    k_gemm2<<<2048, 128, 0, stream>>>(bufB, W2, normS, bufA);
    k_agg<<<(N_NODES + 1) / 2, 256, 0, stream>>>(bufA, row_ptr, ssrc, normD, b2, bufB, keys);

    // hybrid bitonic full sort (same network as the old single-block version)
    const int NCHUNK = BATCH * SORTN / SORTC;          // 64
    const int GCE    = (BATCH * (SORTN / 2) + 255) / 256; // 256 blocks
    k_sort_init<<<(BATCH * SORTN + 255) / 256, 256, 0, stream>>>(keys, sortbuf);
    k_sort_local_full<<<NCHUNK, 1024, 0, stream>>>(sortbuf);
    // k = 4096
    k_sort_global<<<GCE, 256, 0, stream>>>(sortbuf, 4096, 2048);
    k_sort_local_tail<<<NCHUNK, 1024, 0, stream>>>(sortbuf, 4096);
    // k = 8192
    k_sort_global<<<GCE, 256, 0, stream>>>(sortbuf, 8192, 4096);
    k_sort_global<<<GCE, 256, 0, stream>>>(sortbuf, 8192, 2048);
    k_sort_local_tail<<<NCHUNK, 1024, 0, stream>>>(sortbuf, 8192);
    // k = 16384
    k_sort_global<<<GCE, 256, 0, stream>>>(sortbuf, 16384, 8192);
    k_sort_global<<<GCE, 256, 0, stream>>>(sortbuf, 16384, 4096);
    k_sort_global<<<GCE, 256, 0, stream>>>(sortbuf, 16384, 2048);
    k_sort_local_tail<<<NCHUNK, 1024, 0, stream>>>(sortbuf, 16384);
    k_sort_emit<<<(BATCH * TOPK + 255) / 256, 256, 0, stream>>>(sortbuf, topk_idx);

    k_outinit<<<1, 256, 0, stream>>>(b3, out);
    k_final<<<BATCH * (TOPK / KPB), 128, 0, stream>>>(bufB, topk_idx, W3, out);
}

// Round 3
// 788.304 us; speedup vs baseline: 1.6165x; 1.3304x over previous
//
#include <hip/hip_runtime.h>
#include <cstdint>
#include <cstddef>

#define N_NODES 100000
#define N_EDGES 1600000
#define IN_DIM  64
#define HID     128
#define NCLS    18
#define BATCH   8
#define TOPK    5000
#define NPER    12500   // N_NODES / BATCH
#define SORTN   16384   // next pow2 >= NPER
#define SORTC   2048    // LDS-local chunk for hybrid bitonic

// ---------------- degree / norm ----------------

__global__ __launch_bounds__(256) void k_degrees(const int* __restrict__ src,
                                                 const int* __restrict__ dst,
                                                 int* __restrict__ degS,
                                                 int* __restrict__ degD) {
    int e = blockIdx.x * 256 + threadIdx.x;
    if (e < N_EDGES) {
        atomicAdd(&degS[src[e]], 1);
        atomicAdd(&degD[dst[e]], 1);
    }
}

__global__ __launch_bounds__(256) void k_norms(const int* __restrict__ degS,
                                               const int* __restrict__ degD,
                                               float* __restrict__ normS,
                                               float* __restrict__ normD) {
    int i = blockIdx.x * 256 + threadIdx.x;
    if (i < N_NODES) {
        normS[i] = 1.0f / sqrtf((float)max(degS[i], 1));
        normD[i] = 1.0f / sqrtf((float)max(degD[i], 1));
    }
}

// ---------------- exclusive scan of in-degrees (3-kernel) ----------------

__global__ __launch_bounds__(1024) void k_scanA(const int* __restrict__ degD,
                                                int* __restrict__ blockSums) {
    __shared__ int lds[1024];
    int i = blockIdx.x * 1024 + threadIdx.x;
    lds[threadIdx.x] = (i < N_NODES) ? degD[i] : 0;
    __syncthreads();
    for (int s = 512; s > 0; s >>= 1) {
        if (threadIdx.x < s) lds[threadIdx.x] += lds[threadIdx.x + s];
        __syncthreads();
    }
    if (threadIdx.x == 0) blockSums[blockIdx.x] = lds[0];
}

__global__ void k_scanB(const int* __restrict__ blockSums, int* __restrict__ blockOff,
                        int nblocks) {
    if (threadIdx.x == 0 && blockIdx.x == 0) {
        int run = 0;
        for (int b = 0; b < nblocks; ++b) { blockOff[b] = run; run += blockSums[b]; }
        blockOff[nblocks] = run;
    }
}

__global__ __launch_bounds__(1024) void k_scanC(const int* __restrict__ degD,
                                                const int* __restrict__ blockOff,
                                                int* __restrict__ row_ptr,
                                                int* __restrict__ cursor) {
    __shared__ int lds[1024];
    int i = blockIdx.x * 1024 + threadIdx.x;
    int v = (i < N_NODES) ? degD[i] : 0;
    lds[threadIdx.x] = v;
    __syncthreads();
    for (int s = 1; s < 1024; s <<= 1) {      // inclusive Hillis-Steele
        int t = (threadIdx.x >= (unsigned)s) ? lds[threadIdx.x - s] : 0;
        __syncthreads();
        lds[threadIdx.x] += t;
        __syncthreads();
    }
    if (i < N_NODES) {
        int excl = lds[threadIdx.x] - v + blockOff[blockIdx.x];
        row_ptr[i] = excl;
        cursor[i]  = excl;
    }
    if (i == 0) row_ptr[N_NODES] = blockOff[gridDim.x];
}

__global__ __launch_bounds__(256) void k_place(const int* __restrict__ src,
                                               const int* __restrict__ dst,
                                               int* __restrict__ cursor,
                                               int* __restrict__ ssrc) {
    int e = blockIdx.x * 256 + threadIdx.x;
    if (e < N_EDGES) {
        int d = dst[e];
        int pos = atomicAdd(&cursor[d], 1);
        ssrc[pos] = src[e];
    }
}

// ---------------- register-tiled GEMM: out = (X @ W) * normS ----------------
// BM=64 rows x BN=128 cols per block, 256 threads, each thread 8x4 outputs.
// K streamed in BK=32 chunks. LDS ~25.6 KB -> ~6 blocks/CU.

#define BMT 64
#define BKT 32

template<int KDIM>
__global__ __launch_bounds__(256) void k_gemm_rt(const float* __restrict__ X,
                                                 const float* __restrict__ W,
                                                 const float* __restrict__ normS,
                                                 float* __restrict__ out) {
    __shared__ float xs[BMT][BKT + 4];     // 64 x 36 floats, row stride 144 B (16B-aligned)
    __shared__ float ws[BKT * HID];        // 32 x 128

    const int tid = threadIdx.x;
    const int tx = tid & 31;               // col group: cols tx*4 .. tx*4+3
    const int ty = tid >> 5;               // row group: rows ty*8 .. ty*8+7
    const int col0 = tx * 4;
    const int row0 = ty * 8;
    const int rt = blockIdx.x * BMT;

    float acc[8][4];
    #pragma unroll
    for (int r = 0; r < 8; ++r)
        #pragma unroll
        for (int c = 0; c < 4; ++c) acc[r][c] = 0.f;

    for (int k0 = 0; k0 < KDIM; k0 += BKT) {
        __syncthreads();
        // stage W chunk: rows k0..k0+31 of W (contiguous 4096 floats)
        {
            const float4* wsrc = (const float4*)(W + (size_t)k0 * HID);
            #pragma unroll
            for (int i = tid; i < BKT * HID / 4; i += 256)
                ((float4*)ws)[i] = wsrc[i];
        }
        // stage X chunk: 64 rows x 32 k, float4 loads + float4 LDS writes
        {
            #pragma unroll
            for (int i = tid; i < BMT * BKT / 4; i += 256) {
                int row = i >> 3;          // 8 float4 per row
                int kq  = i & 7;
                int gr  = rt + row;
                float4 v = make_float4(0.f, 0.f, 0.f, 0.f);
                if (gr < N_NODES)
                    v = *(const float4*)(X + (size_t)gr * KDIM + k0 + kq * 4);
                *(float4*)&xs[row][kq * 4] = v;
            }
        }
        __syncthreads();

        #pragma unroll 4
        for (int k = 0; k < BKT; ++k) {
            float4 b = *(const float4*)&ws[k * HID + col0];
            float a[8];
            #pragma unroll
            for (int r = 0; r < 8; ++r) a[r] = xs[row0 + r][k];
            #pragma unroll
            for (int r = 0; r < 8; ++r) {
                acc[r][0] += a[r] * b.x;
                acc[r][1] += a[r] * b.y;
                acc[r][2] += a[r] * b.z;
                acc[r][3] += a[r] * b.w;
            }
        }
    }

    #pragma unroll
    for (int r = 0; r < 8; ++r) {
        int gr = rt + row0 + r;
        if (gr < N_NODES) {
            float s = normS[gr];
            float4 o = make_float4(acc[r][0] * s, acc[r][1] * s, acc[r][2] * s, acc[r][3] * s);
            *(float4*)(out + (size_t)gr * HID + col0) = o;
        }
    }
}

// ---------------- CSR aggregation + norm + bias + relu (float4) ----------------

__global__ __launch_bounds__(256) void k_agg(const float* __restrict__ hs,
                                             const int* __restrict__ row_ptr,
                                             const int* __restrict__ ssrc,
                                             const float* __restrict__ normD,
                                             const float* __restrict__ bias,
                                             float* __restrict__ out,
                                             float* __restrict__ keys) {
    int node = blockIdx.x * 8 + (threadIdx.x >> 5);
    int lane = threadIdx.x & 31;           // covers channels lane*4 .. lane*4+3
    if (node >= N_NODES) return;
    int beg = row_ptr[node], end = row_ptr[node + 1];
    float4 acc = make_float4(0.f, 0.f, 0.f, 0.f);
    int e = beg;
    for (; e + 1 < end; e += 2) {
        int s0 = ssrc[e], s1 = ssrc[e + 1];
        float4 v0 = ((const float4*)(hs + (size_t)s0 * HID))[lane];
        float4 v1 = ((const float4*)(hs + (size_t)s1 * HID))[lane];
        acc.x += v0.x; acc.y += v0.y; acc.z += v0.z; acc.w += v0.w;
        acc.x += v1.x; acc.y += v1.y; acc.z += v1.z; acc.w += v1.w;
    }
    if (e < end) {
        int s0 = ssrc[e];
        float4 v0 = ((const float4*)(hs + (size_t)s0 * HID))[lane];
        acc.x += v0.x; acc.y += v0.y; acc.z += v0.z; acc.w += v0.w;
    }
    float nrm = normD[node];
    float4 bb = *(const float4*)(bias + lane * 4);
    float4 o;
    o.x = fmaxf(acc.x * nrm + bb.x, 0.f);
    o.y = fmaxf(acc.y * nrm + bb.y, 0.f);
    o.z = fmaxf(acc.z * nrm + bb.z, 0.f);
    o.w = fmaxf(acc.w * nrm + bb.w, 0.f);
    *(float4*)(out + (size_t)node * HID + lane * 4) = o;
    if (keys != nullptr && lane == 31) keys[node] = o.w;   // channel 127
}

// ---------------- hybrid bitonic top-K ----------------

__global__ __launch_bounds__(256) void k_sort_init(const float* __restrict__ keys,
                                                   unsigned long long* __restrict__ arr) {
    int i = blockIdx.x * 256 + threadIdx.x;          // 0 .. 8*16384-1
    if (i >= BATCH * SORTN) return;
    int g = i >> 14;            // /SORTN
    int l = i & (SORTN - 1);
    unsigned long long c;
    if (l < NPER) {
        unsigned u = __float_as_uint(keys[g * NPER + l]);
        unsigned s = (u & 0x80000000u) ? ~u : (u | 0x80000000u); // ascending map
        unsigned d = ~s;                                         // descending
        c = ((unsigned long long)d << 32) | (unsigned)l;
    } else {
        c = 0xFFFFFFFFFFFFFFFFull;  // sorts last
    }
    arr[i] = c;
}

// stages k = 2 .. SORTC entirely in LDS (one block per SORTC-chunk)
__global__ __launch_bounds__(1024) void k_sort_local_full(unsigned long long* __restrict__ arr) {
    __shared__ unsigned long long lds[SORTC];
    const int base  = blockIdx.x * SORTC;            // flat base into arr
    const int gbase = base & (SORTN - 1);            // base within the graph's array
    lds[threadIdx.x]        = arr[base + threadIdx.x];
    lds[threadIdx.x + 1024] = arr[base + threadIdx.x + 1024];
    __syncthreads();
    for (int k = 2; k <= SORTC; k <<= 1) {
        for (int j = k >> 1; j > 0; j >>= 1) {
            int t = threadIdx.x;                     // SORTC/2 = 1024 CEs
            int i = ((t & ~(j - 1)) << 1) | (t & (j - 1));
            bool up = (((gbase + i) & k) == 0);
            unsigned long long a = lds[i], b = lds[i + j];
            if ((a > b) == up) { lds[i] = b; lds[i + j] = a; }
            __syncthreads();
        }
    }
    arr[base + threadIdx.x]        = lds[threadIdx.x];
    arr[base + threadIdx.x + 1024] = lds[threadIdx.x + 1024];
}

// one global compare-exchange substage (stride j >= SORTC)
__global__ __launch_bounds__(256) void k_sort_global(unsigned long long* __restrict__ arr,
                                                     int k, int j) {
    int tg = blockIdx.x * 256 + threadIdx.x;         // 8 * 8192 CEs
    if (tg >= BATCH * (SORTN / 2)) return;
    int g = tg >> 13;                                // / (SORTN/2)
    int t = tg & (SORTN / 2 - 1);
    int i = ((t & ~(j - 1)) << 1) | (t & (j - 1));
    bool up = ((i & k) == 0);
    unsigned long long* p = arr + (size_t)g * SORTN;
    unsigned long long a = p[i], b = p[i + j];
    if ((a > b) == up) { p[i] = b; p[i + j] = a; }
}

// tail strides j = SORTC/2 .. 1 of stage k, LDS-local per SORTC-chunk
__global__ __launch_bounds__(1024) void k_sort_local_tail(unsigned long long* __restrict__ arr,
                                                          int k) {
    __shared__ unsigned long long lds[SORTC];
    const int base  = blockIdx.x * SORTC;
    const int gbase = base & (SORTN - 1);
    lds[threadIdx.x]        = arr[base + threadIdx.x];
    lds[threadIdx.x + 1024] = arr[base + threadIdx.x + 1024];
    __syncthreads();
    for (int j = SORTC >> 1; j > 0; j >>= 1) {
        int t = threadIdx.x;
        int i = ((t & ~(j - 1)) << 1) | (t & (j - 1));
        bool up = (((gbase + i) & k) == 0);
        unsigned long long a = lds[i], b = lds[i + j];
        if ((a > b) == up) { lds[i] = b; lds[i + j] = a; }
        __syncthreads();
    }
    arr[base + threadIdx.x]        = lds[threadIdx.x];
    arr[base + threadIdx.x + 1024] = lds[threadIdx.x + 1024];
}

__global__ __launch_bounds__(256) void k_sort_emit(const unsigned long long* __restrict__ arr,
                                                   int* __restrict__ topk_idx) {
    int i = blockIdx.x * 256 + threadIdx.x;
    if (i >= BATCH * TOPK) return;
    int b = i / TOPK;
    int k = i - b * TOPK;
    topk_idx[i] = (int)(arr[(size_t)b * SORTN + k] & 0xFFFFFFFFull);
}

// ---------------- output init + final reduction GEMM ----------------

__global__ void k_outinit(const float* __restrict__ b3, float* __restrict__ out) {
    int i = threadIdx.x;
    if (i < BATCH * NCLS) out[i] = b3[i % NCLS];
}

#define KPB 100   // top-k rows per block

__global__ __launch_bounds__(128) void k_final(const float* __restrict__ h2,
                                               const int* __restrict__ topk_idx,
                                               const float* __restrict__ W3,
                                               float* __restrict__ out) {
    __shared__ float red[128 * NCLS];
    const int b = blockIdx.x / (TOPK / KPB);
    const int chunk = blockIdx.x % (TOPK / KPB);
    const int j = threadIdx.x;
    float acc[NCLS];
    #pragma unroll
    for (int c = 0; c < NCLS; ++c) acc[c] = 0.f;
    const int k0 = chunk * KPB;
    for (int k = k0; k < k0 + KPB; ++k) {
        int node = b * NPER + topk_idx[b * TOPK + k];
        float h = h2[(size_t)node * HID + j];
        const float* wrow = W3 + (size_t)(k * HID + j) * NCLS;
        #pragma unroll
        for (int c = 0; c < NCLS; ++c) acc[c] += h * wrow[c];
    }
    #pragma unroll
    for (int c = 0; c < NCLS; ++c) red[j * NCLS + c] = acc[c];
    __syncthreads();
    for (int s = 64; s > 0; s >>= 1) {
        if (j < s) {
            #pragma unroll
            for (int c = 0; c < NCLS; ++c) red[j * NCLS + c] += red[(j + s) * NCLS + c];
        }
        __syncthreads();
    }
    if (j < NCLS) atomicAdd(&out[b * NCLS + j], red[j]);
}

// ---------------- launch ----------------

extern "C" void kernel_launch(void* const* d_in, const int* in_sizes, int n_in,
                              void* d_out, int out_size, void* d_ws, size_t ws_size,
                              hipStream_t stream) {
    const float* features = (const float*)d_in[0];
    const int*   src      = (const int*)d_in[1];
    const int*   dst      = (const int*)d_in[2];
    const float* W1       = (const float*)d_in[3];
    const float* b1       = (const float*)d_in[4];
    const float* W2       = (const float*)d_in[5];
    const float* b2       = (const float*)d_in[6];
    const float* W3       = (const float*)d_in[7];
    const float* b3       = (const float*)d_in[8];
    float* out = (float*)d_out;

    char* p = (char*)d_ws;
    auto carve = [&](size_t bytes) -> void* {
        void* r = (void*)p;
        p += (bytes + 511) & ~(size_t)511;
        return r;
    };
    int*   degS      = (int*)carve((size_t)N_NODES * 4);
    int*   degD      = (int*)carve((size_t)N_NODES * 4);
    float* normS     = (float*)carve((size_t)N_NODES * 4);
    float* normD     = (float*)carve((size_t)N_NODES * 4);
    int*   row_ptr   = (int*)carve((size_t)(N_NODES + 1) * 4);
    int*   cursor    = (int*)carve((size_t)N_NODES * 4);
    int*   blockSums = (int*)carve(1024 * 4);
    int*   blockOff  = (int*)carve(1024 * 4);
    int*   ssrc      = (int*)carve((size_t)N_EDGES * 4);
    float* keys      = (float*)carve((size_t)N_NODES * 4);
    int*   topk_idx  = (int*)carve((size_t)BATCH * TOPK * 4);
    unsigned long long* sortbuf = (unsigned long long*)carve((size_t)BATCH * SORTN * 8);
    float* bufA      = (float*)carve((size_t)N_NODES * HID * 4);
    float* bufB      = (float*)carve((size_t)N_NODES * HID * 4);

    const int EB = (N_EDGES + 255) / 256;
    const int NB = (N_NODES + 255) / 256;
    const int SB = (N_NODES + 1023) / 1024;
    const int GB = (N_NODES + BMT - 1) / BMT;   // 1563 gemm tiles

    hipMemsetAsync(degS, 0, (size_t)N_NODES * 4, stream);
    hipMemsetAsync(degD, 0, (size_t)N_NODES * 4, stream);

    k_degrees<<<EB, 256, 0, stream>>>(src, dst, degS, degD);
    k_norms<<<NB, 256, 0, stream>>>(degS, degD, normS, normD);
    k_scanA<<<SB, 1024, 0, stream>>>(degD, blockSums);
    k_scanB<<<1, 64, 0, stream>>>(blockSums, blockOff, SB);
    k_scanC<<<SB, 1024, 0, stream>>>(degD, blockOff, row_ptr, cursor);
    k_place<<<EB, 256, 0, stream>>>(src, dst, cursor, ssrc);

    k_gemm_rt<IN_DIM><<<GB, 256, 0, stream>>>(features, W1, normS, bufA);
    k_agg<<<(N_NODES + 7) / 8, 256, 0, stream>>>(bufA, row_ptr, ssrc, normD, b1, bufB, nullptr);
    k_gemm_rt<HID><<<GB, 256, 0, stream>>>(bufB, W2, normS, bufA);
    k_agg<<<(N_NODES + 7) / 8, 256, 0, stream>>>(bufA, row_ptr, ssrc, normD, b2, bufB, keys);

    // hybrid bitonic full sort (same network as a single-block bitonic sort)
    const int NCHUNK = BATCH * SORTN / SORTC;          // 64
    const int GCE    = (BATCH * (SORTN / 2) + 255) / 256; // 256 blocks
    k_sort_init<<<(BATCH * SORTN + 255) / 256, 256, 0, stream>>>(keys, sortbuf);
    k_sort_local_full<<<NCHUNK, 1024, 0, stream>>>(sortbuf);
    // k = 4096
    k_sort_global<<<GCE, 256, 0, stream>>>(sortbuf, 4096, 2048);
    k_sort_local_tail<<<NCHUNK, 1024, 0, stream>>>(sortbuf, 4096);
    // k = 8192
    k_sort_global<<<GCE, 256, 0, stream>>>(sortbuf, 8192, 4096);
    k_sort_global<<<GCE, 256, 0, stream>>>(sortbuf, 8192, 2048);
    k_sort_local_tail<<<NCHUNK, 1024, 0, stream>>>(sortbuf, 8192);
    // k = 16384
    k_sort_global<<<GCE, 256, 0, stream>>>(sortbuf, 16384, 8192);
    k_sort_global<<<GCE, 256, 0, stream>>>(sortbuf, 16384, 4096);
    k_sort_global<<<GCE, 256, 0, stream>>>(sortbuf, 16384, 2048);
    k_sort_local_tail<<<NCHUNK, 1024, 0, stream>>>(sortbuf, 16384);
    k_sort_emit<<<(BATCH * TOPK + 255) / 256, 256, 0, stream>>>(sortbuf, topk_idx);

    k_outinit<<<1, 256, 0, stream>>>(b3, out);
    k_final<<<BATCH * (TOPK / KPB), 128, 0, stream>>>(bufB, topk_idx, W3, out);
}

// Round 4
// 721.328 us; speedup vs baseline: 1.7666x; 1.0929x over previous
//
#include <hip/hip_runtime.h>
#include <cstdint>
#include <cstddef>

#define N_NODES 100000
#define N_EDGES 1600000
#define IN_DIM  64
#define HID     128
#define NCLS    18
#define BATCH   8
#define TOPK    5000
#define NPER    12500   // N_NODES / BATCH
#define SORTN   16384   // next pow2 >= NPER
#define SORTC   2048    // LDS-local chunk for hybrid bitonic

#define BSHIFT  9                      // bucket = dst >> 9 (512 nodes per bucket)
#define BNODES  (1 << BSHIFT)
#define NBUCK   ((N_NODES + BNODES - 1) / BNODES)   // 196
#define CHUNK   8192                   // edges per block in k_bin

// ---------------- degree / norm ----------------

__global__ __launch_bounds__(256) void k_degrees(const int* __restrict__ src,
                                                 const int* __restrict__ dst,
                                                 int* __restrict__ degS,
                                                 int* __restrict__ degD) {
    int e = blockIdx.x * 256 + threadIdx.x;
    if (e < N_EDGES) {
        atomicAdd(&degS[src[e]], 1);
        atomicAdd(&degD[dst[e]], 1);
    }
}

__global__ __launch_bounds__(256) void k_norms(const int* __restrict__ degS,
                                               const int* __restrict__ degD,
                                               float* __restrict__ normS,
                                               float* __restrict__ normD) {
    int i = blockIdx.x * 256 + threadIdx.x;
    if (i < N_NODES) {
        normS[i] = 1.0f / sqrtf((float)max(degS[i], 1));
        normD[i] = 1.0f / sqrtf((float)max(degD[i], 1));
    }
}

// ---------------- exclusive scan of in-degrees (3-kernel) ----------------

__global__ __launch_bounds__(1024) void k_scanA(const int* __restrict__ degD,
                                                int* __restrict__ blockSums) {
    __shared__ int lds[1024];
    int i = blockIdx.x * 1024 + threadIdx.x;
    lds[threadIdx.x] = (i < N_NODES) ? degD[i] : 0;
    __syncthreads();
    for (int s = 512; s > 0; s >>= 1) {
        if (threadIdx.x < s) lds[threadIdx.x] += lds[threadIdx.x + s];
        __syncthreads();
    }
    if (threadIdx.x == 0) blockSums[blockIdx.x] = lds[0];
}

__global__ void k_scanB(const int* __restrict__ blockSums, int* __restrict__ blockOff,
                        int nblocks) {
    if (threadIdx.x == 0 && blockIdx.x == 0) {
        int run = 0;
        for (int b = 0; b < nblocks; ++b) { blockOff[b] = run; run += blockSums[b]; }
        blockOff[nblocks] = run;
    }
}

__global__ __launch_bounds__(1024) void k_scanC(const int* __restrict__ degD,
                                                const int* __restrict__ blockOff,
                                                int* __restrict__ row_ptr) {
    __shared__ int lds[1024];
    int i = blockIdx.x * 1024 + threadIdx.x;
    int v = (i < N_NODES) ? degD[i] : 0;
    lds[threadIdx.x] = v;
    __syncthreads();
    for (int s = 1; s < 1024; s <<= 1) {      // inclusive Hillis-Steele
        int t = (threadIdx.x >= (unsigned)s) ? lds[threadIdx.x - s] : 0;
        __syncthreads();
        lds[threadIdx.x] += t;
        __syncthreads();
    }
    if (i < N_NODES) {
        int excl = lds[threadIdx.x] - v + blockOff[blockIdx.x];
        row_ptr[i] = excl;
    }
    if (i == 0) row_ptr[N_NODES] = blockOff[gridDim.x];
}

// ---------------- binned CSR build (replaces scattered k_place) ----------------

__global__ void k_binit(const int* __restrict__ row_ptr, int* __restrict__ bucketCursor) {
    int b = blockIdx.x * 256 + threadIdx.x;
    if (b < NBUCK) bucketCursor[b] = row_ptr[b << BSHIFT];
}

// Phase 1: per-block bucket counting + run reservation + packed scatter.
// Each block owns CHUNK edges; writes land in ~CHUNK/NBUCK-long runs per bucket.
__global__ __launch_bounds__(256) void k_bin(const int* __restrict__ src,
                                             const int* __restrict__ dst,
                                             int* __restrict__ bucketCursor,
                                             unsigned* __restrict__ binbuf) {
    __shared__ int cnt[NBUCK];
    __shared__ int gbase[NBUCK];
    __shared__ int cnt2[NBUCK];
    const int base = blockIdx.x * CHUNK;
    const int end  = min(base + CHUNK, N_EDGES);
    for (int b = threadIdx.x; b < NBUCK; b += 256) { cnt[b] = 0; cnt2[b] = 0; }
    __syncthreads();
    for (int e = base + threadIdx.x; e < end; e += 256)
        atomicAdd(&cnt[dst[e] >> BSHIFT], 1);
    __syncthreads();
    for (int b = threadIdx.x; b < NBUCK; b += 256)
        if (cnt[b] > 0) gbase[b] = atomicAdd(&bucketCursor[b], cnt[b]);
    __syncthreads();
    for (int e = base + threadIdx.x; e < end; e += 256) {
        int d = dst[e];
        int b = d >> BSHIFT;
        int off = atomicAdd(&cnt2[b], 1);
        unsigned packed = ((unsigned)(d & (BNODES - 1)) << 17) | (unsigned)src[e];
        binbuf[gbase[b] + off] = packed;
    }
}

// Phase 2: one block per bucket; LDS cursors; ssrc writes confined to the
// bucket's contiguous CSR window (single CU -> full-line writebacks).
__global__ __launch_bounds__(256) void k_scatter(const unsigned* __restrict__ binbuf,
                                                 const int* __restrict__ row_ptr,
                                                 int* __restrict__ ssrc) {
    __shared__ int cur[BNODES];
    const int nodeBase = blockIdx.x << BSHIFT;
    for (int t = threadIdx.x; t < BNODES; t += 256) {
        int node = nodeBase + t;
        cur[t] = (node < N_NODES) ? row_ptr[node] : 0;
    }
    __syncthreads();
    const int beg = row_ptr[nodeBase];
    const int end = row_ptr[min(nodeBase + BNODES, N_NODES)];
    for (int e = beg + threadIdx.x; e < end; e += 256) {
        unsigned v = binbuf[e];
        int dl = (int)(v >> 17);
        int s  = (int)(v & 0x1FFFFu);
        int pos = atomicAdd(&cur[dl], 1);
        ssrc[pos] = s;
    }
}

// ---------------- register-tiled GEMM: out = (X @ W) * normS ----------------

#define BMT 64
#define BKT 32

template<int KDIM>
__global__ __launch_bounds__(256) void k_gemm_rt(const float* __restrict__ X,
                                                 const float* __restrict__ W,
                                                 const float* __restrict__ normS,
                                                 float* __restrict__ out) {
    __shared__ float xs[BMT][BKT + 4];     // 64 x 36 floats
    __shared__ float ws[BKT * HID];        // 32 x 128

    const int tid = threadIdx.x;
    const int tx = tid & 31;
    const int ty = tid >> 5;
    const int col0 = tx * 4;
    const int row0 = ty * 8;
    const int rt = blockIdx.x * BMT;

    float acc[8][4];
    #pragma unroll
    for (int r = 0; r < 8; ++r)
        #pragma unroll
        for (int c = 0; c < 4; ++c) acc[r][c] = 0.f;

    for (int k0 = 0; k0 < KDIM; k0 += BKT) {
        __syncthreads();
        {
            const float4* wsrc = (const float4*)(W + (size_t)k0 * HID);
            #pragma unroll
            for (int i = tid; i < BKT * HID / 4; i += 256)
                ((float4*)ws)[i] = wsrc[i];
        }
        {
            #pragma unroll
            for (int i = tid; i < BMT * BKT / 4; i += 256) {
                int row = i >> 3;
                int kq  = i & 7;
                int gr  = rt + row;
                float4 v = make_float4(0.f, 0.f, 0.f, 0.f);
                if (gr < N_NODES)
                    v = *(const float4*)(X + (size_t)gr * KDIM + k0 + kq * 4);
                *(float4*)&xs[row][kq * 4] = v;
            }
        }
        __syncthreads();

        #pragma unroll 4
        for (int k = 0; k < BKT; ++k) {
            float4 b = *(const float4*)&ws[k * HID + col0];
            float a[8];
            #pragma unroll
            for (int r = 0; r < 8; ++r) a[r] = xs[row0 + r][k];
            #pragma unroll
            for (int r = 0; r < 8; ++r) {
                acc[r][0] += a[r] * b.x;
                acc[r][1] += a[r] * b.y;
                acc[r][2] += a[r] * b.z;
                acc[r][3] += a[r] * b.w;
            }
        }
    }

    #pragma unroll
    for (int r = 0; r < 8; ++r) {
        int gr = rt + row0 + r;
        if (gr < N_NODES) {
            float s = normS[gr];
            float4 o = make_float4(acc[r][0] * s, acc[r][1] * s, acc[r][2] * s, acc[r][3] * s);
            *(float4*)(out + (size_t)gr * HID + col0) = o;
        }
    }
}

// ---------------- CSR aggregation + norm + bias + relu (float4) ----------------

__global__ __launch_bounds__(256) void k_agg(const float* __restrict__ hs,
                                             const int* __restrict__ row_ptr,
                                             const int* __restrict__ ssrc,
                                             const float* __restrict__ normD,
                                             const float* __restrict__ bias,
                                             float* __restrict__ out,
                                             float* __restrict__ keys) {
    int node = blockIdx.x * 8 + (threadIdx.x >> 5);
    int lane = threadIdx.x & 31;           // covers channels lane*4 .. lane*4+3
    if (node >= N_NODES) return;
    int beg = row_ptr[node], end = row_ptr[node + 1];
    float4 acc = make_float4(0.f, 0.f, 0.f, 0.f);
    int e = beg;
    for (; e + 1 < end; e += 2) {
        int s0 = ssrc[e], s1 = ssrc[e + 1];
        float4 v0 = ((const float4*)(hs + (size_t)s0 * HID))[lane];
        float4 v1 = ((const float4*)(hs + (size_t)s1 * HID))[lane];
        acc.x += v0.x; acc.y += v0.y; acc.z += v0.z; acc.w += v0.w;
        acc.x += v1.x; acc.y += v1.y; acc.z += v1.z; acc.w += v1.w;
    }
    if (e < end) {
        int s0 = ssrc[e];
        float4 v0 = ((const float4*)(hs + (size_t)s0 * HID))[lane];
        acc.x += v0.x; acc.y += v0.y; acc.z += v0.z; acc.w += v0.w;
    }
    float nrm = normD[node];
    float4 bb = *(const float4*)(bias + lane * 4);
    float4 o;
    o.x = fmaxf(acc.x * nrm + bb.x, 0.f);
    o.y = fmaxf(acc.y * nrm + bb.y, 0.f);
    o.z = fmaxf(acc.z * nrm + bb.z, 0.f);
    o.w = fmaxf(acc.w * nrm + bb.w, 0.f);
    *(float4*)(out + (size_t)node * HID + lane * 4) = o;
    if (keys != nullptr && lane == 31) keys[node] = o.w;   // channel 127
}

// ---------------- hybrid bitonic top-K ----------------

__global__ __launch_bounds__(256) void k_sort_init(const float* __restrict__ keys,
                                                   unsigned long long* __restrict__ arr) {
    int i = blockIdx.x * 256 + threadIdx.x;          // 0 .. 8*16384-1
    if (i >= BATCH * SORTN) return;
    int g = i >> 14;            // /SORTN
    int l = i & (SORTN - 1);
    unsigned long long c;
    if (l < NPER) {
        unsigned u = __float_as_uint(keys[g * NPER + l]);
        unsigned s = (u & 0x80000000u) ? ~u : (u | 0x80000000u); // ascending map
        unsigned d = ~s;                                         // descending
        c = ((unsigned long long)d << 32) | (unsigned)l;
    } else {
        c = 0xFFFFFFFFFFFFFFFFull;  // sorts last
    }
    arr[i] = c;
}

// stages k = 2 .. SORTC entirely in LDS (one block per SORTC-chunk)
__global__ __launch_bounds__(1024) void k_sort_local_full(unsigned long long* __restrict__ arr) {
    __shared__ unsigned long long lds[SORTC];
    const int base  = blockIdx.x * SORTC;            // flat base into arr
    const int gbase = base & (SORTN - 1);            // base within the graph's array
    lds[threadIdx.x]        = arr[base + threadIdx.x];
    lds[threadIdx.x + 1024] = arr[base + threadIdx.x + 1024];
    __syncthreads();
    for (int k = 2; k <= SORTC; k <<= 1) {
        for (int j = k >> 1; j > 0; j >>= 1) {
            int t = threadIdx.x;                     // SORTC/2 = 1024 CEs
            int i = ((t & ~(j - 1)) << 1) | (t & (j - 1));
            bool up = (((gbase + i) & k) == 0);
            unsigned long long a = lds[i], b = lds[i + j];
            if ((a > b) == up) { lds[i] = b; lds[i + j] = a; }
            __syncthreads();
        }
    }
    arr[base + threadIdx.x]        = lds[threadIdx.x];
    arr[base + threadIdx.x + 1024] = lds[threadIdx.x + 1024];
}

// one global compare-exchange substage (stride j >= SORTC)
__global__ __launch_bounds__(256) void k_sort_global(unsigned long long* __restrict__ arr,
                                                     int k, int j) {
    int tg = blockIdx.x * 256 + threadIdx.x;         // 8 * 8192 CEs
    if (tg >= BATCH * (SORTN / 2)) return;
    int g = tg >> 13;                                // / (SORTN/2)
    int t = tg & (SORTN / 2 - 1);
    int i = ((t & ~(j - 1)) << 1) | (t & (j - 1));
    bool up = ((i & k) == 0);
    unsigned long long* p = arr + (size_t)g * SORTN;
    unsigned long long a = p[i], b = p[i + j];
    if ((a > b) == up) { p[i] = b; p[i + j] = a; }
}

// tail strides j = SORTC/2 .. 1 of stage k, LDS-local per SORTC-chunk
__global__ __launch_bounds__(1024) void k_sort_local_tail(unsigned long long* __restrict__ arr,
                                                          int k) {
    __shared__ unsigned long long lds[SORTC];
    const int base  = blockIdx.x * SORTC;
    const int gbase = base & (SORTN - 1);
    lds[threadIdx.x]        = arr[base + threadIdx.x];
    lds[threadIdx.x + 1024] = arr[base + threadIdx.x + 1024];
    __syncthreads();
    for (int j = SORTC >> 1; j > 0; j >>= 1) {
        int t = threadIdx.x;
        int i = ((t & ~(j - 1)) << 1) | (t & (j - 1));
        bool up = (((gbase + i) & k) == 0);
        unsigned long long a = lds[i], b = lds[i + j];
        if ((a > b) == up) { lds[i] = b; lds[i + j] = a; }
        __syncthreads();
    }
    arr[base + threadIdx.x]        = lds[threadIdx.x];
    arr[base + threadIdx.x + 1024] = lds[threadIdx.x + 1024];
}

__global__ __launch_bounds__(256) void k_sort_emit(const unsigned long long* __restrict__ arr,
                                                   int* __restrict__ topk_idx) {
    int i = blockIdx.x * 256 + threadIdx.x;
    if (i >= BATCH * TOPK) return;
    int b = i / TOPK;
    int k = i - b * TOPK;
    topk_idx[i] = (int)(arr[(size_t)b * SORTN + k] & 0xFFFFFFFFull);
}

// ---------------- output init + final reduction GEMM ----------------

__global__ void k_outinit(const float* __restrict__ b3, float* __restrict__ out) {
    int i = threadIdx.x;
    if (i < BATCH * NCLS) out[i] = b3[i % NCLS];
}

#define KPB 100   // top-k rows per block

__global__ __launch_bounds__(128) void k_final(const float* __restrict__ h2,
                                               const int* __restrict__ topk_idx,
                                               const float* __restrict__ W3,
                                               float* __restrict__ out) {
    __shared__ float red[128 * NCLS];
    const int b = blockIdx.x / (TOPK / KPB);
    const int chunk = blockIdx.x % (TOPK / KPB);
    const int j = threadIdx.x;
    float acc[NCLS];
    #pragma unroll
    for (int c = 0; c < NCLS; ++c) acc[c] = 0.f;
    const int k0 = chunk * KPB;
    for (int k = k0; k < k0 + KPB; ++k) {
        int node = b * NPER + topk_idx[b * TOPK + k];
        float h = h2[(size_t)node * HID + j];
        const float* wrow = W3 + (size_t)(k * HID + j) * NCLS;
        #pragma unroll
        for (int c = 0; c < NCLS; ++c) acc[c] += h * wrow[c];
    }
    #pragma unroll
    for (int c = 0; c < NCLS; ++c) red[j * NCLS + c] = acc[c];
    __syncthreads();
    for (int s = 64; s > 0; s >>= 1) {
        if (j < s) {
            #pragma unroll
            for (int c = 0; c < NCLS; ++c) red[j * NCLS + c] += red[(j + s) * NCLS + c];
        }
        __syncthreads();
    }
    if (j < NCLS) atomicAdd(&out[b * NCLS + j], red[j]);
}

// ---------------- launch ----------------

extern "C" void kernel_launch(void* const* d_in, const int* in_sizes, int n_in,
                              void* d_out, int out_size, void* d_ws, size_t ws_size,
                              hipStream_t stream) {
    const float* features = (const float*)d_in[0];
    const int*   src      = (const int*)d_in[1];
    const int*   dst      = (const int*)d_in[2];
    const float* W1       = (const float*)d_in[3];
    const float* b1       = (const float*)d_in[4];
    const float* W2       = (const float*)d_in[5];
    const float* b2       = (const float*)d_in[6];
    const float* W3       = (const float*)d_in[7];
    const float* b3       = (const float*)d_in[8];
    float* out = (float*)d_out;

    char* p = (char*)d_ws;
    auto carve = [&](size_t bytes) -> void* {
        void* r = (void*)p;
        p += (bytes + 511) & ~(size_t)511;
        return r;
    };
    int*   degS      = (int*)carve((size_t)N_NODES * 4);
    int*   degD      = (int*)carve((size_t)N_NODES * 4);
    float* normS     = (float*)carve((size_t)N_NODES * 4);
    float* normD     = (float*)carve((size_t)N_NODES * 4);
    int*   row_ptr   = (int*)carve((size_t)(N_NODES + 1) * 4);
    int*   bucketCursor = (int*)carve((size_t)NBUCK * 4);
    int*   blockSums = (int*)carve(1024 * 4);
    int*   blockOff  = (int*)carve(1024 * 4);
    int*   ssrc      = (int*)carve((size_t)N_EDGES * 4);
    unsigned* binbuf = (unsigned*)carve((size_t)N_EDGES * 4);
    float* keys      = (float*)carve((size_t)N_NODES * 4);
    int*   topk_idx  = (int*)carve((size_t)BATCH * TOPK * 4);
    unsigned long long* sortbuf = (unsigned long long*)carve((size_t)BATCH * SORTN * 8);
    float* bufA      = (float*)carve((size_t)N_NODES * HID * 4);
    float* bufB      = (float*)carve((size_t)N_NODES * HID * 4);

    const int EB = (N_EDGES + 255) / 256;
    const int NB = (N_NODES + 255) / 256;
    const int SB = (N_NODES + 1023) / 1024;
    const int GB = (N_NODES + BMT - 1) / BMT;   // gemm tiles
    const int BB = (N_EDGES + CHUNK - 1) / CHUNK; // bin blocks (196)

    hipMemsetAsync(degS, 0, (size_t)N_NODES * 4, stream);
    hipMemsetAsync(degD, 0, (size_t)N_NODES * 4, stream);

    k_degrees<<<EB, 256, 0, stream>>>(src, dst, degS, degD);
    k_norms<<<NB, 256, 0, stream>>>(degS, degD, normS, normD);
    k_scanA<<<SB, 1024, 0, stream>>>(degD, blockSums);
    k_scanB<<<1, 64, 0, stream>>>(blockSums, blockOff, SB);
    k_scanC<<<SB, 1024, 0, stream>>>(degD, blockOff, row_ptr);

    k_binit<<<1, 256, 0, stream>>>(row_ptr, bucketCursor);
    k_bin<<<BB, 256, 0, stream>>>(src, dst, bucketCursor, binbuf);
    k_scatter<<<NBUCK, 256, 0, stream>>>(binbuf, row_ptr, ssrc);

    k_gemm_rt<IN_DIM><<<GB, 256, 0, stream>>>(features, W1, normS, bufA);
    k_agg<<<(N_NODES + 7) / 8, 256, 0, stream>>>(bufA, row_ptr, ssrc, normD, b1, bufB, nullptr);
    k_gemm_rt<HID><<<GB, 256, 0, stream>>>(bufB, W2, normS, bufA);
    k_agg<<<(N_NODES + 7) / 8, 256, 0, stream>>>(bufA, row_ptr, ssrc, normD, b2, bufB, keys);

    // hybrid bitonic full sort (same network as a single-block bitonic sort)
    const int NCHUNK = BATCH * SORTN / SORTC;          // 64
    const int GCE    = (BATCH * (SORTN / 2) + 255) / 256; // 256 blocks
    k_sort_init<<<(BATCH * SORTN + 255) / 256, 256, 0, stream>>>(keys, sortbuf);
    k_sort_local_full<<<NCHUNK, 1024, 0, stream>>>(sortbuf);
    // k = 4096
    k_sort_global<<<GCE, 256, 0, stream>>>(sortbuf, 4096, 2048);
    k_sort_local_tail<<<NCHUNK, 1024, 0, stream>>>(sortbuf, 4096);
    // k = 8192
    k_sort_global<<<GCE, 256, 0, stream>>>(sortbuf, 8192, 4096);
    k_sort_global<<<GCE, 256, 0, stream>>>(sortbuf, 8192, 2048);
    k_sort_local_tail<<<NCHUNK, 1024, 0, stream>>>(sortbuf, 8192);
    // k = 16384
    k_sort_global<<<GCE, 256, 0, stream>>>(sortbuf, 16384, 8192);
    k_sort_global<<<GCE, 256, 0, stream>>>(sortbuf, 16384, 4096);
    k_sort_global<<<GCE, 256, 0, stream>>>(sortbuf, 16384, 2048);
    k_sort_local_tail<<<NCHUNK, 1024, 0, stream>>>(sortbuf, 16384);
    k_sort_emit<<<(BATCH * TOPK + 255) / 256, 256, 0, stream>>>(sortbuf, topk_idx);

    k_outinit<<<1, 256, 0, stream>>>(b3, out);
    k_final<<<BATCH * (TOPK / KPB), 128, 0, stream>>>(bufB, topk_idx, W3, out);
}

// Round 5
// 650.274 us; speedup vs baseline: 1.9597x; 1.1093x over previous
//
#include <hip/hip_runtime.h>
#include <cstdint>
#include <cstddef>

#define N_NODES 100000
#define N_EDGES 1600000
#define IN_DIM  64
#define HID     128
#define NCLS    18
#define BATCH   8
#define TOPK    5000
#define NPER    12500   // N_NODES / BATCH
#define SORTN   16384   // next pow2 >= NPER
#define SORTC   2048    // LDS-local chunk for hybrid bitonic

#define BSHIFT  9                      // bucket = node >> 9 (512 nodes per bucket)
#define BNODES  (1 << BSHIFT)
#define NBUCK   ((N_NODES + BNODES - 1) / BNODES)   // 196
#define CHUNK   8192                   // edges per block in binning kernels

// ---------------- bucket-level counting (LDS-privatized) ----------------

__global__ __launch_bounds__(256) void k_bcount(const int* __restrict__ src,
                                                const int* __restrict__ dst,
                                                int* __restrict__ bcntS,
                                                int* __restrict__ bcntD) {
    __shared__ int cs[NBUCK], cd[NBUCK];
    for (int b = threadIdx.x; b < NBUCK; b += 256) { cs[b] = 0; cd[b] = 0; }
    __syncthreads();
    const int base = blockIdx.x * CHUNK;
    const int end  = min(base + CHUNK, N_EDGES);
    for (int e = base + threadIdx.x; e < end; e += 256) {
        atomicAdd(&cs[src[e] >> BSHIFT], 1);
        atomicAdd(&cd[dst[e] >> BSHIFT], 1);
    }
    __syncthreads();
    for (int b = threadIdx.x; b < NBUCK; b += 256) {
        if (cs[b]) atomicAdd(&bcntS[b], cs[b]);
        if (cd[b]) atomicAdd(&bcntD[b], cd[b]);
    }
}

__global__ void k_bscan(const int* __restrict__ bcntS, const int* __restrict__ bcntD,
                        int* __restrict__ baseS, int* __restrict__ baseD,
                        int* __restrict__ curS, int* __restrict__ curD) {
    if (threadIdx.x == 0 && blockIdx.x == 0) {
        int rs = 0, rd = 0;
        for (int b = 0; b < NBUCK; ++b) {
            baseS[b] = rs; curS[b] = rs; rs += bcntS[b];
            baseD[b] = rd; curD[b] = rd; rd += bcntD[b];
        }
        baseS[NBUCK] = rs; baseD[NBUCK] = rd;
    }
}

// ---------------- binned edge placement ----------------

// bin (local_dst<<17 | src) by dst bucket; writes land in ~42-long runs.
__global__ __launch_bounds__(256) void k_bin(const int* __restrict__ src,
                                             const int* __restrict__ dst,
                                             int* __restrict__ cursorD,
                                             unsigned* __restrict__ binbuf) {
    __shared__ int cnt[NBUCK];
    __shared__ int gbase[NBUCK];
    __shared__ int cnt2[NBUCK];
    const int base = blockIdx.x * CHUNK;
    const int end  = min(base + CHUNK, N_EDGES);
    for (int b = threadIdx.x; b < NBUCK; b += 256) { cnt[b] = 0; cnt2[b] = 0; }
    __syncthreads();
    for (int e = base + threadIdx.x; e < end; e += 256)
        atomicAdd(&cnt[dst[e] >> BSHIFT], 1);
    __syncthreads();
    for (int b = threadIdx.x; b < NBUCK; b += 256)
        if (cnt[b] > 0) gbase[b] = atomicAdd(&cursorD[b], cnt[b]);
    __syncthreads();
    for (int e = base + threadIdx.x; e < end; e += 256) {
        int d = dst[e];
        int b = d >> BSHIFT;
        int off = atomicAdd(&cnt2[b], 1);
        unsigned packed = ((unsigned)(d & (BNODES - 1)) << 17) | (unsigned)src[e];
        binbuf[gbase[b] + off] = packed;
    }
}

// bin local_src by src bucket (for out-degree histogram)
__global__ __launch_bounds__(256) void k_bin_src(const int* __restrict__ src,
                                                 int* __restrict__ cursorS,
                                                 unsigned* __restrict__ sbin) {
    __shared__ int cnt[NBUCK];
    __shared__ int gbase[NBUCK];
    __shared__ int cnt2[NBUCK];
    const int base = blockIdx.x * CHUNK;
    const int end  = min(base + CHUNK, N_EDGES);
    for (int b = threadIdx.x; b < NBUCK; b += 256) { cnt[b] = 0; cnt2[b] = 0; }
    __syncthreads();
    for (int e = base + threadIdx.x; e < end; e += 256)
        atomicAdd(&cnt[src[e] >> BSHIFT], 1);
    __syncthreads();
    for (int b = threadIdx.x; b < NBUCK; b += 256)
        if (cnt[b] > 0) gbase[b] = atomicAdd(&cursorS[b], cnt[b]);
    __syncthreads();
    for (int e = base + threadIdx.x; e < end; e += 256) {
        int s = src[e];
        int b = s >> BSHIFT;
        int off = atomicAdd(&cnt2[b], 1);
        sbin[gbase[b] + off] = (unsigned)(s & (BNODES - 1));
    }
}

// ---------------- per-bucket histograms -> norms (+ row_ptr from degD) ----------------

__global__ __launch_bounds__(256) void k_histS(const unsigned* __restrict__ sbin,
                                               const int* __restrict__ baseS,
                                               float* __restrict__ normS) {
    __shared__ int cnt[BNODES];
    for (int t = threadIdx.x; t < BNODES; t += 256) cnt[t] = 0;
    __syncthreads();
    const int beg = baseS[blockIdx.x], end = baseS[blockIdx.x + 1];
    for (int e = beg + threadIdx.x; e < end; e += 256)
        atomicAdd(&cnt[sbin[e]], 1);
    __syncthreads();
    const int nodeBase = blockIdx.x << BSHIFT;
    for (int t = threadIdx.x; t < BNODES; t += 256) {
        int node = nodeBase + t;
        if (node < N_NODES)
            normS[node] = 1.0f / sqrtf((float)max(cnt[t], 1));
    }
}

// histogram local dst + in-LDS exclusive scan -> normD and row_ptr directly
__global__ __launch_bounds__(256) void k_histD(const unsigned* __restrict__ binbuf,
                                               const int* __restrict__ baseD,
                                               float* __restrict__ normD,
                                               int* __restrict__ row_ptr) {
    __shared__ int cnt[BNODES];
    __shared__ int tmp[BNODES];
    for (int t = threadIdx.x; t < BNODES; t += 256) cnt[t] = 0;
    __syncthreads();
    const int beg = baseD[blockIdx.x], end = baseD[blockIdx.x + 1];
    for (int e = beg + threadIdx.x; e < end; e += 256)
        atomicAdd(&cnt[binbuf[e] >> 17], 1);
    __syncthreads();
    const int nodeBase = blockIdx.x << BSHIFT;
    // write norms, keep counts for scan
    for (int t = threadIdx.x; t < BNODES; t += 256) {
        int node = nodeBase + t;
        if (node < N_NODES)
            normD[node] = 1.0f / sqrtf((float)max(cnt[t], 1));
    }
    // inclusive Hillis-Steele scan over cnt[512]
    for (int s = 1; s < BNODES; s <<= 1) {
        for (int t = threadIdx.x; t < BNODES; t += 256)
            tmp[t] = (t >= s) ? cnt[t - s] + cnt[t] : cnt[t];
        __syncthreads();
        for (int t = threadIdx.x; t < BNODES; t += 256) cnt[t] = tmp[t];
        __syncthreads();
    }
    for (int t = threadIdx.x; t < BNODES; t += 256) {
        int node = nodeBase + t;
        if (node < N_NODES)
            row_ptr[node] = beg + ((t == 0) ? 0 : cnt[t - 1]);   // exclusive
    }
    if (blockIdx.x == 0 && threadIdx.x == 0) row_ptr[N_NODES] = N_EDGES;
}

// Phase 2: one block per bucket; LDS cursors; ssrc writes confined to the
// bucket's contiguous CSR window (single CU -> full-line writebacks).
__global__ __launch_bounds__(256) void k_scatter(const unsigned* __restrict__ binbuf,
                                                 const int* __restrict__ row_ptr,
                                                 int* __restrict__ ssrc) {
    __shared__ int cur[BNODES];
    const int nodeBase = blockIdx.x << BSHIFT;
    for (int t = threadIdx.x; t < BNODES; t += 256) {
        int node = nodeBase + t;
        cur[t] = (node < N_NODES) ? row_ptr[node] : 0;
    }
    __syncthreads();
    const int beg = row_ptr[nodeBase];
    const int end = row_ptr[min(nodeBase + BNODES, N_NODES)];
    for (int e = beg + threadIdx.x; e < end; e += 256) {
        unsigned v = binbuf[e];
        int dl = (int)(v >> 17);
        int s  = (int)(v & 0x1FFFFu);
        int pos = atomicAdd(&cur[dl], 1);
        ssrc[pos] = s;
    }
}

// ---------------- register-tiled GEMM: out = (X @ W) * normS ----------------

#define BMT 64
#define BKT 32

template<int KDIM>
__global__ __launch_bounds__(256) void k_gemm_rt(const float* __restrict__ X,
                                                 const float* __restrict__ W,
                                                 const float* __restrict__ normS,
                                                 float* __restrict__ out) {
    __shared__ float xs[BMT][BKT + 4];     // 64 x 36 floats
    __shared__ float ws[BKT * HID];        // 32 x 128

    const int tid = threadIdx.x;
    const int tx = tid & 31;
    const int ty = tid >> 5;
    const int col0 = tx * 4;
    const int row0 = ty * 8;
    const int rt = blockIdx.x * BMT;

    float acc[8][4];
    #pragma unroll
    for (int r = 0; r < 8; ++r)
        #pragma unroll
        for (int c = 0; c < 4; ++c) acc[r][c] = 0.f;

    for (int k0 = 0; k0 < KDIM; k0 += BKT) {
        __syncthreads();
        {
            const float4* wsrc = (const float4*)(W + (size_t)k0 * HID);
            #pragma unroll
            for (int i = tid; i < BKT * HID / 4; i += 256)
                ((float4*)ws)[i] = wsrc[i];
        }
        {
            #pragma unroll
            for (int i = tid; i < BMT * BKT / 4; i += 256) {
                int row = i >> 3;
                int kq  = i & 7;
                int gr  = rt + row;
                float4 v = make_float4(0.f, 0.f, 0.f, 0.f);
                if (gr < N_NODES)
                    v = *(const float4*)(X + (size_t)gr * KDIM + k0 + kq * 4);
                *(float4*)&xs[row][kq * 4] = v;
            }
        }
        __syncthreads();

        #pragma unroll 4
        for (int k = 0; k < BKT; ++k) {
            float4 b = *(const float4*)&ws[k * HID + col0];
            float a[8];
            #pragma unroll
            for (int r = 0; r < 8; ++r) a[r] = xs[row0 + r][k];
            #pragma unroll
            for (int r = 0; r < 8; ++r) {
                acc[r][0] += a[r] * b.x;
                acc[r][1] += a[r] * b.y;
                acc[r][2] += a[r] * b.z;
                acc[r][3] += a[r] * b.w;
            }
        }
    }

    #pragma unroll
    for (int r = 0; r < 8; ++r) {
        int gr = rt + row0 + r;
        if (gr < N_NODES) {
            float s = normS[gr];
            float4 o = make_float4(acc[r][0] * s, acc[r][1] * s, acc[r][2] * s, acc[r][3] * s);
            *(float4*)(out + (size_t)gr * HID + col0) = o;
        }
    }
}

// ---------------- CSR aggregation + norm + bias + relu (float4) ----------------

__global__ __launch_bounds__(256) void k_agg(const float* __restrict__ hs,
                                             const int* __restrict__ row_ptr,
                                             const int* __restrict__ ssrc,
                                             const float* __restrict__ normD,
                                             const float* __restrict__ bias,
                                             float* __restrict__ out,
                                             float* __restrict__ keys) {
    int node = blockIdx.x * 8 + (threadIdx.x >> 5);
    int lane = threadIdx.x & 31;           // covers channels lane*4 .. lane*4+3
    if (node >= N_NODES) return;
    int beg = row_ptr[node], end = row_ptr[node + 1];
    float4 acc = make_float4(0.f, 0.f, 0.f, 0.f);
    int e = beg;
    for (; e + 1 < end; e += 2) {
        int s0 = ssrc[e], s1 = ssrc[e + 1];
        float4 v0 = ((const float4*)(hs + (size_t)s0 * HID))[lane];
        float4 v1 = ((const float4*)(hs + (size_t)s1 * HID))[lane];
        acc.x += v0.x; acc.y += v0.y; acc.z += v0.z; acc.w += v0.w;
        acc.x += v1.x; acc.y += v1.y; acc.z += v1.z; acc.w += v1.w;
    }
    if (e < end) {
        int s0 = ssrc[e];
        float4 v0 = ((const float4*)(hs + (size_t)s0 * HID))[lane];
        acc.x += v0.x; acc.y += v0.y; acc.z += v0.z; acc.w += v0.w;
    }
    float nrm = normD[node];
    float4 bb = *(const float4*)(bias + lane * 4);
    float4 o;
    o.x = fmaxf(acc.x * nrm + bb.x, 0.f);
    o.y = fmaxf(acc.y * nrm + bb.y, 0.f);
    o.z = fmaxf(acc.z * nrm + bb.z, 0.f);
    o.w = fmaxf(acc.w * nrm + bb.w, 0.f);
    *(float4*)(out + (size_t)node * HID + lane * 4) = o;
    if (keys != nullptr && lane == 31) keys[node] = o.w;   // channel 127
}

// ---------------- hybrid bitonic top-K ----------------

__global__ __launch_bounds__(256) void k_sort_init(const float* __restrict__ keys,
                                                   unsigned long long* __restrict__ arr) {
    int i = blockIdx.x * 256 + threadIdx.x;          // 0 .. 8*16384-1
    if (i >= BATCH * SORTN) return;
    int g = i >> 14;            // /SORTN
    int l = i & (SORTN - 1);
    unsigned long long c;
    if (l < NPER) {
        unsigned u = __float_as_uint(keys[g * NPER + l]);
        unsigned s = (u & 0x80000000u) ? ~u : (u | 0x80000000u); // ascending map
        unsigned d = ~s;                                         // descending
        c = ((unsigned long long)d << 32) | (unsigned)l;
    } else {
        c = 0xFFFFFFFFFFFFFFFFull;  // sorts last
    }
    arr[i] = c;
}

// stages k = 2 .. SORTC entirely in LDS (one block per SORTC-chunk)
__global__ __launch_bounds__(1024) void k_sort_local_full(unsigned long long* __restrict__ arr) {
    __shared__ unsigned long long lds[SORTC];
    const int base  = blockIdx.x * SORTC;            // flat base into arr
    const int gbase = base & (SORTN - 1);            // base within the graph's array
    lds[threadIdx.x]        = arr[base + threadIdx.x];
    lds[threadIdx.x + 1024] = arr[base + threadIdx.x + 1024];
    __syncthreads();
    for (int k = 2; k <= SORTC; k <<= 1) {
        for (int j = k >> 1; j > 0; j >>= 1) {
            int t = threadIdx.x;                     // SORTC/2 = 1024 CEs
            int i = ((t & ~(j - 1)) << 1) | (t & (j - 1));
            bool up = (((gbase + i) & k) == 0);
            unsigned long long a = lds[i], b = lds[i + j];
            if ((a > b) == up) { lds[i] = b; lds[i + j] = a; }
            __syncthreads();
        }
    }
    arr[base + threadIdx.x]        = lds[threadIdx.x];
    arr[base + threadIdx.x + 1024] = lds[threadIdx.x + 1024];
}

// one global compare-exchange substage (stride j >= SORTC)
__global__ __launch_bounds__(256) void k_sort_global(unsigned long long* __restrict__ arr,
                                                     int k, int j) {
    int tg = blockIdx.x * 256 + threadIdx.x;         // 8 * 8192 CEs
    if (tg >= BATCH * (SORTN / 2)) return;
    int g = tg >> 13;                                // / (SORTN/2)
    int t = tg & (SORTN / 2 - 1);
    int i = ((t & ~(j - 1)) << 1) | (t & (j - 1));
    bool up = ((i & k) == 0);
    unsigned long long* p = arr + (size_t)g * SORTN;
    unsigned long long a = p[i], b = p[i + j];
    if ((a > b) == up) { p[i] = b; p[i + j] = a; }
}

// tail strides j = SORTC/2 .. 1 of stage k, LDS-local per SORTC-chunk
__global__ __launch_bounds__(1024) void k_sort_local_tail(unsigned long long* __restrict__ arr,
                                                          int k) {
    __shared__ unsigned long long lds[SORTC];
    const int base  = blockIdx.x * SORTC;
    const int gbase = base & (SORTN - 1);
    lds[threadIdx.x]        = arr[base + threadIdx.x];
    lds[threadIdx.x + 1024] = arr[base + threadIdx.x + 1024];
    __syncthreads();
    for (int j = SORTC >> 1; j > 0; j >>= 1) {
        int t = threadIdx.x;
        int i = ((t & ~(j - 1)) << 1) | (t & (j - 1));
        bool up = (((gbase + i) & k) == 0);
        unsigned long long a = lds[i], b = lds[i + j];
        if ((a > b) == up) { lds[i] = b; lds[i + j] = a; }
        __syncthreads();
    }
    arr[base + threadIdx.x]        = lds[threadIdx.x];
    arr[base + threadIdx.x + 1024] = lds[threadIdx.x + 1024];
}

__global__ __launch_bounds__(256) void k_sort_emit(const unsigned long long* __restrict__ arr,
                                                   int* __restrict__ topk_idx) {
    int i = blockIdx.x * 256 + threadIdx.x;
    if (i >= BATCH * TOPK) return;
    int b = i / TOPK;
    int k = i - b * TOPK;
    topk_idx[i] = (int)(arr[(size_t)b * SORTN + k] & 0xFFFFFFFFull);
}

// ---------------- output init + final reduction GEMM ----------------

__global__ void k_outinit(const float* __restrict__ b3, float* __restrict__ out) {
    int i = threadIdx.x;
    if (i < BATCH * NCLS) out[i] = b3[i % NCLS];
}

#define KPB 100   // top-k rows per block

__global__ __launch_bounds__(128) void k_final(const float* __restrict__ h2,
                                               const int* __restrict__ topk_idx,
                                               const float* __restrict__ W3,
                                               float* __restrict__ out) {
    __shared__ float red[128 * NCLS];
    const int b = blockIdx.x / (TOPK / KPB);
    const int chunk = blockIdx.x % (TOPK / KPB);
    const int j = threadIdx.x;
    float acc[NCLS];
    #pragma unroll
    for (int c = 0; c < NCLS; ++c) acc[c] = 0.f;
    const int k0 = chunk * KPB;
    for (int k = k0; k < k0 + KPB; ++k) {
        int node = b * NPER + topk_idx[b * TOPK + k];
        float h = h2[(size_t)node * HID + j];
        const float* wrow = W3 + (size_t)(k * HID + j) * NCLS;
        #pragma unroll
        for (int c = 0; c < NCLS; ++c) acc[c] += h * wrow[c];
    }
    #pragma unroll
    for (int c = 0; c < NCLS; ++c) red[j * NCLS + c] = acc[c];
    __syncthreads();
    for (int s = 64; s > 0; s >>= 1) {
        if (j < s) {
            #pragma unroll
            for (int c = 0; c < NCLS; ++c) red[j * NCLS + c] += red[(j + s) * NCLS + c];
        }
        __syncthreads();
    }
    if (j < NCLS) atomicAdd(&out[b * NCLS + j], red[j]);
}

// ---------------- launch ----------------

extern "C" void kernel_launch(void* const* d_in, const int* in_sizes, int n_in,
                              void* d_out, int out_size, void* d_ws, size_t ws_size,
                              hipStream_t stream) {
    const float* features = (const float*)d_in[0];
    const int*   src      = (const int*)d_in[1];
    const int*   dst      = (const int*)d_in[2];
    const float* W1       = (const float*)d_in[3];
    const float* b1       = (const float*)d_in[4];
    const float* W2       = (const float*)d_in[5];
    const float* b2       = (const float*)d_in[6];
    const float* W3       = (const float*)d_in[7];
    const float* b3       = (const float*)d_in[8];
    float* out = (float*)d_out;

    char* p = (char*)d_ws;
    auto carve = [&](size_t bytes) -> void* {
        void* r = (void*)p;
        p += (bytes + 511) & ~(size_t)511;
        return r;
    };
    float* normS     = (float*)carve((size_t)N_NODES * 4);
    float* normD     = (float*)carve((size_t)N_NODES * 4);
    int*   row_ptr   = (int*)carve((size_t)(N_NODES + 1) * 4);
    int*   bcntS     = (int*)carve((size_t)NBUCK * 4);
    int*   bcntD     = (int*)carve((size_t)NBUCK * 4);
    int*   baseS     = (int*)carve((size_t)(NBUCK + 1) * 4);
    int*   baseD     = (int*)carve((size_t)(NBUCK + 1) * 4);
    int*   curS      = (int*)carve((size_t)NBUCK * 4);
    int*   curD      = (int*)carve((size_t)NBUCK * 4);
    int*   ssrc      = (int*)carve((size_t)N_EDGES * 4);
    unsigned* binbuf = (unsigned*)carve((size_t)N_EDGES * 4);
    unsigned* sbin   = (unsigned*)carve((size_t)N_EDGES * 4);
    float* keys      = (float*)carve((size_t)N_NODES * 4);
    int*   topk_idx  = (int*)carve((size_t)BATCH * TOPK * 4);
    unsigned long long* sortbuf = (unsigned long long*)carve((size_t)BATCH * SORTN * 8);
    float* bufA      = (float*)carve((size_t)N_NODES * HID * 4);
    float* bufB      = (float*)carve((size_t)N_NODES * HID * 4);

    const int GB = (N_NODES + BMT - 1) / BMT;     // gemm tiles
    const int BB = (N_EDGES + CHUNK - 1) / CHUNK; // bin blocks (196)

    hipMemsetAsync(bcntS, 0, (size_t)NBUCK * 4, stream);
    hipMemsetAsync(bcntD, 0, (size_t)NBUCK * 4, stream);

    // CSR build + degrees/norms, all via bucket binning (no global scatter atomics)
    k_bcount<<<BB, 256, 0, stream>>>(src, dst, bcntS, bcntD);
    k_bscan<<<1, 64, 0, stream>>>(bcntS, bcntD, baseS, baseD, curS, curD);
    k_bin<<<BB, 256, 0, stream>>>(src, dst, curD, binbuf);
    k_bin_src<<<BB, 256, 0, stream>>>(src, curS, sbin);
    k_histS<<<NBUCK, 256, 0, stream>>>(sbin, baseS, normS);
    k_histD<<<NBUCK, 256, 0, stream>>>(binbuf, baseD, normD, row_ptr);
    k_scatter<<<NBUCK, 256, 0, stream>>>(binbuf, row_ptr, ssrc);

    k_gemm_rt<IN_DIM><<<GB, 256, 0, stream>>>(features, W1, normS, bufA);
    k_agg<<<(N_NODES + 7) / 8, 256, 0, stream>>>(bufA, row_ptr, ssrc, normD, b1, bufB, nullptr);
    k_gemm_rt<HID><<<GB, 256, 0, stream>>>(bufB, W2, normS, bufA);
    k_agg<<<(N_NODES + 7) / 8, 256, 0, stream>>>(bufA, row_ptr, ssrc, normD, b2, bufB, keys);

    // hybrid bitonic full sort (same network as a single-block bitonic sort)
    const int NCHUNK = BATCH * SORTN / SORTC;          // 64
    const int GCE    = (BATCH * (SORTN / 2) + 255) / 256; // 256 blocks
    k_sort_init<<<(BATCH * SORTN + 255) / 256, 256, 0, stream>>>(keys, sortbuf);
    k_sort_local_full<<<NCHUNK, 1024, 0, stream>>>(sortbuf);
    // k = 4096
    k_sort_global<<<GCE, 256, 0, stream>>>(sortbuf, 4096, 2048);
    k_sort_local_tail<<<NCHUNK, 1024, 0, stream>>>(sortbuf, 4096);
    // k = 8192
    k_sort_global<<<GCE, 256, 0, stream>>>(sortbuf, 8192, 4096);
    k_sort_global<<<GCE, 256, 0, stream>>>(sortbuf, 8192, 2048);
    k_sort_local_tail<<<NCHUNK, 1024, 0, stream>>>(sortbuf, 8192);
    // k = 16384
    k_sort_global<<<GCE, 256, 0, stream>>>(sortbuf, 16384, 8192);
    k_sort_global<<<GCE, 256, 0, stream>>>(sortbuf, 16384, 4096);
    k_sort_global<<<GCE, 256, 0, stream>>>(sortbuf, 16384, 2048);
    k_sort_local_tail<<<NCHUNK, 1024, 0, stream>>>(sortbuf, 16384);
    k_sort_emit<<<(BATCH * TOPK + 255) / 256, 256, 0, stream>>>(sortbuf, topk_idx);

    k_outinit<<<1, 256, 0, stream>>>(b3, out);
    k_final<<<BATCH * (TOPK / KPB), 128, 0, stream>>>(bufB, topk_idx, W3, out);
}

// Round 6
// 650.100 us; speedup vs baseline: 1.9602x; 1.0003x over previous
//
#include <hip/hip_runtime.h>
#include <cstdint>
#include <cstddef>

#define N_NODES 100000
#define N_EDGES 1600000
#define IN_DIM  64
#define HID     128
#define NCLS    18
#define BATCH   8
#define TOPK    5000
#define NPER    12500   // N_NODES / BATCH
#define SORTN   16384   // next pow2 >= NPER
#define SORTC   2048    // LDS-local chunk for hybrid bitonic

#define BSHIFT  9                      // bucket = node >> 9 (512 nodes per bucket)
#define BNODES  (1 << BSHIFT)
#define NBUCK   ((N_NODES + BNODES - 1) / BNODES)   // 196
#define CHUNK   8192                   // edges per block in binning kernels

// ---------------- bucket-level counting (LDS-privatized) ----------------

__global__ __launch_bounds__(256) void k_bcount(const int* __restrict__ src,
                                                const int* __restrict__ dst,
                                                int* __restrict__ bcntS,
                                                int* __restrict__ bcntD) {
    __shared__ int cs[NBUCK], cd[NBUCK];
    for (int b = threadIdx.x; b < NBUCK; b += 256) { cs[b] = 0; cd[b] = 0; }
    __syncthreads();
    const int base = blockIdx.x * CHUNK;
    const int end  = min(base + CHUNK, N_EDGES);
    for (int e = base + threadIdx.x; e < end; e += 256) {
        atomicAdd(&cs[src[e] >> BSHIFT], 1);
        atomicAdd(&cd[dst[e] >> BSHIFT], 1);
    }
    __syncthreads();
    for (int b = threadIdx.x; b < NBUCK; b += 256) {
        if (cs[b]) atomicAdd(&bcntS[b], cs[b]);
        if (cd[b]) atomicAdd(&bcntD[b], cd[b]);
    }
}

__global__ void k_bscan(const int* __restrict__ bcntS, const int* __restrict__ bcntD,
                        int* __restrict__ baseS, int* __restrict__ baseD,
                        int* __restrict__ curS, int* __restrict__ curD) {
    if (threadIdx.x == 0 && blockIdx.x == 0) {
        int rs = 0, rd = 0;
        for (int b = 0; b < NBUCK; ++b) {
            baseS[b] = rs; curS[b] = rs; rs += bcntS[b];
            baseD[b] = rd; curD[b] = rd; rd += bcntD[b];
        }
        baseS[NBUCK] = rs; baseD[NBUCK] = rd;
    }
}

// ---------------- binned edge placement ----------------

// bin (local_dst<<17 | src) by dst bucket; writes land in ~42-long runs.
__global__ __launch_bounds__(256) void k_bin(const int* __restrict__ src,
                                             const int* __restrict__ dst,
                                             int* __restrict__ cursorD,
                                             unsigned* __restrict__ binbuf) {
    __shared__ int cnt[NBUCK];
    __shared__ int gbase[NBUCK];
    __shared__ int cnt2[NBUCK];
    const int base = blockIdx.x * CHUNK;
    const int end  = min(base + CHUNK, N_EDGES);
    for (int b = threadIdx.x; b < NBUCK; b += 256) { cnt[b] = 0; cnt2[b] = 0; }
    __syncthreads();
    for (int e = base + threadIdx.x; e < end; e += 256)
        atomicAdd(&cnt[dst[e] >> BSHIFT], 1);
    __syncthreads();
    for (int b = threadIdx.x; b < NBUCK; b += 256)
        if (cnt[b] > 0) gbase[b] = atomicAdd(&cursorD[b], cnt[b]);
    __syncthreads();
    for (int e = base + threadIdx.x; e < end; e += 256) {
        int d = dst[e];
        int b = d >> BSHIFT;
        int off = atomicAdd(&cnt2[b], 1);
        unsigned packed = ((unsigned)(d & (BNODES - 1)) << 17) | (unsigned)src[e];
        binbuf[gbase[b] + off] = packed;
    }
}

// bin local_src by src bucket (for out-degree histogram)
__global__ __launch_bounds__(256) void k_bin_src(const int* __restrict__ src,
                                                 int* __restrict__ cursorS,
                                                 unsigned* __restrict__ sbin) {
    __shared__ int cnt[NBUCK];
    __shared__ int gbase[NBUCK];
    __shared__ int cnt2[NBUCK];
    const int base = blockIdx.x * CHUNK;
    const int end  = min(base + CHUNK, N_EDGES);
    for (int b = threadIdx.x; b < NBUCK; b += 256) { cnt[b] = 0; cnt2[b] = 0; }
    __syncthreads();
    for (int e = base + threadIdx.x; e < end; e += 256)
        atomicAdd(&cnt[src[e] >> BSHIFT], 1);
    __syncthreads();
    for (int b = threadIdx.x; b < NBUCK; b += 256)
        if (cnt[b] > 0) gbase[b] = atomicAdd(&cursorS[b], cnt[b]);
    __syncthreads();
    for (int e = base + threadIdx.x; e < end; e += 256) {
        int s = src[e];
        int b = s >> BSHIFT;
        int off = atomicAdd(&cnt2[b], 1);
        sbin[gbase[b] + off] = (unsigned)(s & (BNODES - 1));
    }
}

// ---------------- per-bucket histograms -> norms ----------------

__global__ __launch_bounds__(256) void k_histS(const unsigned* __restrict__ sbin,
                                               const int* __restrict__ baseS,
                                               float* __restrict__ normS) {
    __shared__ int cnt[BNODES];
    for (int t = threadIdx.x; t < BNODES; t += 256) cnt[t] = 0;
    __syncthreads();
    const int beg = baseS[blockIdx.x], end = baseS[blockIdx.x + 1];
    for (int e = beg + threadIdx.x; e < end; e += 256)
        atomicAdd(&cnt[sbin[e]], 1);
    __syncthreads();
    const int nodeBase = blockIdx.x << BSHIFT;
    for (int t = threadIdx.x; t < BNODES; t += 256) {
        int node = nodeBase + t;
        if (node < N_NODES)
            normS[node] = 1.0f / sqrtf((float)max(cnt[t], 1));
    }
}

// fused: histogram local dst + in-LDS scan -> normD, row_ptr, AND scatter ssrc
__global__ __launch_bounds__(256) void k_histD_scatter(const unsigned* __restrict__ binbuf,
                                                       const int* __restrict__ baseD,
                                                       float* __restrict__ normD,
                                                       int* __restrict__ row_ptr,
                                                       int* __restrict__ ssrc) {
    __shared__ int cnt[BNODES];
    __shared__ int tmp[BNODES];
    for (int t = threadIdx.x; t < BNODES; t += 256) cnt[t] = 0;
    __syncthreads();
    const int beg = baseD[blockIdx.x], end = baseD[blockIdx.x + 1];
    for (int e = beg + threadIdx.x; e < end; e += 256)
        atomicAdd(&cnt[binbuf[e] >> 17], 1);
    __syncthreads();
    const int nodeBase = blockIdx.x << BSHIFT;
    // write norms while counts are intact
    for (int t = threadIdx.x; t < BNODES; t += 256) {
        int node = nodeBase + t;
        if (node < N_NODES)
            normD[node] = 1.0f / sqrtf((float)max(cnt[t], 1));
    }
    // inclusive Hillis-Steele scan over cnt[512]
    for (int s = 1; s < BNODES; s <<= 1) {
        for (int t = threadIdx.x; t < BNODES; t += 256)
            tmp[t] = (t >= s) ? cnt[t - s] + cnt[t] : cnt[t];
        __syncthreads();
        for (int t = threadIdx.x; t < BNODES; t += 256) cnt[t] = tmp[t];
        __syncthreads();
    }
    // exclusive bases -> row_ptr + LDS cursors
    for (int t = threadIdx.x; t < BNODES; t += 256) {
        int b = beg + ((t == 0) ? 0 : cnt[t - 1]);
        tmp[t] = b;
        int node = nodeBase + t;
        if (node < N_NODES) row_ptr[node] = b;
    }
    if (blockIdx.x == 0 && threadIdx.x == 0) row_ptr[N_NODES] = N_EDGES;
    __syncthreads();
    // scatter into the bucket's contiguous CSR window
    for (int e = beg + threadIdx.x; e < end; e += 256) {
        unsigned v = binbuf[e];
        int pos = atomicAdd(&tmp[v >> 17], 1);
        ssrc[pos] = (int)(v & 0x1FFFFu);
    }
}

// ---------------- register-tiled GEMM: out = (X @ W) * normS ----------------

#define BMT 64
#define BKT 32

template<int KDIM>
__global__ __launch_bounds__(256) void k_gemm_rt(const float* __restrict__ X,
                                                 const float* __restrict__ W,
                                                 const float* __restrict__ normS,
                                                 float* __restrict__ out) {
    __shared__ float xs[BMT][BKT + 4];     // 64 x 36 floats
    __shared__ float ws[BKT * HID];        // 32 x 128

    const int tid = threadIdx.x;
    const int tx = tid & 31;
    const int ty = tid >> 5;
    const int col0 = tx * 4;
    const int row0 = ty * 8;
    const int rt = blockIdx.x * BMT;

    float acc[8][4];
    #pragma unroll
    for (int r = 0; r < 8; ++r)
        #pragma unroll
        for (int c = 0; c < 4; ++c) acc[r][c] = 0.f;

    for (int k0 = 0; k0 < KDIM; k0 += BKT) {
        __syncthreads();
        {
            const float4* wsrc = (const float4*)(W + (size_t)k0 * HID);
            #pragma unroll
            for (int i = tid; i < BKT * HID / 4; i += 256)
                ((float4*)ws)[i] = wsrc[i];
        }
        {
            #pragma unroll
            for (int i = tid; i < BMT * BKT / 4; i += 256) {
                int row = i >> 3;
                int kq  = i & 7;
                int gr  = rt + row;
                float4 v = make_float4(0.f, 0.f, 0.f, 0.f);
                if (gr < N_NODES)
                    v = *(const float4*)(X + (size_t)gr * KDIM + k0 + kq * 4);
                *(float4*)&xs[row][kq * 4] = v;
            }
        }
        __syncthreads();

        #pragma unroll 4
        for (int k = 0; k < BKT; ++k) {
            float4 b = *(const float4*)&ws[k * HID + col0];
            float a[8];
            #pragma unroll
            for (int r = 0; r < 8; ++r) a[r] = xs[row0 + r][k];
            #pragma unroll
            for (int r = 0; r < 8; ++r) {
                acc[r][0] += a[r] * b.x;
                acc[r][1] += a[r] * b.y;
                acc[r][2] += a[r] * b.z;
                acc[r][3] += a[r] * b.w;
            }
        }
    }

    #pragma unroll
    for (int r = 0; r < 8; ++r) {
        int gr = rt + row0 + r;
        if (gr < N_NODES) {
            float s = normS[gr];
            float4 o = make_float4(acc[r][0] * s, acc[r][1] * s, acc[r][2] * s, acc[r][3] * s);
            *(float4*)(out + (size_t)gr * HID + col0) = o;
        }
    }
}

// ---------------- CSR aggregation + norm + bias + relu ----------------
// 8-deep load batching for MLP; accumulation order (edge-sequential) preserved.

#define ACC4(A, V) { A.x += V.x; A.y += V.y; A.z += V.z; A.w += V.w; }

__global__ __launch_bounds__(256) void k_agg(const float* __restrict__ hs,
                                             const int* __restrict__ row_ptr,
                                             const int* __restrict__ ssrc,
                                             const float* __restrict__ normD,
                                             const float* __restrict__ bias,
                                             float* __restrict__ out,
                                             float* __restrict__ keys) {
    const int node = blockIdx.x * 8 + (threadIdx.x >> 5);
    const int lane = threadIdx.x & 31;     // channels lane*4 .. lane*4+3
    if (node >= N_NODES) return;
    const int beg = row_ptr[node], end = row_ptr[node + 1];
    const float4* __restrict__ hv = (const float4*)hs;
    float4 acc = make_float4(0.f, 0.f, 0.f, 0.f);
    int e = beg;
    for (; e + 8 <= end; e += 8) {
        int s0 = ssrc[e + 0], s1 = ssrc[e + 1], s2 = ssrc[e + 2], s3 = ssrc[e + 3];
        int s4 = ssrc[e + 4], s5 = ssrc[e + 5], s6 = ssrc[e + 6], s7 = ssrc[e + 7];
        float4 v0 = hv[(size_t)s0 * 32 + lane];
        float4 v1 = hv[(size_t)s1 * 32 + lane];
        float4 v2 = hv[(size_t)s2 * 32 + lane];
        float4 v3 = hv[(size_t)s3 * 32 + lane];
        float4 v4 = hv[(size_t)s4 * 32 + lane];
        float4 v5 = hv[(size_t)s5 * 32 + lane];
        float4 v6 = hv[(size_t)s6 * 32 + lane];
        float4 v7 = hv[(size_t)s7 * 32 + lane];
        ACC4(acc, v0); ACC4(acc, v1); ACC4(acc, v2); ACC4(acc, v3);
        ACC4(acc, v4); ACC4(acc, v5); ACC4(acc, v6); ACC4(acc, v7);
    }
    if (e + 4 <= end) {
        int s0 = ssrc[e + 0], s1 = ssrc[e + 1], s2 = ssrc[e + 2], s3 = ssrc[e + 3];
        float4 v0 = hv[(size_t)s0 * 32 + lane];
        float4 v1 = hv[(size_t)s1 * 32 + lane];
        float4 v2 = hv[(size_t)s2 * 32 + lane];
        float4 v3 = hv[(size_t)s3 * 32 + lane];
        ACC4(acc, v0); ACC4(acc, v1); ACC4(acc, v2); ACC4(acc, v3);
        e += 4;
    }
    for (; e < end; ++e) {
        float4 v0 = hv[(size_t)ssrc[e] * 32 + lane];
        ACC4(acc, v0);
    }
    float nrm = normD[node];
    float4 bb = *(const float4*)(bias + lane * 4);
    float4 o;
    o.x = fmaxf(acc.x * nrm + bb.x, 0.f);
    o.y = fmaxf(acc.y * nrm + bb.y, 0.f);
    o.z = fmaxf(acc.z * nrm + bb.z, 0.f);
    o.w = fmaxf(acc.w * nrm + bb.w, 0.f);
    *(float4*)(out + (size_t)node * HID + lane * 4) = o;
    if (keys != nullptr && lane == 31) keys[node] = o.w;   // channel 127
}

// ---------------- hybrid bitonic top-K ----------------

__global__ __launch_bounds__(256) void k_sort_init(const float* __restrict__ keys,
                                                   unsigned long long* __restrict__ arr) {
    int i = blockIdx.x * 256 + threadIdx.x;          // 0 .. 8*16384-1
    if (i >= BATCH * SORTN) return;
    int g = i >> 14;            // /SORTN
    int l = i & (SORTN - 1);
    unsigned long long c;
    if (l < NPER) {
        unsigned u = __float_as_uint(keys[g * NPER + l]);
        unsigned s = (u & 0x80000000u) ? ~u : (u | 0x80000000u); // ascending map
        unsigned d = ~s;                                         // descending
        c = ((unsigned long long)d << 32) | (unsigned)l;
    } else {
        c = 0xFFFFFFFFFFFFFFFFull;  // sorts last
    }
    arr[i] = c;
}

// stages k = 2 .. SORTC entirely in LDS (one block per SORTC-chunk)
__global__ __launch_bounds__(1024) void k_sort_local_full(unsigned long long* __restrict__ arr) {
    __shared__ unsigned long long lds[SORTC];
    const int base  = blockIdx.x * SORTC;            // flat base into arr
    const int gbase = base & (SORTN - 1);            // base within the graph's array
    lds[threadIdx.x]        = arr[base + threadIdx.x];
    lds[threadIdx.x + 1024] = arr[base + threadIdx.x + 1024];
    __syncthreads();
    for (int k = 2; k <= SORTC; k <<= 1) {
        for (int j = k >> 1; j > 0; j >>= 1) {
            int t = threadIdx.x;                     // SORTC/2 = 1024 CEs
            int i = ((t & ~(j - 1)) << 1) | (t & (j - 1));
            bool up = (((gbase + i) & k) == 0);
            unsigned long long a = lds[i], b = lds[i + j];
            if ((a > b) == up) { lds[i] = b; lds[i + j] = a; }
            __syncthreads();
        }
    }
    arr[base + threadIdx.x]        = lds[threadIdx.x];
    arr[base + threadIdx.x + 1024] = lds[threadIdx.x + 1024];
}

// one global compare-exchange substage (stride j >= SORTC)
__global__ __launch_bounds__(256) void k_sort_global(unsigned long long* __restrict__ arr,
                                                     int k, int j) {
    int tg = blockIdx.x * 256 + threadIdx.x;         // 8 * 8192 CEs
    if (tg >= BATCH * (SORTN / 2)) return;
    int g = tg >> 13;                                // / (SORTN/2)
    int t = tg & (SORTN / 2 - 1);
    int i = ((t & ~(j - 1)) << 1) | (t & (j - 1));
    bool up = ((i & k) == 0);
    unsigned long long* p = arr + (size_t)g * SORTN;
    unsigned long long a = p[i], b = p[i + j];
    if ((a > b) == up) { p[i] = b; p[i + j] = a; }
}

// tail strides j = SORTC/2 .. 1 of stage k, LDS-local per SORTC-chunk
__global__ __launch_bounds__(1024) void k_sort_local_tail(unsigned long long* __restrict__ arr,
                                                          int k) {
    __shared__ unsigned long long lds[SORTC];
    const int base  = blockIdx.x * SORTC;
    const int gbase = base & (SORTN - 1);
    lds[threadIdx.x]        = arr[base + threadIdx.x];
    lds[threadIdx.x + 1024] = arr[base + threadIdx.x + 1024];
    __syncthreads();
    for (int j = SORTC >> 1; j > 0; j >>= 1) {
        int t = threadIdx.x;
        int i = ((t & ~(j - 1)) << 1) | (t & (j - 1));
        bool up = (((gbase + i) & k) == 0);
        unsigned long long a = lds[i], b = lds[i + j];
        if ((a > b) == up) { lds[i] = b; lds[i + j] = a; }
        __syncthreads();
    }
    arr[base + threadIdx.x]        = lds[threadIdx.x];
    arr[base + threadIdx.x + 1024] = lds[threadIdx.x + 1024];
}

__global__ __launch_bounds__(256) void k_sort_emit(const unsigned long long* __restrict__ arr,
                                                   int* __restrict__ topk_idx) {
    int i = blockIdx.x * 256 + threadIdx.x;
    if (i >= BATCH * TOPK) return;
    int b = i / TOPK;
    int k = i - b * TOPK;
    topk_idx[i] = (int)(arr[(size_t)b * SORTN + k] & 0xFFFFFFFFull);
}

// ---------------- output init + final reduction GEMM ----------------

__global__ void k_outinit(const float* __restrict__ b3, float* __restrict__ out) {
    int i = threadIdx.x;
    if (i < BATCH * NCLS) out[i] = b3[i % NCLS];
}

#define KPB 100   // top-k rows per block

__global__ __launch_bounds__(128) void k_final(const float* __restrict__ h2,
                                               const int* __restrict__ topk_idx,
                                               const float* __restrict__ W3,
                                               float* __restrict__ out) {
    __shared__ float red[128 * NCLS];
    const int b = blockIdx.x / (TOPK / KPB);
    const int chunk = blockIdx.x % (TOPK / KPB);
    const int j = threadIdx.x;
    float acc[NCLS];
    #pragma unroll
    for (int c = 0; c < NCLS; ++c) acc[c] = 0.f;
    const int k0 = chunk * KPB;
    for (int k = k0; k < k0 + KPB; ++k) {
        int node = b * NPER + topk_idx[b * TOPK + k];
        float h = h2[(size_t)node * HID + j];
        const float* wrow = W3 + (size_t)(k * HID + j) * NCLS;
        #pragma unroll
        for (int c = 0; c < NCLS; ++c) acc[c] += h * wrow[c];
    }
    #pragma unroll
    for (int c = 0; c < NCLS; ++c) red[j * NCLS + c] = acc[c];
    __syncthreads();
    for (int s = 64; s > 0; s >>= 1) {
        if (j < s) {
            #pragma unroll
            for (int c = 0; c < NCLS; ++c) red[j * NCLS + c] += red[(j + s) * NCLS + c];
        }
        __syncthreads();
    }
    if (j < NCLS) atomicAdd(&out[b * NCLS + j], red[j]);
}

// ---------------- launch ----------------

extern "C" void kernel_launch(void* const* d_in, const int* in_sizes, int n_in,
                              void* d_out, int out_size, void* d_ws, size_t ws_size,
                              hipStream_t stream) {
    const float* features = (const float*)d_in[0];
    const int*   src      = (const int*)d_in[1];
    const int*   dst      = (const int*)d_in[2];
    const float* W1       = (const float*)d_in[3];
    const float* b1       = (const float*)d_in[4];
    const float* W2       = (const float*)d_in[5];
    const float* b2       = (const float*)d_in[6];
    const float* W3       = (const float*)d_in[7];
    const float* b3       = (const float*)d_in[8];
    float* out = (float*)d_out;

    char* p = (char*)d_ws;
    auto carve = [&](size_t bytes) -> void* {
        void* r = (void*)p;
        p += (bytes + 511) & ~(size_t)511;
        return r;
    };
    float* normS     = (float*)carve((size_t)N_NODES * 4);
    float* normD     = (float*)carve((size_t)N_NODES * 4);
    int*   row_ptr   = (int*)carve((size_t)(N_NODES + 1) * 4);
    int*   bcntS     = (int*)carve((size_t)NBUCK * 4);
    int*   bcntD     = (int*)carve((size_t)NBUCK * 4);
    int*   baseS     = (int*)carve((size_t)(NBUCK + 1) * 4);
    int*   baseD     = (int*)carve((size_t)(NBUCK + 1) * 4);
    int*   curS      = (int*)carve((size_t)NBUCK * 4);
    int*   curD      = (int*)carve((size_t)NBUCK * 4);
    int*   ssrc      = (int*)carve((size_t)N_EDGES * 4);
    unsigned* binbuf = (unsigned*)carve((size_t)N_EDGES * 4);
    unsigned* sbin   = (unsigned*)carve((size_t)N_EDGES * 4);
    float* keys      = (float*)carve((size_t)N_NODES * 4);
    int*   topk_idx  = (int*)carve((size_t)BATCH * TOPK * 4);
    unsigned long long* sortbuf = (unsigned long long*)carve((size_t)BATCH * SORTN * 8);
    float* bufA      = (float*)carve((size_t)N_NODES * HID * 4);
    float* bufB      = (float*)carve((size_t)N_NODES * HID * 4);

    const int GB = (N_NODES + BMT - 1) / BMT;     // gemm tiles
    const int BB = (N_EDGES + CHUNK - 1) / CHUNK; // bin blocks (196)

    hipMemsetAsync(bcntS, 0, (size_t)NBUCK * 4, stream);
    hipMemsetAsync(bcntD, 0, (size_t)NBUCK * 4, stream);

    // CSR build + degrees/norms, all via bucket binning (no global scatter atomics)
    k_bcount<<<BB, 256, 0, stream>>>(src, dst, bcntS, bcntD);
    k_bscan<<<1, 64, 0, stream>>>(bcntS, bcntD, baseS, baseD, curS, curD);
    k_bin<<<BB, 256, 0, stream>>>(src, dst, curD, binbuf);
    k_bin_src<<<BB, 256, 0, stream>>>(src, curS, sbin);
    k_histS<<<NBUCK, 256, 0, stream>>>(sbin, baseS, normS);
    k_histD_scatter<<<NBUCK, 256, 0, stream>>>(binbuf, baseD, normD, row_ptr, ssrc);

    k_gemm_rt<IN_DIM><<<GB, 256, 0, stream>>>(features, W1, normS, bufA);
    k_agg<<<(N_NODES + 7) / 8, 256, 0, stream>>>(bufA, row_ptr, ssrc, normD, b1, bufB, nullptr);
    k_gemm_rt<HID><<<GB, 256, 0, stream>>>(bufB, W2, normS, bufA);
    k_agg<<<(N_NODES + 7) / 8, 256, 0, stream>>>(bufA, row_ptr, ssrc, normD, b2, bufB, keys);

    // hybrid bitonic full sort (same network as a single-block bitonic sort)
    const int NCHUNK = BATCH * SORTN / SORTC;          // 64
    const int GCE    = (BATCH * (SORTN / 2) + 255) / 256; // 256 blocks
    k_sort_init<<<(BATCH * SORTN + 255) / 256, 256, 0, stream>>>(keys, sortbuf);
    k_sort_local_full<<<NCHUNK, 1024, 0, stream>>>(sortbuf);
    // k = 4096
    k_sort_global<<<GCE, 256, 0, stream>>>(sortbuf, 4096, 2048);
    k_sort_local_tail<<<NCHUNK, 1024, 0, stream>>>(sortbuf, 4096);
    // k = 8192
    k_sort_global<<<GCE, 256, 0, stream>>>(sortbuf, 8192, 4096);
    k_sort_global<<<GCE, 256, 0, stream>>>(sortbuf, 8192, 2048);
    k_sort_local_tail<<<NCHUNK, 1024, 0, stream>>>(sortbuf, 8192);
    // k = 16384
    k_sort_global<<<GCE, 256, 0, stream>>>(sortbuf, 16384, 8192);
    k_sort_global<<<GCE, 256, 0, stream>>>(sortbuf, 16384, 4096);
    k_sort_global<<<GCE, 256, 0, stream>>>(sortbuf, 16384, 2048);
    k_sort_local_tail<<<NCHUNK, 1024, 0, stream>>>(sortbuf, 16384);
    k_sort_emit<<<(BATCH * TOPK + 255) / 256, 256, 0, stream>>>(sortbuf, topk_idx);

    k_outinit<<<1, 256, 0, stream>>>(b3, out);
    k_final<<<BATCH * (TOPK / KPB), 128, 0, stream>>>(bufB, topk_idx, W3, out);
}

// Round 9
// 594.734 us; speedup vs baseline: 2.1427x; 1.0931x over previous
//
#include <hip/hip_runtime.h>
#include <cstdint>
#include <cstddef>

#define N_NODES 100000
#define N_EDGES 1600000
#define IN_DIM  64
#define HID     128
#define NCLS    18
#define BATCH   8
#define TOPK    5000
#define NPER    12500   // N_NODES / BATCH
#define SORTN   16384   // next pow2 >= NPER
#define SORTC   2048    // LDS-local chunk for hybrid bitonic

#define BSHIFT  9                      // bucket = node >> 9 (512 nodes per bucket)
#define BNODES  (1 << BSHIFT)
#define NBUCK   ((N_NODES + BNODES - 1) / BNODES)   // 196
#define CHUNK   8192                   // edges per block in binning kernels

// ---------------- bucket-level counting (LDS-privatized) ----------------

__global__ __launch_bounds__(256) void k_bcount(const int* __restrict__ src,
                                                const int* __restrict__ dst,
                                                int* __restrict__ bcntS,
                                                int* __restrict__ bcntD) {
    __shared__ int cs[NBUCK], cd[NBUCK];
    for (int b = threadIdx.x; b < NBUCK; b += 256) { cs[b] = 0; cd[b] = 0; }
    __syncthreads();
    const int base = blockIdx.x * CHUNK;
    const int end  = min(base + CHUNK, N_EDGES);
    for (int e = base + threadIdx.x; e < end; e += 256) {
        atomicAdd(&cs[src[e] >> BSHIFT], 1);
        atomicAdd(&cd[dst[e] >> BSHIFT], 1);
    }
    __syncthreads();
    for (int b = threadIdx.x; b < NBUCK; b += 256) {
        if (cs[b]) atomicAdd(&bcntS[b], cs[b]);
        if (cd[b]) atomicAdd(&bcntD[b], cd[b]);
    }
}

__global__ void k_bscan(const int* __restrict__ bcntS, const int* __restrict__ bcntD,
                        int* __restrict__ baseS, int* __restrict__ baseD,
                        int* __restrict__ curS, int* __restrict__ curD) {
    if (threadIdx.x == 0 && blockIdx.x == 0) {
        int rs = 0, rd = 0;
        for (int b = 0; b < NBUCK; ++b) {
            baseS[b] = rs; curS[b] = rs; rs += bcntS[b];
            baseD[b] = rd; curD[b] = rd; rd += bcntD[b];
        }
        baseS[NBUCK] = rs; baseD[NBUCK] = rd;
    }
}

// ---------------- binned edge placement ----------------

// bin (local_dst<<17 | src) by dst bucket; writes land in ~42-long runs.
__global__ __launch_bounds__(256) void k_bin(const int* __restrict__ src,
                                             const int* __restrict__ dst,
                                             int* __restrict__ cursorD,
                                             unsigned* __restrict__ binbuf) {
    __shared__ int cnt[NBUCK];
    __shared__ int gbase[NBUCK];
    __shared__ int cnt2[NBUCK];
    const int base = blockIdx.x * CHUNK;
    const int end  = min(base + CHUNK, N_EDGES);
    for (int b = threadIdx.x; b < NBUCK; b += 256) { cnt[b] = 0; cnt2[b] = 0; }
    __syncthreads();
    for (int e = base + threadIdx.x; e < end; e += 256)
        atomicAdd(&cnt[dst[e] >> BSHIFT], 1);
    __syncthreads();
    for (int b = threadIdx.x; b < NBUCK; b += 256)
        if (cnt[b] > 0) gbase[b] = atomicAdd(&cursorD[b], cnt[b]);
    __syncthreads();
    for (int e = base + threadIdx.x; e < end; e += 256) {
        int d = dst[e];
        int b = d >> BSHIFT;
        int off = atomicAdd(&cnt2[b], 1);
        unsigned packed = ((unsigned)(d & (BNODES - 1)) << 17) | (unsigned)src[e];
        binbuf[gbase[b] + off] = packed;
    }
}

// bin local_src by src bucket (for out-degree histogram)
__global__ __launch_bounds__(256) void k_bin_src(const int* __restrict__ src,
                                                 int* __restrict__ cursorS,
                                                 unsigned* __restrict__ sbin) {
    __shared__ int cnt[NBUCK];
    __shared__ int gbase[NBUCK];
    __shared__ int cnt2[NBUCK];
    const int base = blockIdx.x * CHUNK;
    const int end  = min(base + CHUNK, N_EDGES);
    for (int b = threadIdx.x; b < NBUCK; b += 256) { cnt[b] = 0; cnt2[b] = 0; }
    __syncthreads();
    for (int e = base + threadIdx.x; e < end; e += 256)
        atomicAdd(&cnt[src[e] >> BSHIFT], 1);
    __syncthreads();
    for (int b = threadIdx.x; b < NBUCK; b += 256)
        if (cnt[b] > 0) gbase[b] = atomicAdd(&cursorS[b], cnt[b]);
    __syncthreads();
    for (int e = base + threadIdx.x; e < end; e += 256) {
        int s = src[e];
        int b = s >> BSHIFT;
        int off = atomicAdd(&cnt2[b], 1);
        sbin[gbase[b] + off] = (unsigned)(s & (BNODES - 1));
    }
}

// ---------------- per-bucket histograms -> norms ----------------

__global__ __launch_bounds__(256) void k_histS(const unsigned* __restrict__ sbin,
                                               const int* __restrict__ baseS,
                                               float* __restrict__ normS) {
    __shared__ int cnt[BNODES];
    for (int t = threadIdx.x; t < BNODES; t += 256) cnt[t] = 0;
    __syncthreads();
    const int beg = baseS[blockIdx.x], end = baseS[blockIdx.x + 1];
    for (int e = beg + threadIdx.x; e < end; e += 256)
        atomicAdd(&cnt[sbin[e]], 1);
    __syncthreads();
    const int nodeBase = blockIdx.x << BSHIFT;
    for (int t = threadIdx.x; t < BNODES; t += 256) {
        int node = nodeBase + t;
        if (node < N_NODES)
            normS[node] = 1.0f / sqrtf((float)max(cnt[t], 1));
    }
}

// fused: histogram local dst + in-LDS scan -> normD, row_ptr, AND scatter ssrc
__global__ __launch_bounds__(256) void k_histD_scatter(const unsigned* __restrict__ binbuf,
                                                       const int* __restrict__ baseD,
                                                       float* __restrict__ normD,
                                                       int* __restrict__ row_ptr,
                                                       int* __restrict__ ssrc) {
    __shared__ int cnt[BNODES];
    __shared__ int tmp[BNODES];
    for (int t = threadIdx.x; t < BNODES; t += 256) cnt[t] = 0;
    __syncthreads();
    const int beg = baseD[blockIdx.x], end = baseD[blockIdx.x + 1];
    for (int e = beg + threadIdx.x; e < end; e += 256)
        atomicAdd(&cnt[binbuf[e] >> 17], 1);
    __syncthreads();
    const int nodeBase = blockIdx.x << BSHIFT;
    // write norms while counts are intact
    for (int t = threadIdx.x; t < BNODES; t += 256) {
        int node = nodeBase + t;
        if (node < N_NODES)
            normD[node] = 1.0f / sqrtf((float)max(cnt[t], 1));
    }
    // inclusive Hillis-Steele scan over cnt[512]
    for (int s = 1; s < BNODES; s <<= 1) {
        for (int t = threadIdx.x; t < BNODES; t += 256)
            tmp[t] = (t >= s) ? cnt[t - s] + cnt[t] : cnt[t];
        __syncthreads();
        for (int t = threadIdx.x; t < BNODES; t += 256) cnt[t] = tmp[t];
        __syncthreads();
    }
    // exclusive bases -> row_ptr + LDS cursors
    for (int t = threadIdx.x; t < BNODES; t += 256) {
        int b = beg + ((t == 0) ? 0 : cnt[t - 1]);
        tmp[t] = b;
        int node = nodeBase + t;
        if (node < N_NODES) row_ptr[node] = b;
    }
    if (blockIdx.x == 0 && threadIdx.x == 0) row_ptr[N_NODES] = N_EDGES;
    __syncthreads();
    // scatter into the bucket's contiguous CSR window
    for (int e = beg + threadIdx.x; e < end; e += 256) {
        unsigned v = binbuf[e];
        int pos = atomicAdd(&tmp[v >> 17], 1);
        ssrc[pos] = (int)(v & 0x1FFFFu);
    }
}

// ---------------- CSR gather-sum (pre-transform aggregation) ----------------

__global__ __launch_bounds__(256) void k_agg64(const float* __restrict__ hs,
                                               const int* __restrict__ row_ptr,
                                               const int* __restrict__ ssrc,
                                               const float* __restrict__ normS,
                                               float* __restrict__ out) {
    const int node = blockIdx.x * 16 + (threadIdx.x >> 4);
    const int lane = threadIdx.x & 15;     // channels lane*4 .. lane*4+3 of 64
    if (node >= N_NODES) return;
    const int beg = row_ptr[node], end = row_ptr[node + 1];
    const float4* __restrict__ hv = (const float4*)hs;
    float4 acc = make_float4(0.f, 0.f, 0.f, 0.f);
    int e = beg;
    for (; e + 4 <= end; e += 4) {
        int s0 = ssrc[e + 0], s1 = ssrc[e + 1], s2 = ssrc[e + 2], s3 = ssrc[e + 3];
        float n0 = normS[s0], n1 = normS[s1], n2 = normS[s2], n3 = normS[s3];
        float4 v0 = hv[(size_t)s0 * 16 + lane];
        float4 v1 = hv[(size_t)s1 * 16 + lane];
        float4 v2 = hv[(size_t)s2 * 16 + lane];
        float4 v3 = hv[(size_t)s3 * 16 + lane];
        acc.x += v0.x * n0; acc.y += v0.y * n0; acc.z += v0.z * n0; acc.w += v0.w * n0;
        acc.x += v1.x * n1; acc.y += v1.y * n1; acc.z += v1.z * n1; acc.w += v1.w * n1;
        acc.x += v2.x * n2; acc.y += v2.y * n2; acc.z += v2.z * n2; acc.w += v2.w * n2;
        acc.x += v3.x * n3; acc.y += v3.y * n3; acc.z += v3.z * n3; acc.w += v3.w * n3;
    }
    for (; e < end; ++e) {
        int s0 = ssrc[e];
        float n0 = normS[s0];
        float4 v0 = hv[(size_t)s0 * 16 + lane];
        acc.x += v0.x * n0; acc.y += v0.y * n0; acc.z += v0.z * n0; acc.w += v0.w * n0;
    }
    *(float4*)(out + (size_t)node * IN_DIM + lane * 4) = acc;
}

#define ACC4(A, V) { A.x += V.x; A.y += V.y; A.z += V.z; A.w += V.w; }

__global__ __launch_bounds__(256) void k_agg128(const float* __restrict__ hs,
                                                const int* __restrict__ row_ptr,
                                                const int* __restrict__ ssrc,
                                                float* __restrict__ out) {
    const int node = blockIdx.x * 8 + (threadIdx.x >> 5);
    const int lane = threadIdx.x & 31;     // channels lane*4 .. lane*4+3 of 128
    if (node >= N_NODES) return;
    const int beg = row_ptr[node], end = row_ptr[node + 1];
    const float4* __restrict__ hv = (const float4*)hs;
    float4 acc = make_float4(0.f, 0.f, 0.f, 0.f);
    int e = beg;
    for (; e + 4 <= end; e += 4) {
        int s0 = ssrc[e + 0], s1 = ssrc[e + 1], s2 = ssrc[e + 2], s3 = ssrc[e + 3];
        float4 v0 = hv[(size_t)s0 * 32 + lane];
        float4 v1 = hv[(size_t)s1 * 32 + lane];
        float4 v2 = hv[(size_t)s2 * 32 + lane];
        float4 v3 = hv[(size_t)s3 * 32 + lane];
        ACC4(acc, v0); ACC4(acc, v1); ACC4(acc, v2); ACC4(acc, v3);
    }
    for (; e < end; ++e) {
        float4 v0 = hv[(size_t)ssrc[e] * 32 + lane];
        ACC4(acc, v0);
    }
    *(float4*)(out + (size_t)node * HID + lane * 4) = acc;
}

// ---------------- register-tiled GEMM with fused norm/bias/relu epilogue ----
// out = relu((G @ W) * normD + bias) [* normS if POST]; KEYS: keys = out[:,127]

#define BMT 64
#define BKT 32

template<int KDIM, bool POST, bool KEYS>
__global__ __launch_bounds__(256) void k_gemm_rt(const float* __restrict__ X,
                                                 const float* __restrict__ W,
                                                 const float* __restrict__ normD,
                                                 const float* __restrict__ bias,
                                                 const float* __restrict__ normS,
                                                 float* __restrict__ keys,
                                                 float* __restrict__ out) {
    __shared__ float xs[BMT][BKT + 4];     // 64 x 36 floats
    __shared__ float ws[BKT * HID];        // 32 x 128

    const int tid = threadIdx.x;
    const int tx = tid & 31;
    const int ty = tid >> 5;
    const int col0 = tx * 4;
    const int row0 = ty * 8;
    const int rt = blockIdx.x * BMT;

    float acc[8][4];
    #pragma unroll
    for (int r = 0; r < 8; ++r)
        #pragma unroll
        for (int c = 0; c < 4; ++c) acc[r][c] = 0.f;

    for (int k0 = 0; k0 < KDIM; k0 += BKT) {
        __syncthreads();
        {
            const float4* wsrc = (const float4*)(W + (size_t)k0 * HID);
            #pragma unroll
            for (int i = tid; i < BKT * HID / 4; i += 256)
                ((float4*)ws)[i] = wsrc[i];
        }
        {
            #pragma unroll
            for (int i = tid; i < BMT * BKT / 4; i += 256) {
                int row = i >> 3;
                int kq  = i & 7;
                int gr  = rt + row;
                float4 v = make_float4(0.f, 0.f, 0.f, 0.f);
                if (gr < N_NODES)
                    v = *(const float4*)(X + (size_t)gr * KDIM + k0 + kq * 4);
                *(float4*)&xs[row][kq * 4] = v;
            }
        }
        __syncthreads();

        #pragma unroll 4
        for (int k = 0; k < BKT; ++k) {
            float4 b = *(const float4*)&ws[k * HID + col0];
            float a[8];
            #pragma unroll
            for (int r = 0; r < 8; ++r) a[r] = xs[row0 + r][k];
            #pragma unroll
            for (int r = 0; r < 8; ++r) {
                acc[r][0] += a[r] * b.x;
                acc[r][1] += a[r] * b.y;
                acc[r][2] += a[r] * b.z;
                acc[r][3] += a[r] * b.w;
            }
        }
    }

    const float4 bb = *(const float4*)(bias + col0);
    #pragma unroll
    for (int r = 0; r < 8; ++r) {
        int gr = rt + row0 + r;
        if (gr < N_NODES) {
            float nd = normD[gr];
            float4 o;
            o.x = fmaxf(acc[r][0] * nd + bb.x, 0.f);
            o.y = fmaxf(acc[r][1] * nd + bb.y, 0.f);
            o.z = fmaxf(acc[r][2] * nd + bb.z, 0.f);
            o.w = fmaxf(acc[r][3] * nd + bb.w, 0.f);
            if (KEYS && col0 == 124) keys[gr] = o.w;   // channel 127 (pre-POST)
            if (POST) {
                float ns = normS[gr];
                o.x *= ns; o.y *= ns; o.z *= ns; o.w *= ns;
            }
            *(float4*)(out + (size_t)gr * HID + col0) = o;
        }
    }
}

// ---------------- hybrid bitonic top-K ----------------

__global__ __launch_bounds__(256) void k_sort_init(const float* __restrict__ keys,
                                                   unsigned long long* __restrict__ arr) {
    int i = blockIdx.x * 256 + threadIdx.x;          // 0 .. 8*16384-1
    if (i >= BATCH * SORTN) return;
    int g = i >> 14;            // /SORTN
    int l = i & (SORTN - 1);
    unsigned long long c;
    if (l < NPER) {
        unsigned u = __float_as_uint(keys[g * NPER + l]);
        unsigned s = (u & 0x80000000u) ? ~u : (u | 0x80000000u); // ascending map
        unsigned d = ~s;                                         // descending
        c = ((unsigned long long)d << 32) | (unsigned)l;
    } else {
        c = 0xFFFFFFFFFFFFFFFFull;  // sorts last
    }
    arr[i] = c;
}

// stages k = 2 .. SORTC entirely in LDS (one block per SORTC-chunk)
__global__ __launch_bounds__(1024) void k_sort_local_full(unsigned long long* __restrict__ arr) {
    __shared__ unsigned long long lds[SORTC];
    const int base  = blockIdx.x * SORTC;            // flat base into arr
    const int gbase = base & (SORTN - 1);            // base within the graph's array
    lds[threadIdx.x]        = arr[base + threadIdx.x];
    lds[threadIdx.x + 1024] = arr[base + threadIdx.x + 1024];
    __syncthreads();
    for (int k = 2; k <= SORTC; k <<= 1) {
        for (int j = k >> 1; j > 0; j >>= 1) {
            int t = threadIdx.x;                     // SORTC/2 = 1024 CEs
            int i = ((t & ~(j - 1)) << 1) | (t & (j - 1));
            bool up = (((gbase + i) & k) == 0);
            unsigned long long a = lds[i], b = lds[i + j];
            if ((a > b) == up) { lds[i] = b; lds[i + j] = a; }
            __syncthreads();
        }
    }
    arr[base + threadIdx.x]        = lds[threadIdx.x];
    arr[base + threadIdx.x + 1024] = lds[threadIdx.x + 1024];
}

// one global compare-exchange substage (stride j >= SORTC)
__global__ __launch_bounds__(256) void k_sort_global(unsigned long long* __restrict__ arr,
                                                     int k, int j) {
    int tg = blockIdx.x * 256 + threadIdx.x;         // 8 * 8192 CEs
    if (tg >= BATCH * (SORTN / 2)) return;
    int g = tg >> 13;                                // / (SORTN/2)
    int t = tg & (SORTN / 2 - 1);
    int i = ((t & ~(j - 1)) << 1) | (t & (j - 1));
    bool up = ((i & k) == 0);
    unsigned long long* p = arr + (size_t)g * SORTN;
    unsigned long long a = p[i], b = p[i + j];
    if ((a > b) == up) { p[i] = b; p[i + j] = a; }
}

// tail strides j = SORTC/2 .. 1 of stage k, LDS-local per SORTC-chunk
__global__ __launch_bounds__(1024) void k_sort_local_tail(unsigned long long* __restrict__ arr,
                                                          int k) {
    __shared__ unsigned long long lds[SORTC];
    const int base  = blockIdx.x * SORTC;
    const int gbase = base & (SORTN - 1);
    lds[threadIdx.x]        = arr[base + threadIdx.x];
    lds[threadIdx.x + 1024] = arr[base + threadIdx.x + 1024];
    __syncthreads();
    for (int j = SORTC >> 1; j > 0; j >>= 1) {
        int t = threadIdx.x;
        int i = ((t & ~(j - 1)) << 1) | (t & (j - 1));
        bool up = (((gbase + i) & k) == 0);
        unsigned long long a = lds[i], b = lds[i + j];
        if ((a > b) == up) { lds[i] = b; lds[i + j] = a; }
        __syncthreads();
    }
    arr[base + threadIdx.x]        = lds[threadIdx.x];
    arr[base + threadIdx.x + 1024] = lds[threadIdx.x + 1024];
}

__global__ __launch_bounds__(256) void k_sort_emit(const unsigned long long* __restrict__ arr,
                                                   int* __restrict__ topk_idx) {
    int i = blockIdx.x * 256 + threadIdx.x;
    if (i >= BATCH * TOPK) return;
    int b = i / TOPK;
    int k = i - b * TOPK;
    topk_idx[i] = (int)(arr[(size_t)b * SORTN + k] & 0xFFFFFFFFull);
}

// ---------------- output init + final reduction GEMM ----------------

__global__ void k_outinit(const float* __restrict__ b3, float* __restrict__ out) {
    int i = threadIdx.x;
    if (i < BATCH * NCLS) out[i] = b3[i % NCLS];
}

#define KPB 100   // top-k rows per block

__global__ __launch_bounds__(128) void k_final(const float* __restrict__ h2,
                                               const int* __restrict__ topk_idx,
                                               const float* __restrict__ W3,
                                               float* __restrict__ out) {
    __shared__ float red[128 * NCLS];
    const int b = blockIdx.x / (TOPK / KPB);
    const int chunk = blockIdx.x % (TOPK / KPB);
    const int j = threadIdx.x;
    float acc[NCLS];
    #pragma unroll
    for (int c = 0; c < NCLS; ++c) acc[c] = 0.f;
    const int k0 = chunk * KPB;
    for (int k = k0; k < k0 + KPB; ++k) {
        int node = b * NPER + topk_idx[b * TOPK + k];
        float h = h2[(size_t)node * HID + j];
        const float* wrow = W3 + (size_t)(k * HID + j) * NCLS;
        #pragma unroll
        for (int c = 0; c < NCLS; ++c) acc[c] += h * wrow[c];
    }
    #pragma unroll
    for (int c = 0; c < NCLS; ++c) red[j * NCLS + c] = acc[c];
    __syncthreads();
    for (int s = 64; s > 0; s >>= 1) {
        if (j < s) {
            #pragma unroll
            for (int c = 0; c < NCLS; ++c) red[j * NCLS + c] += red[(j + s) * NCLS + c];
        }
        __syncthreads();
    }
    if (j < NCLS) atomicAdd(&out[b * NCLS + j], red[j]);
}

// ---------------- launch ----------------

extern "C" void kernel_launch(void* const* d_in, const int* in_sizes, int n_in,
                              void* d_out, int out_size, void* d_ws, size_t ws_size,
                              hipStream_t stream) {
    const float* features = (const float*)d_in[0];
    const int*   src      = (const int*)d_in[1];
    const int*   dst      = (const int*)d_in[2];
    const float* W1       = (const float*)d_in[3];
    const float* b1       = (const float*)d_in[4];
    const float* W2       = (const float*)d_in[5];
    const float* b2       = (const float*)d_in[6];
    const float* W3       = (const float*)d_in[7];
    const float* b3       = (const float*)d_in[8];
    float* out = (float*)d_out;

    char* p = (char*)d_ws;
    auto carve = [&](size_t bytes) -> void* {
        void* r = (void*)p;
        p += (bytes + 511) & ~(size_t)511;
        return r;
    };
    float* normS     = (float*)carve((size_t)N_NODES * 4);
    float* normD     = (float*)carve((size_t)N_NODES * 4);
    int*   row_ptr   = (int*)carve((size_t)(N_NODES + 1) * 4);
    int*   bcntS     = (int*)carve((size_t)NBUCK * 4);
    int*   bcntD     = (int*)carve((size_t)NBUCK * 4);
    int*   baseS     = (int*)carve((size_t)(NBUCK + 1) * 4);
    int*   baseD     = (int*)carve((size_t)(NBUCK + 1) * 4);
    int*   curS      = (int*)carve((size_t)NBUCK * 4);
    int*   curD      = (int*)carve((size_t)NBUCK * 4);
    int*   ssrc      = (int*)carve((size_t)N_EDGES * 4);
    unsigned* binbuf = (unsigned*)carve((size_t)N_EDGES * 4);
    unsigned* sbin   = (unsigned*)carve((size_t)N_EDGES * 4);
    float* keys      = (float*)carve((size_t)N_NODES * 4);
    int*   topk_idx  = (int*)carve((size_t)BATCH * TOPK * 4);
    unsigned long long* sortbuf = (unsigned long long*)carve((size_t)BATCH * SORTN * 8);
    float* bufA      = (float*)carve((size_t)N_NODES * HID * 4);   // h1s, then h2
    float* bufB      = (float*)carve((size_t)N_NODES * HID * 4);   // g2
    float* g1        = (float*)carve((size_t)N_NODES * IN_DIM * 4);

    const int GB = (N_NODES + BMT - 1) / BMT;     // gemm tiles
    const int BB = (N_EDGES + CHUNK - 1) / CHUNK; // bin blocks (196)

    hipMemsetAsync(bcntS, 0, (size_t)NBUCK * 4, stream);
    hipMemsetAsync(bcntD, 0, (size_t)NBUCK * 4, stream);

    // CSR build + degrees/norms, all via bucket binning (no global scatter atomics)
    k_bcount<<<BB, 256, 0, stream>>>(src, dst, bcntS, bcntD);
    k_bscan<<<1, 64, 0, stream>>>(bcntS, bcntD, baseS, baseD, curS, curD);
    k_bin<<<BB, 256, 0, stream>>>(src, dst, curD, binbuf);
    k_bin_src<<<BB, 256, 0, stream>>>(src, curS, sbin);
    k_histS<<<NBUCK, 256, 0, stream>>>(sbin, baseS, normS);
    k_histD_scatter<<<NBUCK, 256, 0, stream>>>(binbuf, baseD, normD, row_ptr, ssrc);

    // layer 1: aggregate RAW 64-ch features (scaled by normS), then transform
    k_agg64<<<(N_NODES + 15) / 16, 256, 0, stream>>>(features, row_ptr, ssrc, normS, g1);
    k_gemm_rt<IN_DIM, true, false><<<GB, 256, 0, stream>>>(g1, W1, normD, b1, normS, nullptr, bufA);
    // layer 2: aggregate h1s (normS pre-applied in epilogue), then transform
    k_agg128<<<(N_NODES + 7) / 8, 256, 0, stream>>>(bufA, row_ptr, ssrc, bufB);
    k_gemm_rt<HID, false, true><<<GB, 256, 0, stream>>>(bufB, W2, normD, b2, nullptr, keys, bufA);

    // hybrid bitonic full sort (same network as a single-block bitonic sort)
    const int NCHUNK = BATCH * SORTN / SORTC;          // 64
    const int GCE    = (BATCH * (SORTN / 2) + 255) / 256; // 256 blocks
    k_sort_init<<<(BATCH * SORTN + 255) / 256, 256, 0, stream>>>(keys, sortbuf);
    k_sort_local_full<<<NCHUNK, 1024, 0, stream>>>(sortbuf);
    // k = 4096
    k_sort_global<<<GCE, 256, 0, stream>>>(sortbuf, 4096, 2048);
    k_sort_local_tail<<<NCHUNK, 1024, 0, stream>>>(sortbuf, 4096);
    // k = 8192
    k_sort_global<<<GCE, 256, 0, stream>>>(sortbuf, 8192, 4096);
    k_sort_global<<<GCE, 256, 0, stream>>>(sortbuf, 8192, 2048);
    k_sort_local_tail<<<NCHUNK, 1024, 0, stream>>>(sortbuf, 8192);
    // k = 16384
    k_sort_global<<<GCE, 256, 0, stream>>>(sortbuf, 16384, 8192);
    k_sort_global<<<GCE, 256, 0, stream>>>(sortbuf, 16384, 4096);
    k_sort_global<<<GCE, 256, 0, stream>>>(sortbuf, 16384, 2048);
    k_sort_local_tail<<<NCHUNK, 1024, 0, stream>>>(sortbuf, 16384);
    k_sort_emit<<<(BATCH * TOPK + 255) / 256, 256, 0, stream>>>(sortbuf, topk_idx);

    k_outinit<<<1, 256, 0, stream>>>(b3, out);
    k_final<<<BATCH * (TOPK / KPB), 128, 0, stream>>>(bufA, topk_idx, W3, out);
}

// Round 10
// 583.551 us; speedup vs baseline: 2.1837x; 1.0192x over previous
//
#include <hip/hip_runtime.h>
#include <cstdint>
#include <cstddef>

#define N_NODES 100000
#define N_EDGES 1600000
#define IN_DIM  64
#define HID     128
#define NCLS    18
#define BATCH   8
#define TOPK    5000
#define NPER    12500   // N_NODES / BATCH
#define SORTN   16384   // next pow2 >= NPER
#define SORTC   2048    // LDS-local chunk for hybrid bitonic

#define BSHIFT  9                      // bucket = node >> 9 (512 nodes per bucket)
#define BNODES  (1 << BSHIFT)
#define NBUCK   ((N_NODES + BNODES - 1) / BNODES)   // 196
#define CHUNK   8192                   // edges per block in binning kernels

// ---------------- bucket-level counting (LDS-privatized) ----------------

__global__ __launch_bounds__(256) void k_bcount(const int* __restrict__ src,
                                                const int* __restrict__ dst,
                                                int* __restrict__ bcntS,
                                                int* __restrict__ bcntD) {
    __shared__ int cs[NBUCK], cd[NBUCK];
    for (int b = threadIdx.x; b < NBUCK; b += 256) { cs[b] = 0; cd[b] = 0; }
    __syncthreads();
    const int base = blockIdx.x * CHUNK;
    const int end  = min(base + CHUNK, N_EDGES);
    for (int e = base + threadIdx.x; e < end; e += 256) {
        atomicAdd(&cs[src[e] >> BSHIFT], 1);
        atomicAdd(&cd[dst[e] >> BSHIFT], 1);
    }
    __syncthreads();
    for (int b = threadIdx.x; b < NBUCK; b += 256) {
        if (cs[b]) atomicAdd(&bcntS[b], cs[b]);
        if (cd[b]) atomicAdd(&bcntD[b], cd[b]);
    }
}

__global__ void k_bscan(const int* __restrict__ bcntS, const int* __restrict__ bcntD,
                        int* __restrict__ baseS, int* __restrict__ baseD,
                        int* __restrict__ curS, int* __restrict__ curD) {
    if (threadIdx.x == 0 && blockIdx.x == 0) {
        int rs = 0, rd = 0;
        for (int b = 0; b < NBUCK; ++b) {
            baseS[b] = rs; curS[b] = rs; rs += bcntS[b];
            baseD[b] = rd; curD[b] = rd; rd += bcntD[b];
        }
        baseS[NBUCK] = rs; baseD[NBUCK] = rd;
    }
}

// ---------------- merged binned edge placement (dst-bin AND src-bin) --------

__global__ __launch_bounds__(256) void k_bin2(const int* __restrict__ src,
                                              const int* __restrict__ dst,
                                              int* __restrict__ cursorD,
                                              int* __restrict__ cursorS,
                                              unsigned* __restrict__ binbuf,
                                              unsigned* __restrict__ sbin) {
    __shared__ int cD[NBUCK], gD[NBUCK], aD[NBUCK];
    __shared__ int cS[NBUCK], gS[NBUCK], aS[NBUCK];
    const int base = blockIdx.x * CHUNK;
    const int end  = min(base + CHUNK, N_EDGES);
    for (int b = threadIdx.x; b < NBUCK; b += 256) {
        cD[b] = 0; aD[b] = 0; cS[b] = 0; aS[b] = 0;
    }
    __syncthreads();
    for (int e = base + threadIdx.x; e < end; e += 256) {
        atomicAdd(&cD[dst[e] >> BSHIFT], 1);
        atomicAdd(&cS[src[e] >> BSHIFT], 1);
    }
    __syncthreads();
    for (int b = threadIdx.x; b < NBUCK; b += 256) {
        if (cD[b] > 0) gD[b] = atomicAdd(&cursorD[b], cD[b]);
        if (cS[b] > 0) gS[b] = atomicAdd(&cursorS[b], cS[b]);
    }
    __syncthreads();
    for (int e = base + threadIdx.x; e < end; e += 256) {
        int d = dst[e], s = src[e];
        int bd = d >> BSHIFT;
        int od = atomicAdd(&aD[bd], 1);
        binbuf[gD[bd] + od] = ((unsigned)(d & (BNODES - 1)) << 17) | (unsigned)s;
        int bs = s >> BSHIFT;
        int os = atomicAdd(&aS[bs], 1);
        sbin[gS[bs] + os] = (unsigned)(s & (BNODES - 1));
    }
}

// ---------------- merged per-bucket histograms: normS, normD, row_ptr, ssrc --

__global__ __launch_bounds__(256) void k_hist_all(const unsigned* __restrict__ sbin,
                                                  const int* __restrict__ baseS,
                                                  const unsigned* __restrict__ binbuf,
                                                  const int* __restrict__ baseD,
                                                  float* __restrict__ normS,
                                                  float* __restrict__ normD,
                                                  int* __restrict__ row_ptr,
                                                  int* __restrict__ ssrc) {
    __shared__ int cnt[BNODES];
    __shared__ int tmp[BNODES];
    const int nodeBase = blockIdx.x << BSHIFT;
    // ---- src histogram -> normS
    for (int t = threadIdx.x; t < BNODES; t += 256) cnt[t] = 0;
    __syncthreads();
    {
        const int beg = baseS[blockIdx.x], end = baseS[blockIdx.x + 1];
        for (int e = beg + threadIdx.x; e < end; e += 256)
            atomicAdd(&cnt[sbin[e]], 1);
    }
    __syncthreads();
    for (int t = threadIdx.x; t < BNODES; t += 256) {
        int node = nodeBase + t;
        if (node < N_NODES)
            normS[node] = 1.0f / sqrtf((float)max(cnt[t], 1));
        cnt[t] = 0;                      // re-zero own slots for dst pass
    }
    __syncthreads();
    // ---- dst histogram -> normD + scan -> row_ptr + scatter ssrc
    const int beg = baseD[blockIdx.x], end = baseD[blockIdx.x + 1];
    for (int e = beg + threadIdx.x; e < end; e += 256)
        atomicAdd(&cnt[binbuf[e] >> 17], 1);
    __syncthreads();
    for (int t = threadIdx.x; t < BNODES; t += 256) {
        int node = nodeBase + t;
        if (node < N_NODES)
            normD[node] = 1.0f / sqrtf((float)max(cnt[t], 1));
    }
    // inclusive Hillis-Steele scan over cnt[512]
    for (int s = 1; s < BNODES; s <<= 1) {
        for (int t = threadIdx.x; t < BNODES; t += 256)
            tmp[t] = (t >= s) ? cnt[t - s] + cnt[t] : cnt[t];
        __syncthreads();
        for (int t = threadIdx.x; t < BNODES; t += 256) cnt[t] = tmp[t];
        __syncthreads();
    }
    for (int t = threadIdx.x; t < BNODES; t += 256) {
        int b = beg + ((t == 0) ? 0 : cnt[t - 1]);   // exclusive base
        tmp[t] = b;
        int node = nodeBase + t;
        if (node < N_NODES) row_ptr[node] = b;
    }
    if (blockIdx.x == 0 && threadIdx.x == 0) row_ptr[N_NODES] = N_EDGES;
    __syncthreads();
    for (int e = beg + threadIdx.x; e < end; e += 256) {
        unsigned v = binbuf[e];
        int pos = atomicAdd(&tmp[v >> 17], 1);
        ssrc[pos] = (int)(v & 0x1FFFFu);
    }
}

// ---------------- fused gather + GEMM + epilogue per layer ------------------
// Phase 1: gather 64 dst rows' neighbor sums directly into LDS xs tile.
// Phase 2: register-tiled GEMM xs @ W with fused norm/bias/relu epilogue.
// out = relu((A_gather(X) @ W) * normD + bias) [* normS_post if POST]
// Numerics identical to the former k_agg* + k_gemm_rt pair (same edge order,
// same k order, same epilogue).

#define BMT 64
#define BKT 32

template<int KDIM, bool SCALE, bool POST, bool KEYS>
__global__ __launch_bounds__(256) void k_fused(const float* __restrict__ X,
                                               const int* __restrict__ row_ptr,
                                               const int* __restrict__ ssrc,
                                               const float* __restrict__ normSrc,
                                               const float* __restrict__ W,
                                               const float* __restrict__ normD,
                                               const float* __restrict__ bias,
                                               const float* __restrict__ normS_post,
                                               float* __restrict__ keys,
                                               float* __restrict__ out) {
    __shared__ float xs[BMT][KDIM + 4];    // 64x68 (17.4KB) or 64x132 (33.8KB)
    __shared__ float ws[BKT * HID];        // 16 KB

    const int tid = threadIdx.x;
    const int rt = blockIdx.x * BMT;

    // ---- gather phase: LPN lanes per node, NCH nodes in flight
    {
        constexpr int LPN = KDIM / 4;      // 16 or 32 lanes per node
        constexpr int NCH = 256 / LPN;     // 16 or 8 nodes per chunk
        const int w = tid / LPN;
        const int lane = tid % LPN;
        const float4* __restrict__ hv = (const float4*)X;
        #pragma unroll
        for (int c = 0; c < BMT / NCH; ++c) {
            const int row = c * NCH + w;
            const int node = rt + row;
            float4 a4 = make_float4(0.f, 0.f, 0.f, 0.f);
            if (node < N_NODES) {
                const int beg = row_ptr[node], end = row_ptr[node + 1];
                int e = beg;
                for (; e + 4 <= end; e += 4) {
                    int s0 = ssrc[e + 0], s1 = ssrc[e + 1], s2 = ssrc[e + 2], s3 = ssrc[e + 3];
                    float4 v0 = hv[(size_t)s0 * LPN + lane];
                    float4 v1 = hv[(size_t)s1 * LPN + lane];
                    float4 v2 = hv[(size_t)s2 * LPN + lane];
                    float4 v3 = hv[(size_t)s3 * LPN + lane];
                    if constexpr (SCALE) {
                        float n0 = normSrc[s0], n1 = normSrc[s1], n2 = normSrc[s2], n3 = normSrc[s3];
                        a4.x += v0.x * n0; a4.y += v0.y * n0; a4.z += v0.z * n0; a4.w += v0.w * n0;
                        a4.x += v1.x * n1; a4.y += v1.y * n1; a4.z += v1.z * n1; a4.w += v1.w * n1;
                        a4.x += v2.x * n2; a4.y += v2.y * n2; a4.z += v2.z * n2; a4.w += v2.w * n2;
                        a4.x += v3.x * n3; a4.y += v3.y * n3; a4.z += v3.z * n3; a4.w += v3.w * n3;
                    } else {
                        a4.x += v0.x; a4.y += v0.y; a4.z += v0.z; a4.w += v0.w;
                        a4.x += v1.x; a4.y += v1.y; a4.z += v1.z; a4.w += v1.w;
                        a4.x += v2.x; a4.y += v2.y; a4.z += v2.z; a4.w += v2.w;
                        a4.x += v3.x; a4.y += v3.y; a4.z += v3.z; a4.w += v3.w;
                    }
                }
                for (; e < end; ++e) {
                    int s0 = ssrc[e];
                    float4 v0 = hv[(size_t)s0 * LPN + lane];
                    if constexpr (SCALE) {
                        float n0 = normSrc[s0];
                        a4.x += v0.x * n0; a4.y += v0.y * n0; a4.z += v0.z * n0; a4.w += v0.w * n0;
                    } else {
                        a4.x += v0.x; a4.y += v0.y; a4.z += v0.z; a4.w += v0.w;
                    }
                }
            }
            *(float4*)&xs[row][lane * 4] = a4;
        }
    }

    // ---- GEMM phase
    const int tx = tid & 31;
    const int ty = tid >> 5;
    const int col0 = tx * 4;
    const int row0 = ty * 8;

    float acc[8][4];
    #pragma unroll
    for (int r = 0; r < 8; ++r)
        #pragma unroll
        for (int c = 0; c < 4; ++c) acc[r][c] = 0.f;

    for (int k0 = 0; k0 < KDIM; k0 += BKT) {
        __syncthreads();   // first iter: closes gather writes; later: closes ws reads
        {
            const float4* wsrc = (const float4*)(W + (size_t)k0 * HID);
            #pragma unroll
            for (int i = tid; i < BKT * HID / 4; i += 256)
                ((float4*)ws)[i] = wsrc[i];
        }
        __syncthreads();
        #pragma unroll 4
        for (int k = 0; k < BKT; ++k) {
            float4 b = *(const float4*)&ws[k * HID + col0];
            float a[8];
            #pragma unroll
            for (int r = 0; r < 8; ++r) a[r] = xs[row0 + r][k0 + k];
            #pragma unroll
            for (int r = 0; r < 8; ++r) {
                acc[r][0] += a[r] * b.x;
                acc[r][1] += a[r] * b.y;
                acc[r][2] += a[r] * b.z;
                acc[r][3] += a[r] * b.w;
            }
        }
    }

    const float4 bb = *(const float4*)(bias + col0);
    #pragma unroll
    for (int r = 0; r < 8; ++r) {
        int gr = rt + row0 + r;
        if (gr < N_NODES) {
            float nd = normD[gr];
            float4 o;
            o.x = fmaxf(acc[r][0] * nd + bb.x, 0.f);
            o.y = fmaxf(acc[r][1] * nd + bb.y, 0.f);
            o.z = fmaxf(acc[r][2] * nd + bb.z, 0.f);
            o.w = fmaxf(acc[r][3] * nd + bb.w, 0.f);
            if (KEYS && col0 == 124) keys[gr] = o.w;   // channel 127
            if (POST) {
                float ns = normS_post[gr];
                o.x *= ns; o.y *= ns; o.z *= ns; o.w *= ns;
            }
            *(float4*)(out + (size_t)gr * HID + col0) = o;
        }
    }
}

// ---------------- hybrid bitonic top-K ----------------

__global__ __launch_bounds__(256) void k_sort_init(const float* __restrict__ keys,
                                                   unsigned long long* __restrict__ arr) {
    int i = blockIdx.x * 256 + threadIdx.x;          // 0 .. 8*16384-1
    if (i >= BATCH * SORTN) return;
    int g = i >> 14;            // /SORTN
    int l = i & (SORTN - 1);
    unsigned long long c;
    if (l < NPER) {
        unsigned u = __float_as_uint(keys[g * NPER + l]);
        unsigned s = (u & 0x80000000u) ? ~u : (u | 0x80000000u); // ascending map
        unsigned d = ~s;                                         // descending
        c = ((unsigned long long)d << 32) | (unsigned)l;
    } else {
        c = 0xFFFFFFFFFFFFFFFFull;  // sorts last
    }
    arr[i] = c;
}

// stages k = 2 .. SORTC entirely in LDS (one block per SORTC-chunk)
__global__ __launch_bounds__(1024) void k_sort_local_full(unsigned long long* __restrict__ arr) {
    __shared__ unsigned long long lds[SORTC];
    const int base  = blockIdx.x * SORTC;            // flat base into arr
    const int gbase = base & (SORTN - 1);            // base within the graph's array
    lds[threadIdx.x]        = arr[base + threadIdx.x];
    lds[threadIdx.x + 1024] = arr[base + threadIdx.x + 1024];
    __syncthreads();
    for (int k = 2; k <= SORTC; k <<= 1) {
        for (int j = k >> 1; j > 0; j >>= 1) {
            int t = threadIdx.x;                     // SORTC/2 = 1024 CEs
            int i = ((t & ~(j - 1)) << 1) | (t & (j - 1));
            bool up = (((gbase + i) & k) == 0);
            unsigned long long a = lds[i], b = lds[i + j];
            if ((a > b) == up) { lds[i] = b; lds[i + j] = a; }
            __syncthreads();
        }
    }
    arr[base + threadIdx.x]        = lds[threadIdx.x];
    arr[base + threadIdx.x + 1024] = lds[threadIdx.x + 1024];
}

// one global compare-exchange substage (stride j >= SORTC)
__global__ __launch_bounds__(256) void k_sort_global(unsigned long long* __restrict__ arr,
                                                     int k, int j) {
    int tg = blockIdx.x * 256 + threadIdx.x;         // 8 * 8192 CEs
    if (tg >= BATCH * (SORTN / 2)) return;
    int g = tg >> 13;                                // / (SORTN/2)
    int t = tg & (SORTN / 2 - 1);
    int i = ((t & ~(j - 1)) << 1) | (t & (j - 1));
    bool up = ((i & k) == 0);
    unsigned long long* p = arr + (size_t)g * SORTN;
    unsigned long long a = p[i], b = p[i + j];
    if ((a > b) == up) { p[i] = b; p[i + j] = a; }
}

// tail strides j = SORTC/2 .. 1 of stage k, LDS-local per SORTC-chunk
__global__ __launch_bounds__(1024) void k_sort_local_tail(unsigned long long* __restrict__ arr,
                                                          int k) {
    __shared__ unsigned long long lds[SORTC];
    const int base  = blockIdx.x * SORTC;
    const int gbase = base & (SORTN - 1);
    lds[threadIdx.x]        = arr[base + threadIdx.x];
    lds[threadIdx.x + 1024] = arr[base + threadIdx.x + 1024];
    __syncthreads();
    for (int j = SORTC >> 1; j > 0; j >>= 1) {
        int t = threadIdx.x;
        int i = ((t & ~(j - 1)) << 1) | (t & (j - 1));
        bool up = (((gbase + i) & k) == 0);
        unsigned long long a = lds[i], b = lds[i + j];
        if ((a > b) == up) { lds[i] = b; lds[i + j] = a; }
        __syncthreads();
    }
    arr[base + threadIdx.x]        = lds[threadIdx.x];
    arr[base + threadIdx.x + 1024] = lds[threadIdx.x + 1024];
}

// emit top-K indices; also initialize out with bias (folds old k_outinit)
__global__ __launch_bounds__(256) void k_sort_emit(const unsigned long long* __restrict__ arr,
                                                   int* __restrict__ topk_idx,
                                                   const float* __restrict__ b3,
                                                   float* __restrict__ out) {
    int i = blockIdx.x * 256 + threadIdx.x;
    if (i < BATCH * NCLS) out[i] = b3[i % NCLS];
    if (i >= BATCH * TOPK) return;
    int b = i / TOPK;
    int k = i - b * TOPK;
    topk_idx[i] = (int)(arr[(size_t)b * SORTN + k] & 0xFFFFFFFFull);
}

// ---------------- final reduction GEMM ----------------

#define KPB 100   // top-k rows per block

__global__ __launch_bounds__(128) void k_final(const float* __restrict__ h2,
                                               const int* __restrict__ topk_idx,
                                               const float* __restrict__ W3,
                                               float* __restrict__ out) {
    __shared__ float red[128 * NCLS];
    const int b = blockIdx.x / (TOPK / KPB);
    const int chunk = blockIdx.x % (TOPK / KPB);
    const int j = threadIdx.x;
    float acc[NCLS];
    #pragma unroll
    for (int c = 0; c < NCLS; ++c) acc[c] = 0.f;
    const int k0 = chunk * KPB;
    for (int k = k0; k < k0 + KPB; ++k) {
        int node = b * NPER + topk_idx[b * TOPK + k];
        float h = h2[(size_t)node * HID + j];
        const float* wrow = W3 + (size_t)(k * HID + j) * NCLS;
        #pragma unroll
        for (int c = 0; c < NCLS; ++c) acc[c] += h * wrow[c];
    }
    #pragma unroll
    for (int c = 0; c < NCLS; ++c) red[j * NCLS + c] = acc[c];
    __syncthreads();
    for (int s = 64; s > 0; s >>= 1) {
        if (j < s) {
            #pragma unroll
            for (int c = 0; c < NCLS; ++c) red[j * NCLS + c] += red[(j + s) * NCLS + c];
        }
        __syncthreads();
    }
    if (j < NCLS) atomicAdd(&out[b * NCLS + j], red[j]);
}

// ---------------- launch ----------------

extern "C" void kernel_launch(void* const* d_in, const int* in_sizes, int n_in,
                              void* d_out, int out_size, void* d_ws, size_t ws_size,
                              hipStream_t stream) {
    const float* features = (const float*)d_in[0];
    const int*   src      = (const int*)d_in[1];
    const int*   dst      = (const int*)d_in[2];
    const float* W1       = (const float*)d_in[3];
    const float* b1       = (const float*)d_in[4];
    const float* W2       = (const float*)d_in[5];
    const float* b2       = (const float*)d_in[6];
    const float* W3       = (const float*)d_in[7];
    const float* b3       = (const float*)d_in[8];
    float* out = (float*)d_out;

    char* p = (char*)d_ws;
    auto carve = [&](size_t bytes) -> void* {
        void* r = (void*)p;
        p += (bytes + 511) & ~(size_t)511;
        return r;
    };
    float* normS     = (float*)carve((size_t)N_NODES * 4);
    float* normD     = (float*)carve((size_t)N_NODES * 4);
    int*   row_ptr   = (int*)carve((size_t)(N_NODES + 1) * 4);
    int*   bcntS     = (int*)carve((size_t)NBUCK * 4);
    int*   bcntD     = (int*)carve((size_t)NBUCK * 4);
    int*   baseS     = (int*)carve((size_t)(NBUCK + 1) * 4);
    int*   baseD     = (int*)carve((size_t)(NBUCK + 1) * 4);
    int*   curS      = (int*)carve((size_t)NBUCK * 4);
    int*   curD      = (int*)carve((size_t)NBUCK * 4);
    int*   ssrc      = (int*)carve((size_t)N_EDGES * 4);
    unsigned* binbuf = (unsigned*)carve((size_t)N_EDGES * 4);
    unsigned* sbin   = (unsigned*)carve((size_t)N_EDGES * 4);
    float* keys      = (float*)carve((size_t)N_NODES * 4);
    int*   topk_idx  = (int*)carve((size_t)BATCH * TOPK * 4);
    unsigned long long* sortbuf = (unsigned long long*)carve((size_t)BATCH * SORTN * 8);
    float* bufA      = (float*)carve((size_t)N_NODES * HID * 4);   // h1s
    float* bufB      = (float*)carve((size_t)N_NODES * HID * 4);   // h2

    const int GB = (N_NODES + BMT - 1) / BMT;     // 1563 fused tiles
    const int BB = (N_EDGES + CHUNK - 1) / CHUNK; // bin blocks (196)

    hipMemsetAsync(bcntS, 0, (size_t)NBUCK * 4, stream);
    hipMemsetAsync(bcntD, 0, (size_t)NBUCK * 4, stream);

    // CSR build + degrees/norms via bucket binning (no global scatter atomics)
    k_bcount<<<BB, 256, 0, stream>>>(src, dst, bcntS, bcntD);
    k_bscan<<<1, 64, 0, stream>>>(bcntS, bcntD, baseS, baseD, curS, curD);
    k_bin2<<<BB, 256, 0, stream>>>(src, dst, curD, curS, binbuf, sbin);
    k_hist_all<<<NBUCK, 256, 0, stream>>>(sbin, baseS, binbuf, baseD,
                                          normS, normD, row_ptr, ssrc);

    // layer 1: gather raw 64-ch features (x normS) + W1 GEMM + epilogue, fused
    k_fused<IN_DIM, true, true, false><<<GB, 256, 0, stream>>>(
        features, row_ptr, ssrc, normS, W1, normD, b1, normS, nullptr, bufA);
    // layer 2: gather h1s + W2 GEMM + epilogue (writes keys), fused
    k_fused<HID, false, false, true><<<GB, 256, 0, stream>>>(
        bufA, row_ptr, ssrc, nullptr, W2, normD, b2, nullptr, keys, bufB);

    // hybrid bitonic full sort (same network as a single-block bitonic sort)
    const int NCHUNK = BATCH * SORTN / SORTC;          // 64
    const int GCE    = (BATCH * (SORTN / 2) + 255) / 256; // 256 blocks
    k_sort_init<<<(BATCH * SORTN + 255) / 256, 256, 0, stream>>>(keys, sortbuf);
    k_sort_local_full<<<NCHUNK, 1024, 0, stream>>>(sortbuf);
    // k = 4096
    k_sort_global<<<GCE, 256, 0, stream>>>(sortbuf, 4096, 2048);
    k_sort_local_tail<<<NCHUNK, 1024, 0, stream>>>(sortbuf, 4096);
    // k = 8192
    k_sort_global<<<GCE, 256, 0, stream>>>(sortbuf, 8192, 4096);
    k_sort_global<<<GCE, 256, 0, stream>>>(sortbuf, 8192, 2048);
    k_sort_local_tail<<<NCHUNK, 1024, 0, stream>>>(sortbuf, 8192);
    // k = 16384
    k_sort_global<<<GCE, 256, 0, stream>>>(sortbuf, 16384, 8192);
    k_sort_global<<<GCE, 256, 0, stream>>>(sortbuf, 16384, 4096);
    k_sort_global<<<GCE, 256, 0, stream>>>(sortbuf, 16384, 2048);
    k_sort_local_tail<<<NCHUNK, 1024, 0, stream>>>(sortbuf, 16384);
    k_sort_emit<<<(BATCH * TOPK + 255) / 256, 256, 0, stream>>>(sortbuf, topk_idx, b3, out);

    k_final<<<BATCH * (TOPK / KPB), 128, 0, stream>>>(bufB, topk_idx, W3, out);
}

// Round 11
// 578.423 us; speedup vs baseline: 2.2031x; 1.0089x over previous
//
#include <hip/hip_runtime.h>
#include <cstdint>
#include <cstddef>

#define N_NODES 100000
#define N_EDGES 1600000
#define IN_DIM  64
#define HID     128
#define NCLS    18
#define BATCH   8
#define TOPK    5000
#define NPER    12500   // N_NODES / BATCH
#define SORTN   16384   // next pow2 >= NPER
#define SORTC   2048    // LDS-local chunk for hybrid bitonic

#define BSHIFT  9                      // bucket = node >> 9 (512 nodes per bucket)
#define BNODES  (1 << BSHIFT)
#define NBUCK   ((N_NODES + BNODES - 1) / BNODES)   // 196
#define CHUNK   8192                   // edges per block in binning kernels

// ---------------- bucket-level counting (LDS-privatized) ----------------

__global__ __launch_bounds__(256) void k_bcount(const int* __restrict__ src,
                                                const int* __restrict__ dst,
                                                int* __restrict__ bcntS,
                                                int* __restrict__ bcntD) {
    __shared__ int cs[NBUCK], cd[NBUCK];
    for (int b = threadIdx.x; b < NBUCK; b += 256) { cs[b] = 0; cd[b] = 0; }
    __syncthreads();
    const int base = blockIdx.x * CHUNK;
    const int end  = min(base + CHUNK, N_EDGES);
    for (int e = base + threadIdx.x; e < end; e += 256) {
        atomicAdd(&cs[src[e] >> BSHIFT], 1);
        atomicAdd(&cd[dst[e] >> BSHIFT], 1);
    }
    __syncthreads();
    for (int b = threadIdx.x; b < NBUCK; b += 256) {
        if (cs[b]) atomicAdd(&bcntS[b], cs[b]);
        if (cd[b]) atomicAdd(&bcntD[b], cd[b]);
    }
}

__global__ void k_bscan(const int* __restrict__ bcntS, const int* __restrict__ bcntD,
                        int* __restrict__ baseS, int* __restrict__ baseD,
                        int* __restrict__ curS, int* __restrict__ curD) {
    if (threadIdx.x == 0 && blockIdx.x == 0) {
        int rs = 0, rd = 0;
        for (int b = 0; b < NBUCK; ++b) {
            baseS[b] = rs; curS[b] = rs; rs += bcntS[b];
            baseD[b] = rd; curD[b] = rd; rd += bcntD[b];
        }
        baseS[NBUCK] = rs; baseD[NBUCK] = rd;
    }
}

// ---------------- merged binned edge placement (dst-bin AND src-bin) --------

__global__ __launch_bounds__(256) void k_bin2(const int* __restrict__ src,
                                              const int* __restrict__ dst,
                                              int* __restrict__ cursorD,
                                              int* __restrict__ cursorS,
                                              unsigned* __restrict__ binbuf,
                                              unsigned* __restrict__ sbin) {
    __shared__ int cD[NBUCK], gD[NBUCK], aD[NBUCK];
    __shared__ int cS[NBUCK], gS[NBUCK], aS[NBUCK];
    const int base = blockIdx.x * CHUNK;
    const int end  = min(base + CHUNK, N_EDGES);
    for (int b = threadIdx.x; b < NBUCK; b += 256) {
        cD[b] = 0; aD[b] = 0; cS[b] = 0; aS[b] = 0;
    }
    __syncthreads();
    for (int e = base + threadIdx.x; e < end; e += 256) {
        atomicAdd(&cD[dst[e] >> BSHIFT], 1);
        atomicAdd(&cS[src[e] >> BSHIFT], 1);
    }
    __syncthreads();
    for (int b = threadIdx.x; b < NBUCK; b += 256) {
        if (cD[b] > 0) gD[b] = atomicAdd(&cursorD[b], cD[b]);
        if (cS[b] > 0) gS[b] = atomicAdd(&cursorS[b], cS[b]);
    }
    __syncthreads();
    for (int e = base + threadIdx.x; e < end; e += 256) {
        int d = dst[e], s = src[e];
        int bd = d >> BSHIFT;
        int od = atomicAdd(&aD[bd], 1);
        binbuf[gD[bd] + od] = ((unsigned)(d & (BNODES - 1)) << 17) | (unsigned)s;
        int bs = s >> BSHIFT;
        int os = atomicAdd(&aS[bs], 1);
        sbin[gS[bs] + os] = (unsigned)(s & (BNODES - 1));
    }
}

// ---------------- merged per-bucket histograms: normS, normD, row_ptr, ssrc --

__global__ __launch_bounds__(256) void k_hist_all(const unsigned* __restrict__ sbin,
                                                  const int* __restrict__ baseS,
                                                  const unsigned* __restrict__ binbuf,
                                                  const int* __restrict__ baseD,
                                                  float* __restrict__ normS,
                                                  float* __restrict__ normD,
                                                  int* __restrict__ row_ptr,
                                                  int* __restrict__ ssrc) {
    __shared__ int cnt[BNODES];
    __shared__ int tmp[BNODES];
    const int nodeBase = blockIdx.x << BSHIFT;
    // ---- src histogram -> normS
    for (int t = threadIdx.x; t < BNODES; t += 256) cnt[t] = 0;
    __syncthreads();
    {
        const int beg = baseS[blockIdx.x], end = baseS[blockIdx.x + 1];
        for (int e = beg + threadIdx.x; e < end; e += 256)
            atomicAdd(&cnt[sbin[e]], 1);
    }
    __syncthreads();
    for (int t = threadIdx.x; t < BNODES; t += 256) {
        int node = nodeBase + t;
        if (node < N_NODES)
            normS[node] = 1.0f / sqrtf((float)max(cnt[t], 1));
        cnt[t] = 0;                      // re-zero own slots for dst pass
    }
    __syncthreads();
    // ---- dst histogram -> normD + scan -> row_ptr + scatter ssrc
    const int beg = baseD[blockIdx.x], end = baseD[blockIdx.x + 1];
    for (int e = beg + threadIdx.x; e < end; e += 256)
        atomicAdd(&cnt[binbuf[e] >> 17], 1);
    __syncthreads();
    for (int t = threadIdx.x; t < BNODES; t += 256) {
        int node = nodeBase + t;
        if (node < N_NODES)
            normD[node] = 1.0f / sqrtf((float)max(cnt[t], 1));
    }
    // inclusive Hillis-Steele scan over cnt[512]
    for (int s = 1; s < BNODES; s <<= 1) {
        for (int t = threadIdx.x; t < BNODES; t += 256)
            tmp[t] = (t >= s) ? cnt[t - s] + cnt[t] : cnt[t];
        __syncthreads();
        for (int t = threadIdx.x; t < BNODES; t += 256) cnt[t] = tmp[t];
        __syncthreads();
    }
    for (int t = threadIdx.x; t < BNODES; t += 256) {
        int b = beg + ((t == 0) ? 0 : cnt[t - 1]);   // exclusive base
        tmp[t] = b;
        int node = nodeBase + t;
        if (node < N_NODES) row_ptr[node] = b;
    }
    if (blockIdx.x == 0 && threadIdx.x == 0) row_ptr[N_NODES] = N_EDGES;
    __syncthreads();
    for (int e = beg + threadIdx.x; e < end; e += 256) {
        unsigned v = binbuf[e];
        int pos = atomicAdd(&tmp[v >> 17], 1);
        ssrc[pos] = (int)(v & 0x1FFFFu);
    }
}

// ---------------- fused gather + GEMM (layer 1 only, small LDS) -------------
// out = relu((A_gather(X*normS) @ W) * normD + bias) * normS

#define BMT 64
#define BKT 32

__global__ __launch_bounds__(256) void k_fused1(const float* __restrict__ X,
                                                const int* __restrict__ row_ptr,
                                                const int* __restrict__ ssrc,
                                                const float* __restrict__ normS,
                                                const float* __restrict__ W,
                                                const float* __restrict__ normD,
                                                const float* __restrict__ bias,
                                                float* __restrict__ out) {
    __shared__ float xs[BMT][IN_DIM + 4];  // 64x68 = 17.4 KB
    __shared__ float ws[BKT * HID];        // 16 KB

    const int tid = threadIdx.x;
    const int rt = blockIdx.x * BMT;

    // ---- gather phase: 16 lanes per node, 16 nodes in flight
    {
        constexpr int LPN = IN_DIM / 4;    // 16
        constexpr int NCH = 256 / LPN;     // 16
        const int w = tid / LPN;
        const int lane = tid % LPN;
        const float4* __restrict__ hv = (const float4*)X;
        #pragma unroll
        for (int c = 0; c < BMT / NCH; ++c) {
            const int row = c * NCH + w;
            const int node = rt + row;
            float4 a4 = make_float4(0.f, 0.f, 0.f, 0.f);
            if (node < N_NODES) {
                const int beg = row_ptr[node], end = row_ptr[node + 1];
                int e = beg;
                for (; e + 4 <= end; e += 4) {
                    int s0 = ssrc[e + 0], s1 = ssrc[e + 1], s2 = ssrc[e + 2], s3 = ssrc[e + 3];
                    float n0 = normS[s0], n1 = normS[s1], n2 = normS[s2], n3 = normS[s3];
                    float4 v0 = hv[(size_t)s0 * LPN + lane];
                    float4 v1 = hv[(size_t)s1 * LPN + lane];
                    float4 v2 = hv[(size_t)s2 * LPN + lane];
                    float4 v3 = hv[(size_t)s3 * LPN + lane];
                    a4.x += v0.x * n0; a4.y += v0.y * n0; a4.z += v0.z * n0; a4.w += v0.w * n0;
                    a4.x += v1.x * n1; a4.y += v1.y * n1; a4.z += v1.z * n1; a4.w += v1.w * n1;
                    a4.x += v2.x * n2; a4.y += v2.y * n2; a4.z += v2.z * n2; a4.w += v2.w * n2;
                    a4.x += v3.x * n3; a4.y += v3.y * n3; a4.z += v3.z * n3; a4.w += v3.w * n3;
                }
                for (; e < end; ++e) {
                    int s0 = ssrc[e];
                    float n0 = normS[s0];
                    float4 v0 = hv[(size_t)s0 * LPN + lane];
                    a4.x += v0.x * n0; a4.y += v0.y * n0; a4.z += v0.z * n0; a4.w += v0.w * n0;
                }
            }
            *(float4*)&xs[row][lane * 4] = a4;
        }
    }

    // ---- GEMM phase
    const int tx = tid & 31;
    const int ty = tid >> 5;
    const int col0 = tx * 4;
    const int row0 = ty * 8;

    float acc[8][4];
    #pragma unroll
    for (int r = 0; r < 8; ++r)
        #pragma unroll
        for (int c = 0; c < 4; ++c) acc[r][c] = 0.f;

    for (int k0 = 0; k0 < IN_DIM; k0 += BKT) {
        __syncthreads();
        {
            const float4* wsrc = (const float4*)(W + (size_t)k0 * HID);
            #pragma unroll
            for (int i = tid; i < BKT * HID / 4; i += 256)
                ((float4*)ws)[i] = wsrc[i];
        }
        __syncthreads();
        #pragma unroll 4
        for (int k = 0; k < BKT; ++k) {
            float4 b = *(const float4*)&ws[k * HID + col0];
            float a[8];
            #pragma unroll
            for (int r = 0; r < 8; ++r) a[r] = xs[row0 + r][k0 + k];
            #pragma unroll
            for (int r = 0; r < 8; ++r) {
                acc[r][0] += a[r] * b.x;
                acc[r][1] += a[r] * b.y;
                acc[r][2] += a[r] * b.z;
                acc[r][3] += a[r] * b.w;
            }
        }
    }

    const float4 bb = *(const float4*)(bias + col0);
    #pragma unroll
    for (int r = 0; r < 8; ++r) {
        int gr = rt + row0 + r;
        if (gr < N_NODES) {
            float nd = normD[gr];
            float4 o;
            o.x = fmaxf(acc[r][0] * nd + bb.x, 0.f);
            o.y = fmaxf(acc[r][1] * nd + bb.y, 0.f);
            o.z = fmaxf(acc[r][2] * nd + bb.z, 0.f);
            o.w = fmaxf(acc[r][3] * nd + bb.w, 0.f);
            float ns = normS[gr];    // pre-apply next layer's src norm
            o.x *= ns; o.y *= ns; o.z *= ns; o.w *= ns;
            *(float4*)(out + (size_t)gr * HID + col0) = o;
        }
    }
}

// ---------------- layer-2 gather (zero-LDS, max occupancy) ----------------

#define ACC4(A, V) { A.x += V.x; A.y += V.y; A.z += V.z; A.w += V.w; }

__global__ __launch_bounds__(256) void k_agg128(const float* __restrict__ hs,
                                                const int* __restrict__ row_ptr,
                                                const int* __restrict__ ssrc,
                                                float* __restrict__ out) {
    const int node = blockIdx.x * 8 + (threadIdx.x >> 5);
    const int lane = threadIdx.x & 31;     // channels lane*4 .. lane*4+3 of 128
    if (node >= N_NODES) return;
    const int beg = row_ptr[node], end = row_ptr[node + 1];
    const float4* __restrict__ hv = (const float4*)hs;
    float4 acc = make_float4(0.f, 0.f, 0.f, 0.f);
    int e = beg;
    for (; e + 4 <= end; e += 4) {
        int s0 = ssrc[e + 0], s1 = ssrc[e + 1], s2 = ssrc[e + 2], s3 = ssrc[e + 3];
        float4 v0 = hv[(size_t)s0 * 32 + lane];
        float4 v1 = hv[(size_t)s1 * 32 + lane];
        float4 v2 = hv[(size_t)s2 * 32 + lane];
        float4 v3 = hv[(size_t)s3 * 32 + lane];
        ACC4(acc, v0); ACC4(acc, v1); ACC4(acc, v2); ACC4(acc, v3);
    }
    for (; e < end; ++e) {
        float4 v0 = hv[(size_t)ssrc[e] * 32 + lane];
        ACC4(acc, v0);
    }
    *(float4*)(out + (size_t)node * HID + lane * 4) = acc;
}

// ---------------- standalone register-tiled GEMM for layer 2 --------------
// out = relu((G @ W2) * normD + bias); keys = out[:,127]

__global__ __launch_bounds__(256) void k_gemm2(const float* __restrict__ X,
                                               const float* __restrict__ W,
                                               const float* __restrict__ normD,
                                               const float* __restrict__ bias,
                                               float* __restrict__ keys,
                                               float* __restrict__ out) {
    __shared__ float xs[BMT][BKT + 4];     // 64 x 36
    __shared__ float ws[BKT * HID];        // 16 KB

    const int tid = threadIdx.x;
    const int tx = tid & 31;
    const int ty = tid >> 5;
    const int col0 = tx * 4;
    const int row0 = ty * 8;
    const int rt = blockIdx.x * BMT;

    float acc[8][4];
    #pragma unroll
    for (int r = 0; r < 8; ++r)
        #pragma unroll
        for (int c = 0; c < 4; ++c) acc[r][c] = 0.f;

    for (int k0 = 0; k0 < HID; k0 += BKT) {
        __syncthreads();
        {
            const float4* wsrc = (const float4*)(W + (size_t)k0 * HID);
            #pragma unroll
            for (int i = tid; i < BKT * HID / 4; i += 256)
                ((float4*)ws)[i] = wsrc[i];
        }
        {
            #pragma unroll
            for (int i = tid; i < BMT * BKT / 4; i += 256) {
                int row = i >> 3;
                int kq  = i & 7;
                int gr  = rt + row;
                float4 v = make_float4(0.f, 0.f, 0.f, 0.f);
                if (gr < N_NODES)
                    v = *(const float4*)(X + (size_t)gr * HID + k0 + kq * 4);
                *(float4*)&xs[row][kq * 4] = v;
            }
        }
        __syncthreads();

        #pragma unroll 4
        for (int k = 0; k < BKT; ++k) {
            float4 b = *(const float4*)&ws[k * HID + col0];
            float a[8];
            #pragma unroll
            for (int r = 0; r < 8; ++r) a[r] = xs[row0 + r][k];
            #pragma unroll
            for (int r = 0; r < 8; ++r) {
                acc[r][0] += a[r] * b.x;
                acc[r][1] += a[r] * b.y;
                acc[r][2] += a[r] * b.z;
                acc[r][3] += a[r] * b.w;
            }
        }
    }

    const float4 bb = *(const float4*)(bias + col0);
    #pragma unroll
    for (int r = 0; r < 8; ++r) {
        int gr = rt + row0 + r;
        if (gr < N_NODES) {
            float nd = normD[gr];
            float4 o;
            o.x = fmaxf(acc[r][0] * nd + bb.x, 0.f);
            o.y = fmaxf(acc[r][1] * nd + bb.y, 0.f);
            o.z = fmaxf(acc[r][2] * nd + bb.z, 0.f);
            o.w = fmaxf(acc[r][3] * nd + bb.w, 0.f);
            if (col0 == 124) keys[gr] = o.w;   // channel 127
            *(float4*)(out + (size_t)gr * HID + col0) = o;
        }
    }
}

// ---------------- hybrid bitonic top-K ----------------

__global__ __launch_bounds__(256) void k_sort_init(const float* __restrict__ keys,
                                                   unsigned long long* __restrict__ arr) {
    int i = blockIdx.x * 256 + threadIdx.x;          // 0 .. 8*16384-1
    if (i >= BATCH * SORTN) return;
    int g = i >> 14;            // /SORTN
    int l = i & (SORTN - 1);
    unsigned long long c;
    if (l < NPER) {
        unsigned u = __float_as_uint(keys[g * NPER + l]);
        unsigned s = (u & 0x80000000u) ? ~u : (u | 0x80000000u); // ascending map
        unsigned d = ~s;                                         // descending
        c = ((unsigned long long)d << 32) | (unsigned)l;
    } else {
        c = 0xFFFFFFFFFFFFFFFFull;  // sorts last
    }
    arr[i] = c;
}

// stages k = 2 .. SORTC entirely in LDS (one block per SORTC-chunk)
__global__ __launch_bounds__(1024) void k_sort_local_full(unsigned long long* __restrict__ arr) {
    __shared__ unsigned long long lds[SORTC];
    const int base  = blockIdx.x * SORTC;            // flat base into arr
    const int gbase = base & (SORTN - 1);            // base within the graph's array
    lds[threadIdx.x]        = arr[base + threadIdx.x];
    lds[threadIdx.x + 1024] = arr[base + threadIdx.x + 1024];
    __syncthreads();
    for (int k = 2; k <= SORTC; k <<= 1) {
        for (int j = k >> 1; j > 0; j >>= 1) {
            int t = threadIdx.x;                     // SORTC/2 = 1024 CEs
            int i = ((t & ~(j - 1)) << 1) | (t & (j - 1));
            bool up = (((gbase + i) & k) == 0);
            unsigned long long a = lds[i], b = lds[i + j];
            if ((a > b) == up) { lds[i] = b; lds[i + j] = a; }
            __syncthreads();
        }
    }
    arr[base + threadIdx.x]        = lds[threadIdx.x];
    arr[base + threadIdx.x + 1024] = lds[threadIdx.x + 1024];
}

// one global compare-exchange substage (stride j >= SORTC)
__global__ __launch_bounds__(256) void k_sort_global(unsigned long long* __restrict__ arr,
                                                     int k, int j) {
    int tg = blockIdx.x * 256 + threadIdx.x;         // 8 * 8192 CEs
    if (tg >= BATCH * (SORTN / 2)) return;
    int g = tg >> 13;                                // / (SORTN/2)
    int t = tg & (SORTN / 2 - 1);
    int i = ((t & ~(j - 1)) << 1) | (t & (j - 1));
    bool up = ((i & k) == 0);
    unsigned long long* p = arr + (size_t)g * SORTN;
    unsigned long long a = p[i], b = p[i + j];
    if ((a > b) == up) { p[i] = b; p[i + j] = a; }
}

// tail strides j = SORTC/2 .. 1 of stage k, LDS-local per SORTC-chunk
__global__ __launch_bounds__(1024) void k_sort_local_tail(unsigned long long* __restrict__ arr,
                                                          int k) {
    __shared__ unsigned long long lds[SORTC];
    const int base  = blockIdx.x * SORTC;
    const int gbase = base & (SORTN - 1);
    lds[threadIdx.x]        = arr[base + threadIdx.x];
    lds[threadIdx.x + 1024] = arr[base + threadIdx.x + 1024];
    __syncthreads();
    for (int j = SORTC >> 1; j > 0; j >>= 1) {
        int t = threadIdx.x;
        int i = ((t & ~(j - 1)) << 1) | (t & (j - 1));
        bool up = (((gbase + i) & k) == 0);
        unsigned long long a = lds[i], b = lds[i + j];
        if ((a > b) == up) { lds[i] = b; lds[i + j] = a; }
        __syncthreads();
    }
    arr[base + threadIdx.x]        = lds[threadIdx.x];
    arr[base + threadIdx.x + 1024] = lds[threadIdx.x + 1024];
}

// emit top-K indices; also initialize out with bias (folds old k_outinit)
__global__ __launch_bounds__(256) void k_sort_emit(const unsigned long long* __restrict__ arr,
                                                   int* __restrict__ topk_idx,
                                                   const float* __restrict__ b3,
                                                   float* __restrict__ out) {
    int i = blockIdx.x * 256 + threadIdx.x;
    if (i < BATCH * NCLS) out[i] = b3[i % NCLS];
    if (i >= BATCH * TOPK) return;
    int b = i / TOPK;
    int k = i - b * TOPK;
    topk_idx[i] = (int)(arr[(size_t)b * SORTN + k] & 0xFFFFFFFFull);
}

// ---------------- final reduction GEMM ----------------

#define KPB 100   // top-k rows per block

__global__ __launch_bounds__(128) void k_final(const float* __restrict__ h2,
                                               const int* __restrict__ topk_idx,
                                               const float* __restrict__ W3,
                                               float* __restrict__ out) {
    __shared__ float red[128 * NCLS];
    const int b = blockIdx.x / (TOPK / KPB);
    const int chunk = blockIdx.x % (TOPK / KPB);
    const int j = threadIdx.x;
    float acc[NCLS];
    #pragma unroll
    for (int c = 0; c < NCLS; ++c) acc[c] = 0.f;
    const int k0 = chunk * KPB;
    for (int k = k0; k < k0 + KPB; ++k) {
        int node = b * NPER + topk_idx[b * TOPK + k];
        float h = h2[(size_t)node * HID + j];
        const float* wrow = W3 + (size_t)(k * HID + j) * NCLS;
        #pragma unroll
        for (int c = 0; c < NCLS; ++c) acc[c] += h * wrow[c];
    }
    #pragma unroll
    for (int c = 0; c < NCLS; ++c) red[j * NCLS + c] = acc[c];
    __syncthreads();
    for (int s = 64; s > 0; s >>= 1) {
        if (j < s) {
            #pragma unroll
            for (int c = 0; c < NCLS; ++c) red[j * NCLS + c] += red[(j + s) * NCLS + c];
        }
        __syncthreads();
    }
    if (j < NCLS) atomicAdd(&out[b * NCLS + j], red[j]);
}

// ---------------- launch ----------------

extern "C" void kernel_launch(void* const* d_in, const int* in_sizes, int n_in,
                              void* d_out, int out_size, void* d_ws, size_t ws_size,
                              hipStream_t stream) {
    const float* features = (const float*)d_in[0];
    const int*   src      = (const int*)d_in[1];
    const int*   dst      = (const int*)d_in[2];
    const float* W1       = (const float*)d_in[3];
    const float* b1       = (const float*)d_in[4];
    const float* W2       = (const float*)d_in[5];
    const float* b2       = (const float*)d_in[6];
    const float* W3       = (const float*)d_in[7];
    const float* b3       = (const float*)d_in[8];
    float* out = (float*)d_out;

    char* p = (char*)d_ws;
    auto carve = [&](size_t bytes) -> void* {
        void* r = (void*)p;
        p += (bytes + 511) & ~(size_t)511;
        return r;
    };
    float* normS     = (float*)carve((size_t)N_NODES * 4);
    float* normD     = (float*)carve((size_t)N_NODES * 4);
    int*   row_ptr   = (int*)carve((size_t)(N_NODES + 1) * 4);
    int*   bcntS     = (int*)carve((size_t)NBUCK * 4);
    int*   bcntD     = (int*)carve((size_t)NBUCK * 4);
    int*   baseS     = (int*)carve((size_t)(NBUCK + 1) * 4);
    int*   baseD     = (int*)carve((size_t)(NBUCK + 1) * 4);
    int*   curS      = (int*)carve((size_t)NBUCK * 4);
    int*   curD      = (int*)carve((size_t)NBUCK * 4);
    int*   ssrc      = (int*)carve((size_t)N_EDGES * 4);
    unsigned* binbuf = (unsigned*)carve((size_t)N_EDGES * 4);
    unsigned* sbin   = (unsigned*)carve((size_t)N_EDGES * 4);
    float* keys      = (float*)carve((size_t)N_NODES * 4);
    int*   topk_idx  = (int*)carve((size_t)BATCH * TOPK * 4);
    unsigned long long* sortbuf = (unsigned long long*)carve((size_t)BATCH * SORTN * 8);
    float* bufA      = (float*)carve((size_t)N_NODES * HID * 4);   // h1s, then h2
    float* bufB      = (float*)carve((size_t)N_NODES * HID * 4);   // g2

    const int GB = (N_NODES + BMT - 1) / BMT;     // 1563 tiles
    const int BB = (N_EDGES + CHUNK - 1) / CHUNK; // bin blocks (196)

    hipMemsetAsync(bcntS, 0, (size_t)NBUCK * 4, stream);
    hipMemsetAsync(bcntD, 0, (size_t)NBUCK * 4, stream);

    // CSR build + degrees/norms via bucket binning (no global scatter atomics)
    k_bcount<<<BB, 256, 0, stream>>>(src, dst, bcntS, bcntD);
    k_bscan<<<1, 64, 0, stream>>>(bcntS, bcntD, baseS, baseD, curS, curD);
    k_bin2<<<BB, 256, 0, stream>>>(src, dst, curD, curS, binbuf, sbin);
    k_hist_all<<<NBUCK, 256, 0, stream>>>(sbin, baseS, binbuf, baseD,
                                          normS, normD, row_ptr, ssrc);

    // layer 1: fused gather(64ch) + W1 GEMM + epilogue (small LDS, occupancy OK)
    k_fused1<<<GB, 256, 0, stream>>>(features, row_ptr, ssrc, normS, W1, normD, b1, bufA);
    // layer 2: UNFUSED — zero-LDS gather at full occupancy, then GEMM
    k_agg128<<<(N_NODES + 7) / 8, 256, 0, stream>>>(bufA, row_ptr, ssrc, bufB);
    k_gemm2<<<GB, 256, 0, stream>>>(bufB, W2, normD, b2, keys, bufA);

    // hybrid bitonic full sort (same network as a single-block bitonic sort)
    const int NCHUNK = BATCH * SORTN / SORTC;          // 64
    const int GCE    = (BATCH * (SORTN / 2) + 255) / 256; // 256 blocks
    k_sort_init<<<(BATCH * SORTN + 255) / 256, 256, 0, stream>>>(keys, sortbuf);
    k_sort_local_full<<<NCHUNK, 1024, 0, stream>>>(sortbuf);
    // k = 4096
    k_sort_global<<<GCE, 256, 0, stream>>>(sortbuf, 4096, 2048);
    k_sort_local_tail<<<NCHUNK, 1024, 0, stream>>>(sortbuf, 4096);
    // k = 8192
    k_sort_global<<<GCE, 256, 0, stream>>>(sortbuf, 8192, 4096);
    k_sort_global<<<GCE, 256, 0, stream>>>(sortbuf, 8192, 2048);
    k_sort_local_tail<<<NCHUNK, 1024, 0, stream>>>(sortbuf, 8192);
    // k = 16384
    k_sort_global<<<GCE, 256, 0, stream>>>(sortbuf, 16384, 8192);
    k_sort_global<<<GCE, 256, 0, stream>>>(sortbuf, 16384, 4096);
    k_sort_global<<<GCE, 256, 0, stream>>>(sortbuf, 16384, 2048);
    k_sort_local_tail<<<NCHUNK, 1024, 0, stream>>>(sortbuf, 16384);
    k_sort_emit<<<(BATCH * TOPK + 255) / 256, 256, 0, stream>>>(sortbuf, topk_idx, b3, out);

    k_final<<<BATCH * (TOPK / KPB), 128, 0, stream>>>(bufA, topk_idx, W3, out);
}